// Round 2
// baseline (1046.857 us; speedup 1.0000x reference)
//
#include <hip/hip_runtime.h>
#include <stdint.h>
#include <math.h>

// Problem constants
#define NB 8
#define NN 4096
#define ND 1024
#define NM 50
#define NF 4096
#define NS_ITERS 26

// ---------------- threefry2x32 (JAX-compatible) ----------------
__host__ __device__ constexpr uint32_t rotl32(uint32_t v, int n){ return (v<<n)|(v>>(32-n)); }
struct TFOut { uint32_t a, b; };
__host__ __device__ constexpr TFOut tf2x32(uint32_t k0, uint32_t k1, uint32_t x0, uint32_t x1){
  uint32_t ks2 = k0 ^ k1 ^ 0x1BD11BDAu;
  x0 += k0; x1 += k1;
#define TFR(R) x0 += x1; x1 = rotl32(x1,(R)) ^ x0;
  TFR(13) TFR(15) TFR(26) TFR(6)
  x0 += k1; x1 += ks2 + 1u;
  TFR(17) TFR(29) TFR(16) TFR(24)
  x0 += ks2; x1 += k0 + 2u;
  TFR(13) TFR(15) TFR(26) TFR(6)
  x0 += k0; x1 += k1 + 3u;
  TFR(17) TFR(29) TFR(16) TFR(24)
  x0 += k1; x1 += ks2 + 4u;
  TFR(13) TFR(15) TFR(26) TFR(6)
  x0 += ks2; x1 += k0 + 5u;
#undef TFR
  return TFOut{x0, x1};
}

// XLA/Giles erfinv (f32)
__device__ __forceinline__ float erfinv_f32(float x){
  float w = -log1pf(-x*x);
  float p;
  if (w < 5.0f) {
    w -= 2.5f;
    p = 2.81022636e-08f;
    p = fmaf(p, w, 3.43273939e-07f);
    p = fmaf(p, w, -3.5233877e-06f);
    p = fmaf(p, w, -4.39150654e-06f);
    p = fmaf(p, w, 0.00021858087f);
    p = fmaf(p, w, -0.00125372503f);
    p = fmaf(p, w, -0.00417768164f);
    p = fmaf(p, w, 0.246640727f);
    p = fmaf(p, w, 1.50140941f);
  } else {
    w = sqrtf(w) - 3.0f;
    p = -0.000200214257f;
    p = fmaf(p, w, 0.000100950558f);
    p = fmaf(p, w, 0.00134934322f);
    p = fmaf(p, w, -0.00367342844f);
    p = fmaf(p, w, 0.00573950773f);
    p = fmaf(p, w, -0.0076224613f);
    p = fmaf(p, w, 0.00943887047f);
    p = fmaf(p, w, 1.00167406f);
    p = fmaf(p, w, 2.83297682f);
  }
  return p * x;
}

// ---------------- K1: normalize primes -> Pt[k][64] (x10 temp folded, cols 50..63 zero) ----------------
__global__ __launch_bounds__(256) void kprep(const float* __restrict__ prime, float* __restrict__ Pt){
  int m = blockIdx.x;           // 0..49
  __shared__ float red[256];
  const float* pr = prime + (size_t)m*ND;
  float ss = 0.f;
  for (int k = threadIdx.x; k < ND; k += 256){ float v = pr[k]; ss = fmaf(v, v, ss); }
  red[threadIdx.x] = ss; __syncthreads();
  for (int s = 128; s > 0; s >>= 1){ if (threadIdx.x < s) red[threadIdx.x] += red[threadIdx.x + s]; __syncthreads(); }
  float scale = 10.0f / fmaxf(sqrtf(red[0]), 1e-12f);
  for (int k = threadIdx.x; k < ND; k += 256) Pt[k*64 + m] = pr[k] * scale;
  if (m == 0){
    for (int k = threadIdx.x; k < ND; k += 256)
      for (int j = 50; j < 64; j++) Pt[k*64 + j] = 0.f;
  }
}

// ---------------- K2: C = softmax over M of (x_hat . p_hat / T), 64 tokens/block ----------------
__global__ __launch_bounds__(256) void kC(const float* __restrict__ x, const float* __restrict__ Pt, float* __restrict__ C){
  int blk = blockIdx.x;                 // 512 = 8 * 64
  int b = blk >> 6, n0 = (blk & 63) << 6;
  int tid = threadIdx.x;
  int tok = tid & 63, mg = tid >> 6;    // wave-uniform mg
  __shared__ __align__(16) float ps[64*64];
  __shared__ __align__(16) float xs[64*65];
  __shared__ float S[64*52];
  __shared__ float sq[64][4];
  __shared__ float inorm[64];
  __shared__ float isum[64];
  float acc[16];
#pragma unroll
  for (int i = 0; i < 16; i++) acc[i] = 0.f;
  sq[tok][mg] = 0.f;
  const float* xb = x + ((size_t)(b*NN + n0))*ND;
  for (int kc = 0; kc < 16; kc++){
    int k0 = kc*64;
    __syncthreads();
    { // stage Pt chunk: contiguous 64x64
      const float* src = Pt + (size_t)k0*64;
      for (int i4 = tid; i4 < 1024; i4 += 256)
        *reinterpret_cast<float4*>(ps + i4*4) = *reinterpret_cast<const float4*>(src + i4*4);
    }
    { // stage x chunk 64 tok x 64 k (scalar LDS stores, stride 65)
      for (int i4 = tid; i4 < 1024; i4 += 256){
        int r = i4 >> 4, c4 = (i4 & 15) << 2;
        float4 v = *reinterpret_cast<const float4*>(xb + (size_t)r*ND + k0 + c4);
        float* dst = &xs[r*65 + c4];
        dst[0] = v.x; dst[1] = v.y; dst[2] = v.z; dst[3] = v.w;
      }
    }
    __syncthreads();
    { // per-token sumsq accumulation (16 elems per thread)
      const float* xr = &xs[tok*65 + mg*16];
      float s = 0.f;
#pragma unroll
      for (int j = 0; j < 16; j++){ float v = xr[j]; s = fmaf(v, v, s); }
      sq[tok][mg] += s;
    }
    for (int kk = 0; kk < 64; kk++){
      float xv = xs[tok*65 + kk];
      const float* pb = ps + kk*64 + (mg << 4);
#pragma unroll
      for (int q = 0; q < 4; q++){
        float4 pv = *reinterpret_cast<const float4*>(pb + q*4);
        acc[q*4+0] = fmaf(pv.x, xv, acc[q*4+0]);
        acc[q*4+1] = fmaf(pv.y, xv, acc[q*4+1]);
        acc[q*4+2] = fmaf(pv.z, xv, acc[q*4+2]);
        acc[q*4+3] = fmaf(pv.w, xv, acc[q*4+3]);
      }
    }
  }
  __syncthreads();
  if (tid < 64){
    float ss = sq[tid][0] + sq[tid][1] + sq[tid][2] + sq[tid][3];
    inorm[tid] = 1.0f / fmaxf(sqrtf(ss), 1e-12f);
  }
  __syncthreads();
  float inv = inorm[tok];
#pragma unroll
  for (int i = 0; i < 16; i++){
    int m = (mg << 4) + i;
    if (m < NM) S[tok*52 + m] = acc[i] * inv;
  }
  __syncthreads();
  if (tid < 64){
    float mx = -1e30f;
    for (int m = 0; m < NM; m++) mx = fmaxf(mx, S[tid*52 + m]);
    float sum = 0.f;
    for (int m = 0; m < NM; m++){ float e = expf(S[tid*52 + m] - mx); S[tid*52 + m] = e; sum += e; }
    isum[tid] = 1.0f / sum;
  }
  __syncthreads();
  float* Cb = C + ((size_t)(b*NN + n0))*NM;
  for (int idx = tid; idx < 64*NM; idx += 256){
    int r = idx / NM, m = idx - r*NM;
    Cb[idx] = S[r*52 + m] * isum[r];
  }
}

// ---------------- K3: H_prime partials: Hpart[b][kt][m][d] over n-chunks ----------------
__global__ __launch_bounds__(256) void kHp(const float* __restrict__ x, const float* __restrict__ C, float* __restrict__ Hpart){
  int blk = blockIdx.x;             // 512 = b(8) * dt(16) * kt(4)
  int kt = blk & 3, dt = (blk >> 2) & 15, b = blk >> 6;
  int d0 = dt*64;
  int tid = threadIdx.x;
  int d = tid & 63, mg = tid >> 6;
  __shared__ __align__(16) float Cs[64*64];
  __shared__ __align__(16) float xs[64*65];
  float acc[16];
#pragma unroll
  for (int i = 0; i < 16; i++) acc[i] = 0.f;
  const float* xb = x + ((size_t)(b*NN + kt*1024))*ND;
  const float* Cb = C + ((size_t)(b*NN + kt*1024))*NM;
  for (int nc = 0; nc < 16; nc++){
    int n0 = nc*64;
    __syncthreads();
    for (int idx = tid; idx < 4096; idx += 256){
      int r = idx >> 6, m = idx & 63;
      Cs[idx] = (m < NM) ? Cb[(size_t)(n0 + r)*NM + m] : 0.f;
    }
    for (int i4 = tid; i4 < 1024; i4 += 256){
      int r = i4 >> 4, c4 = (i4 & 15) << 2;
      float4 v = *reinterpret_cast<const float4*>(xb + (size_t)(n0 + r)*ND + d0 + c4);
      float* dst = &xs[r*65 + c4];
      dst[0] = v.x; dst[1] = v.y; dst[2] = v.z; dst[3] = v.w;
    }
    __syncthreads();
    for (int nn = 0; nn < 64; nn++){
      float xv = xs[nn*65 + d];
      const float* cb = Cs + nn*64 + (mg << 4);
#pragma unroll
      for (int q = 0; q < 4; q++){
        float4 cv = *reinterpret_cast<const float4*>(cb + q*4);
        acc[q*4+0] = fmaf(cv.x, xv, acc[q*4+0]);
        acc[q*4+1] = fmaf(cv.y, xv, acc[q*4+1]);
        acc[q*4+2] = fmaf(cv.z, xv, acc[q*4+2]);
        acc[q*4+3] = fmaf(cv.w, xv, acc[q*4+3]);
      }
    }
  }
#pragma unroll
  for (int i = 0; i < 16; i++){
    int m = (mg << 4) + i;
    if (m < NM) Hpart[(((size_t)b*4 + kt)*NM + m)*ND + d0 + d] = acc[i];
  }
}

// ---------------- K3b: reduce partials -> H ----------------
__global__ void kred(const float* __restrict__ Hpart, float* __restrict__ H){
  int e = blockIdx.x*256 + threadIdx.x;    // grid 1600 -> 409600
  int b = e / 51200; int rem = e - b*51200;
  const float* p = Hpart + (size_t)b*204800 + rem;
  H[e] = p[0] + p[51200] + p[102400] + p[153600];
}

// ---------------- K4a: Gram G[b] = H[b] H[b]^T ----------------
__global__ __launch_bounds__(256) void kgram(const float* __restrict__ H, float* __restrict__ G){
  int blk = blockIdx.x;         // 400 = b*50+i
  int b = blk / NM, i = blk - b*NM;
  __shared__ float Hi[ND];
  int tid = threadIdx.x;
  const float* Hb = H + (size_t)b*NM*ND;
  const float* hi = Hb + (size_t)i*ND;
  for (int k = tid; k < ND; k += 256) Hi[k] = hi[k];
  __syncthreads();
  int lane = tid & 63, w = tid >> 6;
  for (int j = w; j < NM; j += 4){
    const float* hj = Hb + (size_t)j*ND;
    float s = 0.f;
#pragma unroll
    for (int u = 0; u < 16; u++){ int k = lane + u*64; s = fmaf(Hi[k], hj[k], s); }
    for (int off = 1; off < 64; off <<= 1) s += __shfl_xor(s, off, 64);
    if (lane == 0) G[((size_t)b*NM + i)*NM + j] = s;
  }
}

// ---------------- K4b: Newton-Schulz inverse sqrt of G — boring rewrite ----------------
// Y0 = G/tr + eps*I  (eig in (0, 1+eps]); coupled NS:
//   T = 1.5I - 0.5*Z*Y ; Y <- Y*T ; Z <- T*Z   (plain row x col, no symmetry tricks)
// Wm = Z * rsqrt(tr) ~= invsqrt(G)
__global__ __launch_bounds__(512) void kns2(const float* __restrict__ G, float* __restrict__ Wm){
  int b = blockIdx.x;
  __shared__ float Yb[2][50*51];
  __shared__ float Zb2[2][50*51];
  __shared__ float Tm[50*51];
  __shared__ float sv[2];
  int tid = threadIdx.x;
  const float* Gb = G + (size_t)b*2500;
  if (tid < 64){
    float v = (tid < NM) ? Gb[tid*NM + tid] : 0.f;
    for (int off = 1; off < 64; off <<= 1) v += __shfl_xor(v, off, 64);
    if (tid == 0){ sv[0] = 1.0f / v; sv[1] = rsqrtf(v); }
  }
  __syncthreads();
  float rs = sv[0];
  for (int idx = tid; idx < 2500; idx += 512){
    int r = idx / 50, c = idx - r*50;
    Yb[0][r*51 + c] = Gb[idx] * rs + ((r == c) ? 2e-6f : 0.f);
    Zb2[0][r*51 + c] = (r == c) ? 1.f : 0.f;
  }
  __syncthreads();
  for (int it = 0; it < NS_ITERS; it++){
    int cur = it & 1;
    const float* Y = Yb[cur];
    const float* Z = Zb2[cur];
    float* Yn = Yb[cur ^ 1];
    float* Zn = Zb2[cur ^ 1];
    // phase 1: Tm = 1.5 I - 0.5 * (Z @ Y) ; 500 strips of (r, c0..c0+4)
    if (tid < 500){
      int r = tid / 10, c0 = (tid - (tid/10)*10) * 5;
      float s0=0.f, s1=0.f, s2=0.f, s3=0.f, s4=0.f;
      for (int k = 0; k < NM; k++){
        float a = Z[r*51 + k];
        const float* yk = &Y[k*51 + c0];
        s0 = fmaf(a, yk[0], s0);
        s1 = fmaf(a, yk[1], s1);
        s2 = fmaf(a, yk[2], s2);
        s3 = fmaf(a, yk[3], s3);
        s4 = fmaf(a, yk[4], s4);
      }
      float* tr_ = &Tm[r*51 + c0];
      tr_[0] = ((r == c0+0) ? 1.5f : 0.f) - 0.5f*s0;
      tr_[1] = ((r == c0+1) ? 1.5f : 0.f) - 0.5f*s1;
      tr_[2] = ((r == c0+2) ? 1.5f : 0.f) - 0.5f*s2;
      tr_[3] = ((r == c0+3) ? 1.5f : 0.f) - 0.5f*s3;
      tr_[4] = ((r == c0+4) ? 1.5f : 0.f) - 0.5f*s4;
    }
    __syncthreads();
    // phase 2: Yn = Y @ Tm ; Zn = Tm @ Z ; 1000 strips
    for (int st = tid; st < 1000; st += 512){
      int w2 = (st >= 500);
      int ii = w2 ? st - 500 : st;
      int r = ii / 10, c0 = (ii - (ii/10)*10) * 5;
      const float* A = w2 ? Tm : Y;
      const float* Bm = w2 ? Z : Tm;
      float* O = w2 ? Zn : Yn;
      float s0=0.f, s1=0.f, s2=0.f, s3=0.f, s4=0.f;
      for (int k = 0; k < NM; k++){
        float a = A[r*51 + k];
        const float* bk = &Bm[k*51 + c0];
        s0 = fmaf(a, bk[0], s0);
        s1 = fmaf(a, bk[1], s1);
        s2 = fmaf(a, bk[2], s2);
        s3 = fmaf(a, bk[3], s3);
        s4 = fmaf(a, bk[4], s4);
      }
      float* o = &O[r*51 + c0];
      o[0] = s0; o[1] = s1; o[2] = s2; o[3] = s3; o[4] = s4;
    }
    __syncthreads();
  }
  // NS_ITERS even -> final result sits in buffer 0
  float rss = sv[1];
  for (int idx = tid; idx < 2500; idx += 512){
    int r = idx / 50, c = idx - r*50;
    Wm[(size_t)b*2500 + idx] = Zb2[0][r*51 + c] * rss;
  }
}

// ---------------- K4c: H_logic = Wm @ H (true row x col; no symmetry assumption) ----------------
__global__ __launch_bounds__(256) void kapply(const float* __restrict__ H, const float* __restrict__ Wm, float* __restrict__ Zb){
  int blk = blockIdx.x;          // 128 = b(8) * dt(16)
  int dt = blk & 15, b = blk >> 4;
  int d0 = dt*64;
  int tid = threadIdx.x;
  int d = tid & 63, mg = tid >> 6;
  __shared__ __align__(16) float WsT[50*64];   // WsT[j*64 + m] = Wm[m][j]
  __shared__ float Hs[50*65];
  for (int idx = tid; idx < 3200; idx += 256){
    int j = idx >> 6, c = idx & 63;
    WsT[idx] = (c < NM) ? Wm[(size_t)b*2500 + c*NM + j] : 0.f;
  }
  for (int idx = tid; idx < 3200; idx += 256){
    int j = idx >> 6, c = idx & 63;
    Hs[j*65 + c] = H[((size_t)b*NM + j)*ND + d0 + c];
  }
  __syncthreads();
  float acc[16];
#pragma unroll
  for (int i = 0; i < 16; i++) acc[i] = 0.f;
  for (int j = 0; j < NM; j++){
    float hv = Hs[j*65 + d];
    const float* wb = WsT + j*64 + (mg << 4);
#pragma unroll
    for (int q = 0; q < 4; q++){
      float4 wv = *reinterpret_cast<const float4*>(wb + q*4);
      acc[q*4+0] = fmaf(wv.x, hv, acc[q*4+0]);
      acc[q*4+1] = fmaf(wv.y, hv, acc[q*4+1]);
      acc[q*4+2] = fmaf(wv.z, hv, acc[q*4+2]);
      acc[q*4+3] = fmaf(wv.w, hv, acc[q*4+3]);
    }
  }
#pragma unroll
  for (int i = 0; i < 16; i++){
    int m = (mg << 4) + i;
    if (m < NM) Zb[((size_t)b*NM + m)*ND + d0 + d] = acc[i];
  }
}

// ---------------- K4d: z += mask * (0.1 * normal)   [JAX threefry noise] ----------------
__global__ __launch_bounds__(256) void knoise(float* __restrict__ z){
  // keys computed in-kernel (compile-time foldable): split(key(42)) foldlike
  TFOut K1 = tf2x32(0u, 42u, 0u, 0u);
  TFOut K2 = tf2x32(0u, 42u, 0u, 1u);
  int e0 = (blockIdx.x*256 + threadIdx.x)*4;     // grid 400 -> 409600
  float4 v = *reinterpret_cast<float4*>(z + e0);
  float vv[4] = {v.x, v.y, v.z, v.w};
#pragma unroll
  for (int q = 0; q < 4; q++){
    uint32_t j = (uint32_t)(e0 + q);
    TFOut r1 = tf2x32(K1.a, K1.b, 0u, j);
    uint32_t bits = r1.a ^ r1.b;
    float u = __uint_as_float(0x3F800000u | (bits >> 9)) - 1.0f;
    if (u < 0.0464f){
      TFOut r2 = tf2x32(K2.a, K2.b, 0u, j);
      uint32_t nb = r2.a ^ r2.b;
      float w = __uint_as_float(0x3F800000u | (nb >> 9)) - 1.0f;
      const float lo = -0.99999994f;
      float un = fmaxf(lo, fmaf(w, 2.0f, lo));
      vv[q] += 0.1f * (1.4142135f * erfinv_f32(un));
    }
  }
  *reinterpret_cast<float4*>(z + e0) = make_float4(vv[0], vv[1], vv[2], vv[3]);
}

// ---------------- K5: h = gelu(z @ W1 + b1) ----------------
__global__ __launch_bounds__(256) void kmlp1(const float* __restrict__ Zb, const float* __restrict__ W1,
                                             const float* __restrict__ b1, float* __restrict__ Hh){
  int blk = blockIdx.x;            // 512 = b(8) * ct(64)
  int ct = blk & 63, b = blk >> 6;
  int c0 = ct*64;
  int tid = threadIdx.x;
  int d = tid & 63, rg = tid >> 6;
  __shared__ __align__(16) float zsT[64*64];     // [k][r], rows>=50 zero
  __shared__ float Ws[64*65];                    // [k][c]
  float acc[16];
#pragma unroll
  for (int i = 0; i < 16; i++) acc[i] = 0.f;
  for (int kc = 0; kc < 16; kc++){
    int k0 = kc*64;
    __syncthreads();
    for (int idx = tid; idx < 3200; idx += 256){
      int r = idx >> 6, c = idx & 63;
      zsT[c*64 + r] = Zb[((size_t)b*NM + r)*ND + k0 + c];
    }
    for (int idx = tid; idx < 64*14; idx += 256){
      int c = idx / 14, rr = idx - c*14;
      zsT[c*64 + 50 + rr] = 0.f;
    }
    for (int i4 = tid; i4 < 1024; i4 += 256){
      int r = i4 >> 4, c4 = (i4 & 15) << 2;
      float4 v = *reinterpret_cast<const float4*>(W1 + (size_t)(k0 + r)*NF + c0 + c4);
      float* dst = &Ws[r*65 + c4];
      dst[0] = v.x; dst[1] = v.y; dst[2] = v.z; dst[3] = v.w;
    }
    __syncthreads();
    for (int kk = 0; kk < 64; kk++){
      float wv = Ws[kk*65 + d];
      const float* zb = zsT + kk*64 + (rg << 4);
#pragma unroll
      for (int q = 0; q < 4; q++){
        float4 zv = *reinterpret_cast<const float4*>(zb + q*4);
        acc[q*4+0] = fmaf(zv.x, wv, acc[q*4+0]);
        acc[q*4+1] = fmaf(zv.y, wv, acc[q*4+1]);
        acc[q*4+2] = fmaf(zv.z, wv, acc[q*4+2]);
        acc[q*4+3] = fmaf(zv.w, wv, acc[q*4+3]);
      }
    }
  }
  float bias = b1[c0 + d];
#pragma unroll
  for (int i = 0; i < 16; i++){
    int r = (rg << 4) + i;
    if (r < NM){
      float v = acc[i] + bias;
      float g = 0.5f * v * (1.0f + erff(v * 0.70710678f));
      Hh[((size_t)b*NM + r)*NF + c0 + d] = g;
    }
  }
}

// ---------------- K6: partials of h @ W2 ----------------
__global__ __launch_bounds__(256) void kmlp2(const float* __restrict__ Hh, const float* __restrict__ W2, float* __restrict__ Hpart){
  int blk = blockIdx.x;            // 512 = b(8) * dt(16) * kt(4)
  int kt = blk & 3, dt = (blk >> 2) & 15, b = blk >> 6;
  int d0 = dt*64, kbase = kt*1024;
  int tid = threadIdx.x;
  int d = tid & 63, rg = tid >> 6;
  __shared__ __align__(16) float hsT[64*64];
  __shared__ float Ws[64*65];
  float acc[16];
#pragma unroll
  for (int i = 0; i < 16; i++) acc[i] = 0.f;
  for (int kc = 0; kc < 16; kc++){
    int k0 = kbase + kc*64;
    __syncthreads();
    for (int idx = tid; idx < 3200; idx += 256){
      int r = idx >> 6, c = idx & 63;
      hsT[c*64 + r] = Hh[((size_t)b*NM + r)*NF + k0 + c];
    }
    for (int idx = tid; idx < 64*14; idx += 256){
      int c = idx / 14, rr = idx - c*14;
      hsT[c*64 + 50 + rr] = 0.f;
    }
    for (int i4 = tid; i4 < 1024; i4 += 256){
      int r = i4 >> 4, c4 = (i4 & 15) << 2;
      float4 v = *reinterpret_cast<const float4*>(W2 + (size_t)(k0 + r)*ND + d0 + c4);
      float* dst = &Ws[r*65 + c4];
      dst[0] = v.x; dst[1] = v.y; dst[2] = v.z; dst[3] = v.w;
    }
    __syncthreads();
    for (int kk = 0; kk < 64; kk++){
      float wv = Ws[kk*65 + d];
      const float* hb = hsT + kk*64 + (rg << 4);
#pragma unroll
      for (int q = 0; q < 4; q++){
        float4 hv = *reinterpret_cast<const float4*>(hb + q*4);
        acc[q*4+0] = fmaf(hv.x, wv, acc[q*4+0]);
        acc[q*4+1] = fmaf(hv.y, wv, acc[q*4+1]);
        acc[q*4+2] = fmaf(hv.z, wv, acc[q*4+2]);
        acc[q*4+3] = fmaf(hv.w, wv, acc[q*4+3]);
      }
    }
  }
#pragma unroll
  for (int i = 0; i < 16; i++){
    int m = (rg << 4) + i;
    if (m < NM) Hpart[(((size_t)b*4 + kt)*NM + m)*ND + d0 + d] = acc[i];
  }
}

// ---------------- K6b: Hf = tanh(sum partials + b2) ----------------
__global__ void kred2(const float* __restrict__ Hpart, const float* __restrict__ b2, float* __restrict__ Hf){
  int e = blockIdx.x*256 + threadIdx.x;    // grid 1600
  int b = e / 51200; int rem = e - b*51200;
  int dcol = e & 1023;
  const float* p = Hpart + (size_t)b*204800 + rem;
  float s = p[0] + p[51200] + p[102400] + p[153600] + b2[dcol];
  Hf[e] = tanhf(s);
}

// ---------------- K7: out = x + C @ Hf ----------------
__global__ __launch_bounds__(256) void kdec(const float* __restrict__ x, const float* __restrict__ C,
                                            const float* __restrict__ Hf, float* __restrict__ out){
  int blk = blockIdx.x;            // 512 = b(8) * nt(64)
  int nt = blk & 63, b = blk >> 6;
  int n0 = nt*64;
  int tid = threadIdx.x;
  int d = tid & 63, ng = tid >> 6;
  __shared__ __align__(16) float CsT[50*68];    // [m][n]
  __shared__ float Hs[50*65];                   // [m][dcol]
  for (int idx = tid; idx < 3200; idx += 256){
    int n = idx / NM, m = idx - n*NM;
    CsT[m*68 + n] = C[((size_t)(b*NN + n0 + n))*NM + m];
  }
  __syncthreads();
  for (int dtile = 0; dtile < 16; dtile++){
    int d0 = dtile*64;
    __syncthreads();
    for (int idx = tid; idx < 3200; idx += 256){
      int m = idx >> 6, c = idx & 63;
      Hs[m*65 + c] = Hf[((size_t)b*NM + m)*ND + d0 + c];
    }
    __syncthreads();
    float acc[16];
#pragma unroll
    for (int i = 0; i < 16; i++) acc[i] = 0.f;
    for (int m = 0; m < NM; m++){
      float hv = Hs[m*65 + d];
      const float* cb = CsT + m*68 + (ng << 4);
#pragma unroll
      for (int q = 0; q < 4; q++){
        float4 cv = *reinterpret_cast<const float4*>(cb + q*4);
        acc[q*4+0] = fmaf(cv.x, hv, acc[q*4+0]);
        acc[q*4+1] = fmaf(cv.y, hv, acc[q*4+1]);
        acc[q*4+2] = fmaf(cv.z, hv, acc[q*4+2]);
        acc[q*4+3] = fmaf(cv.w, hv, acc[q*4+3]);
      }
    }
#pragma unroll
    for (int i = 0; i < 16; i++){
      int n = (ng << 4) + i;
      size_t o = ((size_t)(b*NN + n0 + n))*ND + d0 + d;
      out[o] = x[o] + acc[i];
    }
  }
}

// ---------------- launch ----------------
extern "C" void kernel_launch(void* const* d_in, const int* in_sizes, int n_in,
                              void* d_out, int out_size, void* d_ws, size_t ws_size,
                              hipStream_t stream) {
  (void)in_sizes; (void)n_in; (void)out_size;
  // workspace need: 6,249,536 floats = 24,998,144 bytes. If ws is smaller, bail
  // (out stays zero -> absmax ~5.4 signals ws_size was the problem).
  if (ws_size < (size_t)6249536 * 4) return;
  const float* x  = (const float*)d_in[0];
  const float* pn = (const float*)d_in[1];
  const float* W1 = (const float*)d_in[8];
  const float* b1 = (const float*)d_in[9];
  const float* W2 = (const float*)d_in[10];
  const float* b2 = (const float*)d_in[11];
  float* out = (float*)d_out;
  float* ws = (float*)d_ws;

  float* PT = ws;                 // 1024*64        = 65536
  float* C  = PT + 65536;         // 32768*50       = 1638400
  float* HP = C + 1638400;        // 8*4*50*1024    = 1638400 (reused by kmlp2)
  float* H  = HP + 1638400;       // 8*50*1024      = 409600
  float* G  = H + 409600;         // 8*50*50        = 20000
  float* WM = G + 20000;          // 8*50*50        = 20000
  float* ZB = WM + 20000;         // 8*50*1024      = 409600
  float* HH = ZB + 409600;        // 8*50*4096      = 1638400
  float* HF = HH + 1638400;       // 8*50*1024      = 409600

  hipLaunchKernelGGL(kprep,  dim3(50),   dim3(256), 0, stream, pn, PT);
  hipLaunchKernelGGL(kC,     dim3(512),  dim3(256), 0, stream, x, PT, C);
  hipLaunchKernelGGL(kHp,    dim3(512),  dim3(256), 0, stream, x, C, HP);
  hipLaunchKernelGGL(kred,   dim3(1600), dim3(256), 0, stream, HP, H);
  hipLaunchKernelGGL(kgram,  dim3(400),  dim3(256), 0, stream, H, G);
  hipLaunchKernelGGL(kns2,   dim3(8),    dim3(512), 0, stream, G, WM);
  hipLaunchKernelGGL(kapply, dim3(128),  dim3(256), 0, stream, H, WM, ZB);
  hipLaunchKernelGGL(knoise, dim3(400),  dim3(256), 0, stream, ZB);
  hipLaunchKernelGGL(kmlp1,  dim3(512),  dim3(256), 0, stream, ZB, W1, b1, HH);
  hipLaunchKernelGGL(kmlp2,  dim3(512),  dim3(256), 0, stream, HH, W2, HP);
  hipLaunchKernelGGL(kred2,  dim3(1600), dim3(256), 0, stream, HP, b2, HF);
  hipLaunchKernelGGL(kdec,   dim3(512),  dim3(256), 0, stream, x, C, HF, out);
}

// Round 3
// 530.616 us; speedup vs baseline: 1.9729x; 1.9729x over previous
//
#include <hip/hip_runtime.h>
#include <stdint.h>
#include <math.h>

#define NS_ITERS 26
#define PIT 72   // LDS row pitch in shorts (144B: 16B-aligned, bank-spread)

typedef unsigned short u16;
typedef __attribute__((ext_vector_type(8))) short short8;
typedef __attribute__((ext_vector_type(4))) float f32x4;

__device__ __forceinline__ u16 f2b(float f){
  unsigned u = __float_as_uint(f);
  unsigned r = (u + 0x7FFFu + ((u>>16)&1u)) >> 16;
  return (u16)r;
}
__device__ __forceinline__ float b2f(u16 h){ return __uint_as_float(((unsigned)h)<<16); }

// ---------------- threefry2x32 (JAX-compatible) ----------------
__host__ __device__ constexpr uint32_t rotl32(uint32_t v, int n){ return (v<<n)|(v>>(32-n)); }
struct TFOut { uint32_t a, b; };
__host__ __device__ constexpr TFOut tf2x32(uint32_t k0, uint32_t k1, uint32_t x0, uint32_t x1){
  uint32_t ks2 = k0 ^ k1 ^ 0x1BD11BDAu;
  x0 += k0; x1 += k1;
#define TFR(R) x0 += x1; x1 = rotl32(x1,(R)) ^ x0;
  TFR(13) TFR(15) TFR(26) TFR(6)
  x0 += k1; x1 += ks2 + 1u;
  TFR(17) TFR(29) TFR(16) TFR(24)
  x0 += ks2; x1 += k0 + 2u;
  TFR(13) TFR(15) TFR(26) TFR(6)
  x0 += k0; x1 += k1 + 3u;
  TFR(17) TFR(29) TFR(16) TFR(24)
  x0 += k1; x1 += ks2 + 4u;
  TFR(13) TFR(15) TFR(26) TFR(6)
  x0 += ks2; x1 += k0 + 5u;
#undef TFR
  return TFOut{x0, x1};
}

__device__ __forceinline__ float erfinv_f32(float x){
  float w = -log1pf(-x*x);
  float p;
  if (w < 5.0f) {
    w -= 2.5f;
    p = 2.81022636e-08f;
    p = fmaf(p, w, 3.43273939e-07f);
    p = fmaf(p, w, -3.5233877e-06f);
    p = fmaf(p, w, -4.39150654e-06f);
    p = fmaf(p, w, 0.00021858087f);
    p = fmaf(p, w, -0.00125372503f);
    p = fmaf(p, w, -0.00417768164f);
    p = fmaf(p, w, 0.246640727f);
    p = fmaf(p, w, 1.50140941f);
  } else {
    w = sqrtf(w) - 3.0f;
    p = -0.000200214257f;
    p = fmaf(p, w, 0.000100950558f);
    p = fmaf(p, w, 0.00134934322f);
    p = fmaf(p, w, -0.00367342844f);
    p = fmaf(p, w, 0.00573950773f);
    p = fmaf(p, w, -0.0076224613f);
    p = fmaf(p, w, 0.00943887047f);
    p = fmaf(p, w, 1.00167406f);
    p = fmaf(p, w, 2.83297682f);
  }
  return p * x;
}

// ---------------- K1: primes -> PT bf16 [64][1024], unit-normalized, rows>=50 zero ----
__global__ __launch_bounds__(256) void kprep(const float* __restrict__ prime, u16* __restrict__ PT){
  int m = blockIdx.x;
  u16* dst = PT + m*1024;
  if (m >= 50){ for (int k = threadIdx.x; k < 1024; k += 256) dst[k] = 0; return; }
  __shared__ float red[256];
  const float* pr = prime + m*1024;
  float ss = 0.f;
  for (int k = threadIdx.x; k < 1024; k += 256){ float v = pr[k]; ss = fmaf(v,v,ss); }
  red[threadIdx.x] = ss; __syncthreads();
  for (int s = 128; s > 0; s >>= 1){ if (threadIdx.x < s) red[threadIdx.x] += red[threadIdx.x+s]; __syncthreads(); }
  float sc = 1.0f / fmaxf(sqrtf(red[0]), 1e-12f);
  for (int k = threadIdx.x; k < 1024; k += 256) dst[k] = f2b(pr[k]*sc);
}

// ---------------- K2: MFMA logits + softmax -> C[n][64] bf16 and CT[m][4096n] bf16 ----
__global__ __launch_bounds__(256) void kC(const float* __restrict__ x, const u16* __restrict__ PT,
                                          u16* __restrict__ C, u16* __restrict__ CT){
  int blk = blockIdx.x; int b = blk>>6, n0 = (blk&63)<<6;
  int tid = threadIdx.x, lane = tid&63, w = tid>>6;
  __shared__ __align__(16) u16 xs[64*PIT];
  __shared__ __align__(16) u16 ps[64*PIT];
  __shared__ float sq[64][5];
  f32x4 acc[4] = {{0,0,0,0},{0,0,0,0},{0,0,0,0},{0,0,0,0}};
  float sqa = 0.f;
  int stok = tid>>2, sseg = tid&3;                 // staging map
  int qtok = tid&63, qg = tid>>6;                  // sumsq map
  const float* xb = x + ((size_t)(b*4096 + n0))*1024;
  for (int kc = 0; kc < 16; kc++){
    int k0 = kc*64;
    __syncthreads();
    { // stage x (cvt bf16): 16 f32 per thread
      const float* src = xb + (size_t)stok*1024 + k0 + sseg*16;
      u16* d = &xs[stok*PIT + sseg*16];
#pragma unroll
      for (int i = 0; i < 4; i++){
        float4 v = *reinterpret_cast<const float4*>(src + i*4);
        d[i*4+0]=f2b(v.x); d[i*4+1]=f2b(v.y); d[i*4+2]=f2b(v.z); d[i*4+3]=f2b(v.w);
      }
    }
    { // stage P rows
      const u16* src = PT + (size_t)stok*1024 + k0 + sseg*16;
      *reinterpret_cast<uint4*>(&ps[stok*PIT + sseg*16])   = *reinterpret_cast<const uint4*>(src);
      *reinterpret_cast<uint4*>(&ps[stok*PIT + sseg*16+8]) = *reinterpret_cast<const uint4*>(src+8);
    }
    __syncthreads();
    { // sumsq of this token's 16 values
      const u16* xr = &xs[qtok*PIT + qg*16];
#pragma unroll
      for (int j = 0; j < 16; j++){ float v = b2f(xr[j]); sqa = fmaf(v,v,sqa); }
    }
#pragma unroll
    for (int s = 0; s < 2; s++){
      short8 a = *reinterpret_cast<const short8*>(&xs[(16*w + (lane&15))*PIT + s*32 + (lane>>4)*8]);
#pragma unroll
      for (int t = 0; t < 4; t++){
        short8 bb = *reinterpret_cast<const short8*>(&ps[(t*16 + (lane&15))*PIT + s*32 + (lane>>4)*8]);
        acc[t] = __builtin_amdgcn_mfma_f32_16x16x32_bf16(a, bb, acc[t], 0, 0, 0);
      }
    }
  }
  sq[qtok][qg] = sqa;
  __syncthreads();
  if (tid < 64){
    float ss = sq[tid][0]+sq[tid][1]+sq[tid][2]+sq[tid][3];
    sq[tid][4] = 10.0f / fmaxf(sqrtf(ss), 1e-12f);
  }
  __syncthreads();
  // softmax per token (rows spread over lane>>4 groups; primes = lane&15 + 16*t)
  u16* cl = xs;  // reuse
#pragma unroll
  for (int r = 0; r < 4; r++){
    int gt = 16*w + (lane>>4)*4 + r;
    float scale = sq[gt][4];
    float v[4];
#pragma unroll
    for (int t = 0; t < 4; t++) v[t] = acc[t][r] * scale;
    if ((lane&15) >= 2) v[3] = -1e30f;
    float mx = fmaxf(fmaxf(v[0],v[1]), fmaxf(v[2],v[3]));
#pragma unroll
    for (int off = 1; off < 16; off <<= 1) mx = fmaxf(mx, __shfl_xor(mx, off, 64));
    float e[4], sum = 0.f;
#pragma unroll
    for (int t = 0; t < 4; t++){ e[t] = __expf(v[t]-mx); sum += e[t]; }
#pragma unroll
    for (int off = 1; off < 16; off <<= 1) sum += __shfl_xor(sum, off, 64);
    float inv = 1.0f / sum;
#pragma unroll
    for (int t = 0; t < 4; t++) cl[gt*PIT + t*16 + (lane&15)] = f2b(e[t]*inv);
  }
  __syncthreads();
  { // C write (row-major) b128
    u16* dst = C + ((size_t)(b*4096 + n0 + stok))*64 + sseg*16;
    *reinterpret_cast<uint4*>(dst)   = *reinterpret_cast<const uint4*>(&cl[stok*PIT + sseg*16]);
    *reinterpret_cast<uint4*>(dst+8) = *reinterpret_cast<const uint4*>(&cl[stok*PIT + sseg*16+8]);
  }
  { // CT write (transposed)
    int m = tid>>2, nseg = tid&3;
    unsigned vs[8];
#pragma unroll
    for (int j = 0; j < 8; j++){
      u16 lo = cl[(nseg*16 + 2*j)*PIT + m];
      u16 hi = cl[(nseg*16 + 2*j+1)*PIT + m];
      vs[j] = (unsigned)lo | ((unsigned)hi<<16);
    }
    u16* dst = CT + ((size_t)(b*64 + m))*4096 + n0 + nseg*16;
    uint4 w0; w0.x=vs[0]; w0.y=vs[1]; w0.z=vs[2]; w0.w=vs[3];
    uint4 w1; w1.x=vs[4]; w1.y=vs[5]; w1.z=vs[6]; w1.w=vs[7];
    *reinterpret_cast<uint4*>(dst)   = w0;
    *reinterpret_cast<uint4*>(dst+8) = w1;
  }
}

// ---------------- K3: H_prime = CT @ x  (MFMA, x transposed in staging) ----------------
__global__ __launch_bounds__(256) void kHp(const float* __restrict__ x, const u16* __restrict__ CT,
                                           float* __restrict__ H, u16* __restrict__ Hb){
  int blk = blockIdx.x; int b = blk>>4, dt = blk&15, d0 = dt*64;
  int tid = threadIdx.x, lane = tid&63, w = tid>>6;
  __shared__ __align__(16) u16 cs[64*PIT];    // [m][n]
  __shared__ __align__(16) u16 xt[64*PIT];    // [d][n]
  f32x4 acc[4] = {{0,0,0,0},{0,0,0,0},{0,0,0,0},{0,0,0,0}};
  int nn = tid>>2, seg = tid&3;
  for (int nc = 0; nc < 64; nc++){
    int n0 = nc*64;
    __syncthreads();
    { // stage CT rows [m][n-chunk]
      const u16* src = CT + ((size_t)(b*64 + nn))*4096 + n0 + seg*16;  // nn = m here
      *reinterpret_cast<uint4*>(&cs[nn*PIT + seg*16])   = *reinterpret_cast<const uint4*>(src);
      *reinterpret_cast<uint4*>(&cs[nn*PIT + seg*16+8]) = *reinterpret_cast<const uint4*>(src+8);
    }
    { // stage x transposed: read [n][d] f32, write [d][n] bf16
      const float* src = x + ((size_t)(b*4096 + n0 + nn))*1024 + d0 + seg*16;
#pragma unroll
      for (int i = 0; i < 4; i++){
        float4 v = *reinterpret_cast<const float4*>(src + i*4);
        xt[(seg*16 + i*4+0)*PIT + nn] = f2b(v.x);
        xt[(seg*16 + i*4+1)*PIT + nn] = f2b(v.y);
        xt[(seg*16 + i*4+2)*PIT + nn] = f2b(v.z);
        xt[(seg*16 + i*4+3)*PIT + nn] = f2b(v.w);
      }
    }
    __syncthreads();
#pragma unroll
    for (int s = 0; s < 2; s++){
      short8 a = *reinterpret_cast<const short8*>(&cs[(16*w + (lane&15))*PIT + s*32 + (lane>>4)*8]);
#pragma unroll
      for (int t = 0; t < 4; t++){
        short8 bb = *reinterpret_cast<const short8*>(&xt[(t*16 + (lane&15))*PIT + s*32 + (lane>>4)*8]);
        acc[t] = __builtin_amdgcn_mfma_f32_16x16x32_bf16(a, bb, acc[t], 0, 0, 0);
      }
    }
  }
#pragma unroll
  for (int t = 0; t < 4; t++)
#pragma unroll
    for (int r = 0; r < 4; r++){
      int m = 16*w + (lane>>4)*4 + r;
      int d = d0 + t*16 + (lane&15);
      size_t o = ((size_t)(b*64 + m))*1024 + d;
      H[o] = acc[t][r];
      Hb[o] = f2b(acc[t][r]);
    }
}

// ---------------- K4a: Gram via MFMA: G = Hb Hb^T ----------------
__global__ __launch_bounds__(256) void kgram(const u16* __restrict__ Hb, float* __restrict__ G){
  int b = blockIdx.x;
  int tid = threadIdx.x, lane = tid&63, w = tid>>6;
  __shared__ __align__(16) u16 hs[64*PIT];
  f32x4 acc[4] = {{0,0,0,0},{0,0,0,0},{0,0,0,0},{0,0,0,0}};
  int m = tid>>2, seg = tid&3;
  for (int kc = 0; kc < 16; kc++){
    int k0 = kc*64;
    __syncthreads();
    const u16* src = Hb + ((size_t)(b*64 + m))*1024 + k0 + seg*16;
    *reinterpret_cast<uint4*>(&hs[m*PIT + seg*16])   = *reinterpret_cast<const uint4*>(src);
    *reinterpret_cast<uint4*>(&hs[m*PIT + seg*16+8]) = *reinterpret_cast<const uint4*>(src+8);
    __syncthreads();
#pragma unroll
    for (int s = 0; s < 2; s++){
      short8 a = *reinterpret_cast<const short8*>(&hs[(16*w + (lane&15))*PIT + s*32 + (lane>>4)*8]);
#pragma unroll
      for (int t = 0; t < 4; t++){
        short8 bb = *reinterpret_cast<const short8*>(&hs[(t*16 + (lane&15))*PIT + s*32 + (lane>>4)*8]);
        acc[t] = __builtin_amdgcn_mfma_f32_16x16x32_bf16(a, bb, acc[t], 0, 0, 0);
      }
    }
  }
#pragma unroll
  for (int t = 0; t < 4; t++)
#pragma unroll
    for (int r = 0; r < 4; r++){
      int i = 16*w + (lane>>4)*4 + r;
      int j = t*16 + (lane&15);
      if (i < 50 && j < 50) G[(size_t)b*2500 + i*50 + j] = acc[t][r];
    }
}

// ---------------- K4b: Newton-Schulz invsqrt, 5x5 register tiles, unrolled ----------------
__global__ __launch_bounds__(256) void kns2(const float* __restrict__ G, float* __restrict__ Wm){
  int b = blockIdx.x;
  __shared__ float Yb[2][50*51];
  __shared__ float Zb2[2][50*51];
  __shared__ float Tm[50*51];
  __shared__ float sv[2];
  int tid = threadIdx.x;
  const float* Gb = G + (size_t)b*2500;
  if (tid < 64){
    float v = (tid < 50) ? Gb[tid*50 + tid] : 0.f;
    for (int off = 1; off < 64; off <<= 1) v += __shfl_xor(v, off, 64);
    if (tid == 0){ sv[0] = 1.0f / v; sv[1] = rsqrtf(v); }
  }
  __syncthreads();
  float rs = sv[0];
  for (int idx = tid; idx < 2500; idx += 256){
    int r = idx/50, c = idx - r*50;
    Yb[0][r*51+c] = Gb[idx]*rs + ((r==c) ? 2e-6f : 0.f);
    Zb2[0][r*51+c] = (r==c) ? 1.f : 0.f;
  }
  __syncthreads();
  for (int it = 0; it < NS_ITERS; it++){
    int cur = it & 1;
    const float* Y = Yb[cur];
    const float* Z = Zb2[cur];
    float* Yn = Yb[cur^1];
    float* Zn = Zb2[cur^1];
    if (tid < 100){
      int r0 = (tid/10)*5, c0 = (tid - (tid/10)*10)*5;
      float a[5][5] = {};
#pragma unroll
      for (int k = 0; k < 50; k++){
        float zr[5], yc[5];
#pragma unroll
        for (int i = 0; i < 5; i++){ zr[i] = Z[(r0+i)*51+k]; yc[i] = Y[k*51+c0+i]; }
#pragma unroll
        for (int i = 0; i < 5; i++)
#pragma unroll
          for (int j = 0; j < 5; j++) a[i][j] = fmaf(zr[i], yc[j], a[i][j]);
      }
#pragma unroll
      for (int i = 0; i < 5; i++)
#pragma unroll
        for (int j = 0; j < 5; j++){
          int r = r0+i, c = c0+j;
          Tm[r*51+c] = ((r==c) ? 1.5f : 0.f) - 0.5f*a[i][j];
        }
    }
    __syncthreads();
    if (tid < 200){
      int w2 = tid >= 100;
      int tt = w2 ? tid-100 : tid;
      int r0 = (tt/10)*5, c0 = (tt - (tt/10)*10)*5;
      const float* A = w2 ? Tm : Y;
      const float* Bm = w2 ? Z : Tm;
      float* O = w2 ? Zn : Yn;
      float a[5][5] = {};
#pragma unroll
      for (int k = 0; k < 50; k++){
        float ar[5], bc[5];
#pragma unroll
        for (int i = 0; i < 5; i++){ ar[i] = A[(r0+i)*51+k]; bc[i] = Bm[k*51+c0+i]; }
#pragma unroll
        for (int i = 0; i < 5; i++)
#pragma unroll
          for (int j = 0; j < 5; j++) a[i][j] = fmaf(ar[i], bc[j], a[i][j]);
      }
#pragma unroll
      for (int i = 0; i < 5; i++)
#pragma unroll
        for (int j = 0; j < 5; j++) O[(r0+i)*51 + c0+j] = a[i][j];
    }
    __syncthreads();
  }
  float rss = sv[1];
  for (int idx = tid; idx < 2500; idx += 256){
    int r = idx/50, c = idx - r*50;
    Wm[(size_t)b*2500 + idx] = Zb2[0][r*51+c]*rss;
  }
}

// ---------------- K4c: H_logic = Wm @ H (fp32 VALU) ----------------
__global__ __launch_bounds__(256) void kapply(const float* __restrict__ H, const float* __restrict__ Wm, float* __restrict__ Zb){
  int blk = blockIdx.x;          // 128 = b(8) * dt(16)
  int dt = blk & 15, b = blk >> 4;
  int d0 = dt*64;
  int tid = threadIdx.x;
  int d = tid & 63, mg = tid >> 6;
  __shared__ __align__(16) float WsT[50*64];
  __shared__ float Hs[50*65];
  for (int idx = tid; idx < 3200; idx += 256){
    int j = idx >> 6, c = idx & 63;
    WsT[idx] = (c < 50) ? Wm[(size_t)b*2500 + c*50 + j] : 0.f;
  }
  for (int idx = tid; idx < 3200; idx += 256){
    int j = idx >> 6, c = idx & 63;
    Hs[j*65 + c] = H[((size_t)(b*64) + j)*1024 + d0 + c];
  }
  __syncthreads();
  float acc[16];
#pragma unroll
  for (int i = 0; i < 16; i++) acc[i] = 0.f;
  for (int j = 0; j < 50; j++){
    float hv = Hs[j*65 + d];
    const float* wb = WsT + j*64 + (mg << 4);
#pragma unroll
    for (int q = 0; q < 4; q++){
      float4 wv = *reinterpret_cast<const float4*>(wb + q*4);
      acc[q*4+0] = fmaf(wv.x, hv, acc[q*4+0]);
      acc[q*4+1] = fmaf(wv.y, hv, acc[q*4+1]);
      acc[q*4+2] = fmaf(wv.z, hv, acc[q*4+2]);
      acc[q*4+3] = fmaf(wv.w, hv, acc[q*4+3]);
    }
  }
#pragma unroll
  for (int i = 0; i < 16; i++){
    int m = (mg << 4) + i;
    if (m < 50) Zb[((size_t)(b*50) + m)*1024 + d0 + d] = acc[i];
  }
}

// ---------------- K4d: noise (threefry) on ZB; emit ZbB bf16 padded ----------------
__global__ __launch_bounds__(256) void knoise(float* __restrict__ z, u16* __restrict__ zb){
  TFOut K1 = tf2x32(0u, 42u, 0u, 0u);
  TFOut K2 = tf2x32(0u, 42u, 0u, 1u);
  int e0 = (blockIdx.x*256 + threadIdx.x)*4;    // over 8*64*1024
  int b = e0 >> 16, rem = e0 & 65535;
  int m = rem >> 10, d = rem & 1023;
  u16* zdst = zb + ((size_t)(b*64 + m))*1024 + d;
  if (m >= 50){
    uint2 zz; zz.x = 0; zz.y = 0;
    *reinterpret_cast<uint2*>(zdst) = zz;
    return;
  }
  size_t zoff = ((size_t)(b*50 + m))*1024 + d;
  float4 v = *reinterpret_cast<float4*>(z + zoff);
  float vv[4] = {v.x, v.y, v.z, v.w};
  uint32_t jbase = (uint32_t)zoff;
#pragma unroll
  for (int q = 0; q < 4; q++){
    uint32_t j = jbase + q;
    TFOut r1 = tf2x32(K1.a, K1.b, 0u, j);
    uint32_t bits = r1.a ^ r1.b;
    float u = __uint_as_float(0x3F800000u | (bits >> 9)) - 1.0f;
    if (u < 0.0464f){
      TFOut r2 = tf2x32(K2.a, K2.b, 0u, j);
      uint32_t nb = r2.a ^ r2.b;
      float ww = __uint_as_float(0x3F800000u | (nb >> 9)) - 1.0f;
      const float lo = -0.99999994f;
      float un = fmaxf(lo, fmaf(ww, 2.0f, lo));
      vv[q] += 0.1f * (1.4142135f * erfinv_f32(un));
    }
  }
  *reinterpret_cast<float4*>(z + zoff) = make_float4(vv[0], vv[1], vv[2], vv[3]);
  uint2 zz;
  zz.x = (unsigned)f2b(vv[0]) | ((unsigned)f2b(vv[1])<<16);
  zz.y = (unsigned)f2b(vv[2]) | ((unsigned)f2b(vv[3])<<16);
  *reinterpret_cast<uint2*>(zdst) = zz;
}

// ---------------- K5: Hh = gelu(ZbB @ W1 + b1) (MFMA; W1 transpose-staged) ----------------
__global__ __launch_bounds__(256) void kmlp1(const u16* __restrict__ ZbB, const float* __restrict__ W1,
                                             const float* __restrict__ b1, u16* __restrict__ Hh){
  int blk = blockIdx.x; int b = blk>>6, c0 = (blk&63)<<6;
  int tid = threadIdx.x, lane = tid&63, w = tid>>6;
  __shared__ __align__(16) u16 az[64*PIT];   // [m][k]
  __shared__ __align__(16) u16 wt[64*PIT];   // [n][k]
  f32x4 acc[4] = {{0,0,0,0},{0,0,0,0},{0,0,0,0},{0,0,0,0}};
  int rr = tid>>2, seg = tid&3;
  for (int kc = 0; kc < 16; kc++){
    int k0 = kc*64;
    __syncthreads();
    { // stage A (ZbB rows)
      const u16* src = ZbB + ((size_t)(b*64 + rr))*1024 + k0 + seg*16;
      *reinterpret_cast<uint4*>(&az[rr*PIT + seg*16])   = *reinterpret_cast<const uint4*>(src);
      *reinterpret_cast<uint4*>(&az[rr*PIT + seg*16+8]) = *reinterpret_cast<const uint4*>(src+8);
    }
    { // stage W1 transposed: read [k][n] f32 -> wt[n][k] bf16
      const float* src = W1 + ((size_t)(k0 + rr))*4096 + c0 + seg*16;  // rr = kk
#pragma unroll
      for (int i = 0; i < 4; i++){
        float4 v = *reinterpret_cast<const float4*>(src + i*4);
        wt[(seg*16 + i*4+0)*PIT + rr] = f2b(v.x);
        wt[(seg*16 + i*4+1)*PIT + rr] = f2b(v.y);
        wt[(seg*16 + i*4+2)*PIT + rr] = f2b(v.z);
        wt[(seg*16 + i*4+3)*PIT + rr] = f2b(v.w);
      }
    }
    __syncthreads();
#pragma unroll
    for (int s = 0; s < 2; s++){
      short8 a = *reinterpret_cast<const short8*>(&az[(16*w + (lane&15))*PIT + s*32 + (lane>>4)*8]);
#pragma unroll
      for (int t = 0; t < 4; t++){
        short8 bb = *reinterpret_cast<const short8*>(&wt[(t*16 + (lane&15))*PIT + s*32 + (lane>>4)*8]);
        acc[t] = __builtin_amdgcn_mfma_f32_16x16x32_bf16(a, bb, acc[t], 0, 0, 0);
      }
    }
  }
#pragma unroll
  for (int t = 0; t < 4; t++)
#pragma unroll
    for (int r = 0; r < 4; r++){
      int m = 16*w + (lane>>4)*4 + r;
      int n = c0 + t*16 + (lane&15);
      float val = acc[t][r] + b1[n];
      float g = 0.5f * val * (1.0f + erff(val * 0.70710678f));
      Hh[((size_t)(b*64 + m))*4096 + n] = (m < 50) ? f2b(g) : (u16)0;
    }
}

// ---------------- K6: HfT = tanh(Hh @ W2 + b2)^T (MFMA; W2 transpose-staged; LDS transpose out) ----
__global__ __launch_bounds__(256) void kmlp2(const u16* __restrict__ Hh, const float* __restrict__ W2,
                                             const float* __restrict__ b2, u16* __restrict__ HfT){
  int blk = blockIdx.x; int b = blk>>4, dt = blk&15, d0 = dt*64;
  int tid = threadIdx.x, lane = tid&63, w = tid>>6;
  __shared__ __align__(16) u16 az[64*PIT];
  __shared__ __align__(16) u16 wt[64*PIT];
  f32x4 acc[4] = {{0,0,0,0},{0,0,0,0},{0,0,0,0},{0,0,0,0}};
  int rr = tid>>2, seg = tid&3;
  for (int kc = 0; kc < 64; kc++){
    int k0 = kc*64;
    __syncthreads();
    {
      const u16* src = Hh + ((size_t)(b*64 + rr))*4096 + k0 + seg*16;
      *reinterpret_cast<uint4*>(&az[rr*PIT + seg*16])   = *reinterpret_cast<const uint4*>(src);
      *reinterpret_cast<uint4*>(&az[rr*PIT + seg*16+8]) = *reinterpret_cast<const uint4*>(src+8);
    }
    {
      const float* src = W2 + ((size_t)(k0 + rr))*1024 + d0 + seg*16;
#pragma unroll
      for (int i = 0; i < 4; i++){
        float4 v = *reinterpret_cast<const float4*>(src + i*4);
        wt[(seg*16 + i*4+0)*PIT + rr] = f2b(v.x);
        wt[(seg*16 + i*4+1)*PIT + rr] = f2b(v.y);
        wt[(seg*16 + i*4+2)*PIT + rr] = f2b(v.z);
        wt[(seg*16 + i*4+3)*PIT + rr] = f2b(v.w);
      }
    }
    __syncthreads();
#pragma unroll
    for (int s = 0; s < 2; s++){
      short8 a = *reinterpret_cast<const short8*>(&az[(16*w + (lane&15))*PIT + s*32 + (lane>>4)*8]);
#pragma unroll
      for (int t = 0; t < 4; t++){
        short8 bb = *reinterpret_cast<const short8*>(&wt[(t*16 + (lane&15))*PIT + s*32 + (lane>>4)*8]);
        acc[t] = __builtin_amdgcn_mfma_f32_16x16x32_bf16(a, bb, acc[t], 0, 0, 0);
      }
    }
  }
  __syncthreads();
  // write tanh result transposed into LDS: cl[d_local][m]
  u16* cl = az;
#pragma unroll
  for (int t = 0; t < 4; t++)
#pragma unroll
    for (int r = 0; r < 4; r++){
      int m = 16*w + (lane>>4)*4 + r;
      int dl = t*16 + (lane&15);
      float val = tanhf(acc[t][r] + b2[d0 + dl]);
      cl[dl*PIT + m] = (m < 50) ? f2b(val) : (u16)0;
    }
  __syncthreads();
  {
    const u16* srow = &cl[rr*PIT + seg*16];  // rr = d_local
    u16* dst = HfT + ((size_t)(b*1024 + d0 + rr))*64 + seg*16;
    *reinterpret_cast<uint4*>(dst)   = *reinterpret_cast<const uint4*>(srow);
    *reinterpret_cast<uint4*>(dst+8) = *reinterpret_cast<const uint4*>(srow+8);
  }
}

// ---------------- K7: out = x + C @ Hf (MFMA) ----------------
__global__ __launch_bounds__(256) void kdec(const float* __restrict__ x, const u16* __restrict__ C,
                                            const u16* __restrict__ HfT, float* __restrict__ out){
  int blk = blockIdx.x; int b = blk>>6, n0 = (blk&63)<<6;
  int tid = threadIdx.x, lane = tid&63, w = tid>>6;
  __shared__ __align__(16) u16 ctile[64*PIT];   // [tok][m]
  __shared__ __align__(16) u16 htile[64*PIT];   // [d][m]
  int rr = tid>>2, seg = tid&3;
  {
    const u16* src = C + ((size_t)(b*4096 + n0 + rr))*64 + seg*16;
    *reinterpret_cast<uint4*>(&ctile[rr*PIT + seg*16])   = *reinterpret_cast<const uint4*>(src);
    *reinterpret_cast<uint4*>(&ctile[rr*PIT + seg*16+8]) = *reinterpret_cast<const uint4*>(src+8);
  }
  __syncthreads();
  short8 afrag[2];
#pragma unroll
  for (int s = 0; s < 2; s++)
    afrag[s] = *reinterpret_cast<const short8*>(&ctile[(16*w + (lane&15))*PIT + s*32 + (lane>>4)*8]);
  for (int dt2 = 0; dt2 < 16; dt2++){
    int d0 = dt2*64;
    __syncthreads();
    {
      const u16* src = HfT + ((size_t)(b*1024 + d0 + rr))*64 + seg*16;
      *reinterpret_cast<uint4*>(&htile[rr*PIT + seg*16])   = *reinterpret_cast<const uint4*>(src);
      *reinterpret_cast<uint4*>(&htile[rr*PIT + seg*16+8]) = *reinterpret_cast<const uint4*>(src+8);
    }
    __syncthreads();
    f32x4 acc[4] = {{0,0,0,0},{0,0,0,0},{0,0,0,0},{0,0,0,0}};
#pragma unroll
    for (int s = 0; s < 2; s++){
#pragma unroll
      for (int t = 0; t < 4; t++){
        short8 bb = *reinterpret_cast<const short8*>(&htile[(t*16 + (lane&15))*PIT + s*32 + (lane>>4)*8]);
        acc[t] = __builtin_amdgcn_mfma_f32_16x16x32_bf16(afrag[s], bb, acc[t], 0, 0, 0);
      }
    }
#pragma unroll
    for (int t = 0; t < 4; t++)
#pragma unroll
      for (int r = 0; r < 4; r++){
        int n = n0 + 16*w + (lane>>4)*4 + r;
        int d = d0 + t*16 + (lane&15);
        size_t o = ((size_t)(b*4096 + n))*1024 + d;
        out[o] = x[o] + acc[t][r];
      }
  }
}

// ---------------- launch ----------------
extern "C" void kernel_launch(void* const* d_in, const int* in_sizes, int n_in,
                              void* d_out, int out_size, void* d_ws, size_t ws_size,
                              hipStream_t stream) {
  (void)in_sizes; (void)n_in; (void)out_size;
  if (ws_size < (size_t)19755264) return;
  const float* x  = (const float*)d_in[0];
  const float* pn = (const float*)d_in[1];
  const float* W1 = (const float*)d_in[8];
  const float* b1 = (const float*)d_in[9];
  const float* W2 = (const float*)d_in[10];
  const float* b2 = (const float*)d_in[11];
  float* out = (float*)d_out;
  char* ws = (char*)d_ws;

  u16*   C   = (u16*)(ws);                      // 4,194,304 B
  u16*   CT  = (u16*)(ws + 4194304);            // 4,194,304 B
  u16*   Hh  = (u16*)(ws + 8388608);            // 4,194,304 B
  float* H   = (float*)(ws + 12582912);         // 2,097,152 B
  float* ZB  = (float*)(ws + 14680064);         // 1,638,400 B
  u16*   ZbB = (u16*)(ws + 16318464);           // 1,048,576 B
  u16*   HfT = (u16*)(ws + 17367040);           // 1,048,576 B
  u16*   Hb  = (u16*)(ws + 18415616);           // 1,048,576 B
  u16*   PT  = (u16*)(ws + 19464192);           //   131,072 B
  float* G   = (float*)(ws + 19595264);         //    80,000 B
  float* WM  = (float*)(ws + 19675264);         //    80,000 B

  hipLaunchKernelGGL(kprep,  dim3(64),  dim3(256), 0, stream, pn, PT);
  hipLaunchKernelGGL(kC,     dim3(512), dim3(256), 0, stream, x, PT, C, CT);
  hipLaunchKernelGGL(kHp,    dim3(128), dim3(256), 0, stream, x, CT, H, Hb);
  hipLaunchKernelGGL(kgram,  dim3(8),   dim3(256), 0, stream, Hb, G);
  hipLaunchKernelGGL(kns2,   dim3(8),   dim3(256), 0, stream, G, WM);
  hipLaunchKernelGGL(kapply, dim3(128), dim3(256), 0, stream, H, WM, ZB);
  hipLaunchKernelGGL(knoise, dim3(512), dim3(256), 0, stream, ZB, ZbB);
  hipLaunchKernelGGL(kmlp1,  dim3(512), dim3(256), 0, stream, ZbB, W1, b1, Hh);
  hipLaunchKernelGGL(kmlp2,  dim3(128), dim3(256), 0, stream, Hh, W2, b2, HfT);
  hipLaunchKernelGGL(kdec,   dim3(512), dim3(256), 0, stream, x, C, HfT, out);
}

// Round 4
// 426.784 us; speedup vs baseline: 2.4529x; 1.2433x over previous
//
#include <hip/hip_runtime.h>
#include <stdint.h>
#include <math.h>

#define NS_ITERS 26
#define PIT 72   // LDS row pitch in shorts (144B: 16B-aligned, bank-spread)
#define P2  72   // pitch for kns3 matrices

typedef unsigned short u16;
typedef __attribute__((ext_vector_type(8))) short short8;
typedef __attribute__((ext_vector_type(4))) float f32x4;

__device__ __forceinline__ u16 f2b(float f){
  unsigned u = __float_as_uint(f);
  unsigned r = (u + 0x7FFFu + ((u>>16)&1u)) >> 16;
  return (u16)r;
}
__device__ __forceinline__ float b2f(u16 h){ return __uint_as_float(((unsigned)h)<<16); }

// ---------------- threefry2x32 (JAX-compatible) ----------------
__host__ __device__ constexpr uint32_t rotl32(uint32_t v, int n){ return (v<<n)|(v>>(32-n)); }
struct TFOut { uint32_t a, b; };
__host__ __device__ constexpr TFOut tf2x32(uint32_t k0, uint32_t k1, uint32_t x0, uint32_t x1){
  uint32_t ks2 = k0 ^ k1 ^ 0x1BD11BDAu;
  x0 += k0; x1 += k1;
#define TFR(R) x0 += x1; x1 = rotl32(x1,(R)) ^ x0;
  TFR(13) TFR(15) TFR(26) TFR(6)
  x0 += k1; x1 += ks2 + 1u;
  TFR(17) TFR(29) TFR(16) TFR(24)
  x0 += ks2; x1 += k0 + 2u;
  TFR(13) TFR(15) TFR(26) TFR(6)
  x0 += k0; x1 += k1 + 3u;
  TFR(17) TFR(29) TFR(16) TFR(24)
  x0 += k1; x1 += ks2 + 4u;
  TFR(13) TFR(15) TFR(26) TFR(6)
  x0 += ks2; x1 += k0 + 5u;
#undef TFR
  return TFOut{x0, x1};
}

__device__ __forceinline__ float erfinv_f32(float x){
  float w = -log1pf(-x*x);
  float p;
  if (w < 5.0f) {
    w -= 2.5f;
    p = 2.81022636e-08f;
    p = fmaf(p, w, 3.43273939e-07f);
    p = fmaf(p, w, -3.5233877e-06f);
    p = fmaf(p, w, -4.39150654e-06f);
    p = fmaf(p, w, 0.00021858087f);
    p = fmaf(p, w, -0.00125372503f);
    p = fmaf(p, w, -0.00417768164f);
    p = fmaf(p, w, 0.246640727f);
    p = fmaf(p, w, 1.50140941f);
  } else {
    w = sqrtf(w) - 3.0f;
    p = -0.000200214257f;
    p = fmaf(p, w, 0.000100950558f);
    p = fmaf(p, w, 0.00134934322f);
    p = fmaf(p, w, -0.00367342844f);
    p = fmaf(p, w, 0.00573950773f);
    p = fmaf(p, w, -0.0076224613f);
    p = fmaf(p, w, 0.00943887047f);
    p = fmaf(p, w, 1.00167406f);
    p = fmaf(p, w, 2.83297682f);
  }
  return p * x;
}

// ---------------- K1: primes -> PT bf16 [64][1024], unit-normalized, rows>=50 zero ----
__global__ __launch_bounds__(256) void kprep(const float* __restrict__ prime, u16* __restrict__ PT){
  int m = blockIdx.x;
  u16* dst = PT + m*1024;
  if (m >= 50){ for (int k = threadIdx.x; k < 1024; k += 256) dst[k] = 0; return; }
  __shared__ float red[256];
  const float* pr = prime + m*1024;
  float ss = 0.f;
  for (int k = threadIdx.x; k < 1024; k += 256){ float v = pr[k]; ss = fmaf(v,v,ss); }
  red[threadIdx.x] = ss; __syncthreads();
  for (int s = 128; s > 0; s >>= 1){ if (threadIdx.x < s) red[threadIdx.x] += red[threadIdx.x+s]; __syncthreads(); }
  float sc = 1.0f / fmaxf(sqrtf(red[0]), 1e-12f);
  for (int k = threadIdx.x; k < 1024; k += 256) dst[k] = f2b(pr[k]*sc);
}

// ---------------- K2: MFMA logits + softmax -> C[n][64] bf16 and CT[m][4096n] bf16 ----
__global__ __launch_bounds__(256) void kC(const float* __restrict__ x, const u16* __restrict__ PT,
                                          u16* __restrict__ C, u16* __restrict__ CT){
  int blk = blockIdx.x; int b = blk>>6, n0 = (blk&63)<<6;
  int tid = threadIdx.x, lane = tid&63, w = tid>>6;
  __shared__ __align__(16) u16 xs[64*PIT];
  __shared__ __align__(16) u16 ps[64*PIT];
  __shared__ float sq[64][5];
  f32x4 acc[4] = {{0,0,0,0},{0,0,0,0},{0,0,0,0},{0,0,0,0}};
  float sqa = 0.f;
  int stok = tid>>2, sseg = tid&3;                 // staging map
  int qtok = tid&63, qg = tid>>6;                  // sumsq map
  const float* xb = x + ((size_t)(b*4096 + n0))*1024;
  for (int kc = 0; kc < 16; kc++){
    int k0 = kc*64;
    __syncthreads();
    { // stage x (cvt bf16): 16 f32 per thread
      const float* src = xb + (size_t)stok*1024 + k0 + sseg*16;
      u16* d = &xs[stok*PIT + sseg*16];
#pragma unroll
      for (int i = 0; i < 4; i++){
        float4 v = *reinterpret_cast<const float4*>(src + i*4);
        d[i*4+0]=f2b(v.x); d[i*4+1]=f2b(v.y); d[i*4+2]=f2b(v.z); d[i*4+3]=f2b(v.w);
      }
    }
    { // stage P rows
      const u16* src = PT + (size_t)stok*1024 + k0 + sseg*16;
      *reinterpret_cast<uint4*>(&ps[stok*PIT + sseg*16])   = *reinterpret_cast<const uint4*>(src);
      *reinterpret_cast<uint4*>(&ps[stok*PIT + sseg*16+8]) = *reinterpret_cast<const uint4*>(src+8);
    }
    __syncthreads();
    { // sumsq of this token's 16 values
      const u16* xr = &xs[qtok*PIT + qg*16];
#pragma unroll
      for (int j = 0; j < 16; j++){ float v = b2f(xr[j]); sqa = fmaf(v,v,sqa); }
    }
#pragma unroll
    for (int s = 0; s < 2; s++){
      short8 a = *reinterpret_cast<const short8*>(&xs[(16*w + (lane&15))*PIT + s*32 + (lane>>4)*8]);
#pragma unroll
      for (int t = 0; t < 4; t++){
        short8 bb = *reinterpret_cast<const short8*>(&ps[(t*16 + (lane&15))*PIT + s*32 + (lane>>4)*8]);
        acc[t] = __builtin_amdgcn_mfma_f32_16x16x32_bf16(a, bb, acc[t], 0, 0, 0);
      }
    }
  }
  sq[qtok][qg] = sqa;
  __syncthreads();
  if (tid < 64){
    float ss = sq[tid][0]+sq[tid][1]+sq[tid][2]+sq[tid][3];
    sq[tid][4] = 10.0f / fmaxf(sqrtf(ss), 1e-12f);
  }
  __syncthreads();
  // softmax per token (rows spread over lane>>4 groups; primes = lane&15 + 16*t)
  u16* cl = xs;  // reuse
#pragma unroll
  for (int r = 0; r < 4; r++){
    int gt = 16*w + (lane>>4)*4 + r;
    float scale = sq[gt][4];
    float v[4];
#pragma unroll
    for (int t = 0; t < 4; t++) v[t] = acc[t][r] * scale;
    if ((lane&15) >= 2) v[3] = -1e30f;
    float mx = fmaxf(fmaxf(v[0],v[1]), fmaxf(v[2],v[3]));
#pragma unroll
    for (int off = 1; off < 16; off <<= 1) mx = fmaxf(mx, __shfl_xor(mx, off, 64));
    float e[4], sum = 0.f;
#pragma unroll
    for (int t = 0; t < 4; t++){ e[t] = __expf(v[t]-mx); sum += e[t]; }
#pragma unroll
    for (int off = 1; off < 16; off <<= 1) sum += __shfl_xor(sum, off, 64);
    float inv = 1.0f / sum;
#pragma unroll
    for (int t = 0; t < 4; t++) cl[gt*PIT + t*16 + (lane&15)] = f2b(e[t]*inv);
  }
  __syncthreads();
  { // C write (row-major) b128
    u16* dst = C + ((size_t)(b*4096 + n0 + stok))*64 + sseg*16;
    *reinterpret_cast<uint4*>(dst)   = *reinterpret_cast<const uint4*>(&cl[stok*PIT + sseg*16]);
    *reinterpret_cast<uint4*>(dst+8) = *reinterpret_cast<const uint4*>(&cl[stok*PIT + sseg*16+8]);
  }
  { // CT write (transposed)
    int m = tid>>2, nseg = tid&3;
    unsigned vs[8];
#pragma unroll
    for (int j = 0; j < 8; j++){
      u16 lo = cl[(nseg*16 + 2*j)*PIT + m];
      u16 hi = cl[(nseg*16 + 2*j+1)*PIT + m];
      vs[j] = (unsigned)lo | ((unsigned)hi<<16);
    }
    u16* dst = CT + ((size_t)(b*64 + m))*4096 + n0 + nseg*16;
    uint4 w0; w0.x=vs[0]; w0.y=vs[1]; w0.z=vs[2]; w0.w=vs[3];
    uint4 w1; w1.x=vs[4]; w1.y=vs[5]; w1.z=vs[6]; w1.w=vs[7];
    *reinterpret_cast<uint4*>(dst)   = w0;
    *reinterpret_cast<uint4*>(dst+8) = w1;
  }
}

// ---------------- K3: H_prime = CT @ x  (MFMA, x transposed in staging) ----------------
__global__ __launch_bounds__(256) void kHp(const float* __restrict__ x, const u16* __restrict__ CT,
                                           float* __restrict__ H, u16* __restrict__ Hb){
  int blk = blockIdx.x; int b = blk>>4, dt = blk&15, d0 = dt*64;
  int tid = threadIdx.x, lane = tid&63, w = tid>>6;
  __shared__ __align__(16) u16 cs[64*PIT];    // [m][n]
  __shared__ __align__(16) u16 xt[64*PIT];    // [d][n]
  f32x4 acc[4] = {{0,0,0,0},{0,0,0,0},{0,0,0,0},{0,0,0,0}};
  int nn = tid>>2, seg = tid&3;
  for (int nc = 0; nc < 64; nc++){
    int n0 = nc*64;
    __syncthreads();
    { // stage CT rows [m][n-chunk]
      const u16* src = CT + ((size_t)(b*64 + nn))*4096 + n0 + seg*16;  // nn = m here
      *reinterpret_cast<uint4*>(&cs[nn*PIT + seg*16])   = *reinterpret_cast<const uint4*>(src);
      *reinterpret_cast<uint4*>(&cs[nn*PIT + seg*16+8]) = *reinterpret_cast<const uint4*>(src+8);
    }
    { // stage x transposed: read [n][d] f32, write [d][n] bf16
      const float* src = x + ((size_t)(b*4096 + n0 + nn))*1024 + d0 + seg*16;
#pragma unroll
      for (int i = 0; i < 4; i++){
        float4 v = *reinterpret_cast<const float4*>(src + i*4);
        xt[(seg*16 + i*4+0)*PIT + nn] = f2b(v.x);
        xt[(seg*16 + i*4+1)*PIT + nn] = f2b(v.y);
        xt[(seg*16 + i*4+2)*PIT + nn] = f2b(v.z);
        xt[(seg*16 + i*4+3)*PIT + nn] = f2b(v.w);
      }
    }
    __syncthreads();
#pragma unroll
    for (int s = 0; s < 2; s++){
      short8 a = *reinterpret_cast<const short8*>(&cs[(16*w + (lane&15))*PIT + s*32 + (lane>>4)*8]);
#pragma unroll
      for (int t = 0; t < 4; t++){
        short8 bb = *reinterpret_cast<const short8*>(&xt[(t*16 + (lane&15))*PIT + s*32 + (lane>>4)*8]);
        acc[t] = __builtin_amdgcn_mfma_f32_16x16x32_bf16(a, bb, acc[t], 0, 0, 0);
      }
    }
  }
#pragma unroll
  for (int t = 0; t < 4; t++)
#pragma unroll
    for (int r = 0; r < 4; r++){
      int m = 16*w + (lane>>4)*4 + r;
      int d = d0 + t*16 + (lane&15);
      size_t o = ((size_t)(b*64 + m))*1024 + d;
      H[o] = acc[t][r];
      Hb[o] = f2b(acc[t][r]);
    }
}

// ---------------- K4a: Gram via MFMA: G = Hb Hb^T ----------------
__global__ __launch_bounds__(256) void kgram(const u16* __restrict__ Hb, float* __restrict__ G){
  int b = blockIdx.x;
  int tid = threadIdx.x, lane = tid&63, w = tid>>6;
  __shared__ __align__(16) u16 hs[64*PIT];
  f32x4 acc[4] = {{0,0,0,0},{0,0,0,0},{0,0,0,0},{0,0,0,0}};
  int m = tid>>2, seg = tid&3;
  for (int kc = 0; kc < 16; kc++){
    int k0 = kc*64;
    __syncthreads();
    const u16* src = Hb + ((size_t)(b*64 + m))*1024 + k0 + seg*16;
    *reinterpret_cast<uint4*>(&hs[m*PIT + seg*16])   = *reinterpret_cast<const uint4*>(src);
    *reinterpret_cast<uint4*>(&hs[m*PIT + seg*16+8]) = *reinterpret_cast<const uint4*>(src+8);
    __syncthreads();
#pragma unroll
    for (int s = 0; s < 2; s++){
      short8 a = *reinterpret_cast<const short8*>(&hs[(16*w + (lane&15))*PIT + s*32 + (lane>>4)*8]);
#pragma unroll
      for (int t = 0; t < 4; t++){
        short8 bb = *reinterpret_cast<const short8*>(&hs[(t*16 + (lane&15))*PIT + s*32 + (lane>>4)*8]);
        acc[t] = __builtin_amdgcn_mfma_f32_16x16x32_bf16(a, bb, acc[t], 0, 0, 0);
      }
    }
  }
#pragma unroll
  for (int t = 0; t < 4; t++)
#pragma unroll
    for (int r = 0; r < 4; r++){
      int i = 16*w + (lane>>4)*4 + r;
      int j = t*16 + (lane&15);
      if (i < 50 && j < 50) G[(size_t)b*2500 + i*50 + j] = acc[t][r];
    }
}

// ---------------- K4b: Newton-Schulz invsqrt via MFMA (bf16 fragments, 64x64 padded) ----
// Yr/Yc, Zr/Zc double-buffered; Tr/Tc single. r-layout = [row][k] (A operand),
// c-layout = [col][k] (B operand). Padding dims: Y diag=1 -> converge to 1.
__global__ __launch_bounds__(256) void kns3(const float* __restrict__ G, float* __restrict__ Wm){
  int b = blockIdx.x;
  __shared__ __align__(16) u16 Yr[2][64*P2], Yc[2][64*P2], Zr[2][64*P2], Zc[2][64*P2];
  __shared__ __align__(16) u16 Tr[64*P2], Tc[64*P2];
  __shared__ float sv[2];
  int tid = threadIdx.x, lane = tid&63, w = tid>>6;
  int lr = lane>>4, lc = lane&15;
  int row0 = 16*w;
  const float* Gb = G + (size_t)b*2500;
  if (tid < 64){
    float v = (tid < 50) ? Gb[tid*50+tid] : 0.f;
    for (int off = 1; off < 64; off <<= 1) v += __shfl_xor(v, off, 64);
    if (tid == 0){ sv[0] = 1.0f / v; sv[1] = rsqrtf(v); }
  }
  __syncthreads();
  float rs = sv[0];
  for (int idx = tid; idx < 4096; idx += 256){
    int r = idx>>6, c = idx&63;
    float yv = (r<50 && c<50) ? Gb[r*50+c]*rs : ((r==c) ? 1.f : 0.f);
    float zv = (r==c) ? 1.f : 0.f;
    u16 yb = f2b(yv), zb = f2b(zv);
    Yr[0][r*P2+c] = yb; Yc[0][c*P2+r] = yb;
    Zr[0][r*P2+c] = zb; Zc[0][c*P2+r] = zb;
  }
  __syncthreads();
  for (int it = 0; it < NS_ITERS; it++){
    int cur = it & 1, nxt = cur ^ 1;
    { // phase 1: T = 1.5I - 0.5 * Z@Y
      short8 a0 = *reinterpret_cast<const short8*>(&Zr[cur][(row0+lc)*P2 + lr*8]);
      short8 a1 = *reinterpret_cast<const short8*>(&Zr[cur][(row0+lc)*P2 + 32 + lr*8]);
      f32x4 acc[4] = {{0,0,0,0},{0,0,0,0},{0,0,0,0},{0,0,0,0}};
#pragma unroll
      for (int t = 0; t < 4; t++){
        short8 b0 = *reinterpret_cast<const short8*>(&Yc[cur][(t*16+lc)*P2 + lr*8]);
        short8 b1 = *reinterpret_cast<const short8*>(&Yc[cur][(t*16+lc)*P2 + 32 + lr*8]);
        acc[t] = __builtin_amdgcn_mfma_f32_16x16x32_bf16(a0, b0, acc[t], 0, 0, 0);
        acc[t] = __builtin_amdgcn_mfma_f32_16x16x32_bf16(a1, b1, acc[t], 0, 0, 0);
      }
#pragma unroll
      for (int t = 0; t < 4; t++)
#pragma unroll
        for (int r = 0; r < 4; r++){
          int row = row0 + lr*4 + r, col = t*16 + lc;
          float v = ((row==col) ? 1.5f : 0.f) - 0.5f*acc[t][r];
          u16 h = f2b(v);
          Tr[row*P2+col] = h; Tc[col*P2+row] = h;
        }
    }
    __syncthreads();
    { // phase 2: Y' = Y@T ; Z' = T@Z
      short8 ya0 = *reinterpret_cast<const short8*>(&Yr[cur][(row0+lc)*P2 + lr*8]);
      short8 ya1 = *reinterpret_cast<const short8*>(&Yr[cur][(row0+lc)*P2 + 32 + lr*8]);
      short8 ta0 = *reinterpret_cast<const short8*>(&Tr[(row0+lc)*P2 + lr*8]);
      short8 ta1 = *reinterpret_cast<const short8*>(&Tr[(row0+lc)*P2 + 32 + lr*8]);
      f32x4 accY[4] = {{0,0,0,0},{0,0,0,0},{0,0,0,0},{0,0,0,0}};
      f32x4 accZ[4] = {{0,0,0,0},{0,0,0,0},{0,0,0,0},{0,0,0,0}};
#pragma unroll
      for (int t = 0; t < 4; t++){
        short8 tb0 = *reinterpret_cast<const short8*>(&Tc[(t*16+lc)*P2 + lr*8]);
        short8 tb1 = *reinterpret_cast<const short8*>(&Tc[(t*16+lc)*P2 + 32 + lr*8]);
        accY[t] = __builtin_amdgcn_mfma_f32_16x16x32_bf16(ya0, tb0, accY[t], 0, 0, 0);
        accY[t] = __builtin_amdgcn_mfma_f32_16x16x32_bf16(ya1, tb1, accY[t], 0, 0, 0);
        short8 zb0 = *reinterpret_cast<const short8*>(&Zc[cur][(t*16+lc)*P2 + lr*8]);
        short8 zb1 = *reinterpret_cast<const short8*>(&Zc[cur][(t*16+lc)*P2 + 32 + lr*8]);
        accZ[t] = __builtin_amdgcn_mfma_f32_16x16x32_bf16(ta0, zb0, accZ[t], 0, 0, 0);
        accZ[t] = __builtin_amdgcn_mfma_f32_16x16x32_bf16(ta1, zb1, accZ[t], 0, 0, 0);
      }
#pragma unroll
      for (int t = 0; t < 4; t++)
#pragma unroll
        for (int r = 0; r < 4; r++){
          int row = row0 + lr*4 + r, col = t*16 + lc;
          u16 hy = f2b(accY[t][r]);
          u16 hz = f2b(accZ[t][r]);
          Yr[nxt][row*P2+col] = hy; Yc[nxt][col*P2+row] = hy;
          Zr[nxt][row*P2+col] = hz; Zc[nxt][col*P2+row] = hz;
        }
    }
    __syncthreads();
  }
  float rss = sv[1];
  int fin = NS_ITERS & 1;
  for (int idx = tid; idx < 2500; idx += 256){
    int r = idx/50, c = idx - r*50;
    Wm[(size_t)b*2500 + idx] = b2f(Zr[fin][r*P2+c]) * rss;
  }
}

// ---------------- K4c: H_logic = Wm @ H (fp32 VALU) ----------------
__global__ __launch_bounds__(256) void kapply(const float* __restrict__ H, const float* __restrict__ Wm, float* __restrict__ Zb){
  int blk = blockIdx.x;          // 128 = b(8) * dt(16)
  int dt = blk & 15, b = blk >> 4;
  int d0 = dt*64;
  int tid = threadIdx.x;
  int d = tid & 63, mg = tid >> 6;
  __shared__ __align__(16) float WsT[50*64];
  __shared__ float Hs[50*65];
  for (int idx = tid; idx < 3200; idx += 256){
    int j = idx >> 6, c = idx & 63;
    WsT[idx] = (c < 50) ? Wm[(size_t)b*2500 + c*50 + j] : 0.f;
  }
  for (int idx = tid; idx < 3200; idx += 256){
    int j = idx >> 6, c = idx & 63;
    Hs[j*65 + c] = H[((size_t)(b*64) + j)*1024 + d0 + c];
  }
  __syncthreads();
  float acc[16];
#pragma unroll
  for (int i = 0; i < 16; i++) acc[i] = 0.f;
  for (int j = 0; j < 50; j++){
    float hv = Hs[j*65 + d];
    const float* wb = WsT + j*64 + (mg << 4);
#pragma unroll
    for (int q = 0; q < 4; q++){
      float4 wv = *reinterpret_cast<const float4*>(wb + q*4);
      acc[q*4+0] = fmaf(wv.x, hv, acc[q*4+0]);
      acc[q*4+1] = fmaf(wv.y, hv, acc[q*4+1]);
      acc[q*4+2] = fmaf(wv.z, hv, acc[q*4+2]);
      acc[q*4+3] = fmaf(wv.w, hv, acc[q*4+3]);
    }
  }
#pragma unroll
  for (int i = 0; i < 16; i++){
    int m = (mg << 4) + i;
    if (m < 50) Zb[((size_t)(b*50) + m)*1024 + d0 + d] = acc[i];
  }
}

// ---------------- K4d: noise (threefry) on ZB; emit ZbB bf16 padded ----------------
__global__ __launch_bounds__(256) void knoise(float* __restrict__ z, u16* __restrict__ zb){
  TFOut K1 = tf2x32(0u, 42u, 0u, 0u);
  TFOut K2 = tf2x32(0u, 42u, 0u, 1u);
  int e0 = (blockIdx.x*256 + threadIdx.x)*4;    // over 8*64*1024
  int b = e0 >> 16, rem = e0 & 65535;
  int m = rem >> 10, d = rem & 1023;
  u16* zdst = zb + ((size_t)(b*64 + m))*1024 + d;
  if (m >= 50){
    uint2 zz; zz.x = 0; zz.y = 0;
    *reinterpret_cast<uint2*>(zdst) = zz;
    return;
  }
  size_t zoff = ((size_t)(b*50 + m))*1024 + d;
  float4 v = *reinterpret_cast<float4*>(z + zoff);
  float vv[4] = {v.x, v.y, v.z, v.w};
  uint32_t jbase = (uint32_t)zoff;
#pragma unroll
  for (int q = 0; q < 4; q++){
    uint32_t j = jbase + q;
    TFOut r1 = tf2x32(K1.a, K1.b, 0u, j);
    uint32_t bits = r1.a ^ r1.b;
    float u = __uint_as_float(0x3F800000u | (bits >> 9)) - 1.0f;
    if (u < 0.0464f){
      TFOut r2 = tf2x32(K2.a, K2.b, 0u, j);
      uint32_t nb = r2.a ^ r2.b;
      float ww = __uint_as_float(0x3F800000u | (nb >> 9)) - 1.0f;
      const float lo = -0.99999994f;
      float un = fmaxf(lo, fmaf(ww, 2.0f, lo));
      vv[q] += 0.1f * (1.4142135f * erfinv_f32(un));
    }
  }
  *reinterpret_cast<float4*>(z + zoff) = make_float4(vv[0], vv[1], vv[2], vv[3]);
  uint2 zz;
  zz.x = (unsigned)f2b(vv[0]) | ((unsigned)f2b(vv[1])<<16);
  zz.y = (unsigned)f2b(vv[2]) | ((unsigned)f2b(vv[3])<<16);
  *reinterpret_cast<uint2*>(zdst) = zz;
}

// ---------------- K5: Hh = gelu(ZbB @ W1 + b1) (MFMA; W1 transpose-staged) ----------------
__global__ __launch_bounds__(256) void kmlp1(const u16* __restrict__ ZbB, const float* __restrict__ W1,
                                             const float* __restrict__ b1, u16* __restrict__ Hh){
  int blk = blockIdx.x; int b = blk>>6, c0 = (blk&63)<<6;
  int tid = threadIdx.x, lane = tid&63, w = tid>>6;
  __shared__ __align__(16) u16 az[64*PIT];   // [m][k]
  __shared__ __align__(16) u16 wt[64*PIT];   // [n][k]
  f32x4 acc[4] = {{0,0,0,0},{0,0,0,0},{0,0,0,0},{0,0,0,0}};
  int rr = tid>>2, seg = tid&3;
  for (int kc = 0; kc < 16; kc++){
    int k0 = kc*64;
    __syncthreads();
    { // stage A (ZbB rows)
      const u16* src = ZbB + ((size_t)(b*64 + rr))*1024 + k0 + seg*16;
      *reinterpret_cast<uint4*>(&az[rr*PIT + seg*16])   = *reinterpret_cast<const uint4*>(src);
      *reinterpret_cast<uint4*>(&az[rr*PIT + seg*16+8]) = *reinterpret_cast<const uint4*>(src+8);
    }
    { // stage W1 transposed: read [k][n] f32 -> wt[n][k] bf16
      const float* src = W1 + ((size_t)(k0 + rr))*4096 + c0 + seg*16;  // rr = kk
#pragma unroll
      for (int i = 0; i < 4; i++){
        float4 v = *reinterpret_cast<const float4*>(src + i*4);
        wt[(seg*16 + i*4+0)*PIT + rr] = f2b(v.x);
        wt[(seg*16 + i*4+1)*PIT + rr] = f2b(v.y);
        wt[(seg*16 + i*4+2)*PIT + rr] = f2b(v.z);
        wt[(seg*16 + i*4+3)*PIT + rr] = f2b(v.w);
      }
    }
    __syncthreads();
#pragma unroll
    for (int s = 0; s < 2; s++){
      short8 a = *reinterpret_cast<const short8*>(&az[(16*w + (lane&15))*PIT + s*32 + (lane>>4)*8]);
#pragma unroll
      for (int t = 0; t < 4; t++){
        short8 bb = *reinterpret_cast<const short8*>(&wt[(t*16 + (lane&15))*PIT + s*32 + (lane>>4)*8]);
        acc[t] = __builtin_amdgcn_mfma_f32_16x16x32_bf16(a, bb, acc[t], 0, 0, 0);
      }
    }
  }
#pragma unroll
  for (int t = 0; t < 4; t++)
#pragma unroll
    for (int r = 0; r < 4; r++){
      int m = 16*w + (lane>>4)*4 + r;
      int n = c0 + t*16 + (lane&15);
      float val = acc[t][r] + b1[n];
      float g = 0.5f * val * (1.0f + erff(val * 0.70710678f));
      Hh[((size_t)(b*64 + m))*4096 + n] = (m < 50) ? f2b(g) : (u16)0;
    }
}

// ---------------- K6: HfT = tanh(Hh @ W2 + b2)^T (MFMA; W2 transpose-staged; LDS transpose out) ----
__global__ __launch_bounds__(256) void kmlp2(const u16* __restrict__ Hh, const float* __restrict__ W2,
                                             const float* __restrict__ b2, u16* __restrict__ HfT){
  int blk = blockIdx.x; int b = blk>>4, dt = blk&15, d0 = dt*64;
  int tid = threadIdx.x, lane = tid&63, w = tid>>6;
  __shared__ __align__(16) u16 az[64*PIT];
  __shared__ __align__(16) u16 wt[64*PIT];
  f32x4 acc[4] = {{0,0,0,0},{0,0,0,0},{0,0,0,0},{0,0,0,0}};
  int rr = tid>>2, seg = tid&3;
  for (int kc = 0; kc < 64; kc++){
    int k0 = kc*64;
    __syncthreads();
    {
      const u16* src = Hh + ((size_t)(b*64 + rr))*4096 + k0 + seg*16;
      *reinterpret_cast<uint4*>(&az[rr*PIT + seg*16])   = *reinterpret_cast<const uint4*>(src);
      *reinterpret_cast<uint4*>(&az[rr*PIT + seg*16+8]) = *reinterpret_cast<const uint4*>(src+8);
    }
    {
      const float* src = W2 + ((size_t)(k0 + rr))*1024 + d0 + seg*16;
#pragma unroll
      for (int i = 0; i < 4; i++){
        float4 v = *reinterpret_cast<const float4*>(src + i*4);
        wt[(seg*16 + i*4+0)*PIT + rr] = f2b(v.x);
        wt[(seg*16 + i*4+1)*PIT + rr] = f2b(v.y);
        wt[(seg*16 + i*4+2)*PIT + rr] = f2b(v.z);
        wt[(seg*16 + i*4+3)*PIT + rr] = f2b(v.w);
      }
    }
    __syncthreads();
#pragma unroll
    for (int s = 0; s < 2; s++){
      short8 a = *reinterpret_cast<const short8*>(&az[(16*w + (lane&15))*PIT + s*32 + (lane>>4)*8]);
#pragma unroll
      for (int t = 0; t < 4; t++){
        short8 bb = *reinterpret_cast<const short8*>(&wt[(t*16 + (lane&15))*PIT + s*32 + (lane>>4)*8]);
        acc[t] = __builtin_amdgcn_mfma_f32_16x16x32_bf16(a, bb, acc[t], 0, 0, 0);
      }
    }
  }
  __syncthreads();
  // write tanh result transposed into LDS: cl[d_local][m]
  u16* cl = az;
#pragma unroll
  for (int t = 0; t < 4; t++)
#pragma unroll
    for (int r = 0; r < 4; r++){
      int m = 16*w + (lane>>4)*4 + r;
      int dl = t*16 + (lane&15);
      float val = tanhf(acc[t][r] + b2[d0 + dl]);
      cl[dl*PIT + m] = (m < 50) ? f2b(val) : (u16)0;
    }
  __syncthreads();
  {
    const u16* srow = &cl[rr*PIT + seg*16];  // rr = d_local
    u16* dst = HfT + ((size_t)(b*1024 + d0 + rr))*64 + seg*16;
    *reinterpret_cast<uint4*>(dst)   = *reinterpret_cast<const uint4*>(srow);
    *reinterpret_cast<uint4*>(dst+8) = *reinterpret_cast<const uint4*>(srow+8);
  }
}

// ---------------- K7: out = x + C @ Hf (MFMA) ----------------
__global__ __launch_bounds__(256) void kdec(const float* __restrict__ x, const u16* __restrict__ C,
                                            const u16* __restrict__ HfT, float* __restrict__ out){
  int blk = blockIdx.x; int b = blk>>6, n0 = (blk&63)<<6;
  int tid = threadIdx.x, lane = tid&63, w = tid>>6;
  __shared__ __align__(16) u16 ctile[64*PIT];   // [tok][m]
  __shared__ __align__(16) u16 htile[64*PIT];   // [d][m]
  int rr = tid>>2, seg = tid&3;
  {
    const u16* src = C + ((size_t)(b*4096 + n0 + rr))*64 + seg*16;
    *reinterpret_cast<uint4*>(&ctile[rr*PIT + seg*16])   = *reinterpret_cast<const uint4*>(src);
    *reinterpret_cast<uint4*>(&ctile[rr*PIT + seg*16+8]) = *reinterpret_cast<const uint4*>(src+8);
  }
  __syncthreads();
  short8 afrag[2];
#pragma unroll
  for (int s = 0; s < 2; s++)
    afrag[s] = *reinterpret_cast<const short8*>(&ctile[(16*w + (lane&15))*PIT + s*32 + (lane>>4)*8]);
  for (int dt2 = 0; dt2 < 16; dt2++){
    int d0 = dt2*64;
    __syncthreads();
    {
      const u16* src = HfT + ((size_t)(b*1024 + d0 + rr))*64 + seg*16;
      *reinterpret_cast<uint4*>(&htile[rr*PIT + seg*16])   = *reinterpret_cast<const uint4*>(src);
      *reinterpret_cast<uint4*>(&htile[rr*PIT + seg*16+8]) = *reinterpret_cast<const uint4*>(src+8);
    }
    __syncthreads();
    f32x4 acc[4] = {{0,0,0,0},{0,0,0,0},{0,0,0,0},{0,0,0,0}};
#pragma unroll
    for (int s = 0; s < 2; s++){
#pragma unroll
      for (int t = 0; t < 4; t++){
        short8 bb = *reinterpret_cast<const short8*>(&htile[(t*16 + (lane&15))*PIT + s*32 + (lane>>4)*8]);
        acc[t] = __builtin_amdgcn_mfma_f32_16x16x32_bf16(afrag[s], bb, acc[t], 0, 0, 0);
      }
    }
#pragma unroll
    for (int t = 0; t < 4; t++)
#pragma unroll
      for (int r = 0; r < 4; r++){
        int n = n0 + 16*w + (lane>>4)*4 + r;
        int d = d0 + t*16 + (lane&15);
        size_t o = ((size_t)(b*4096 + n))*1024 + d;
        out[o] = x[o] + acc[t][r];
      }
  }
}

// ---------------- launch ----------------
extern "C" void kernel_launch(void* const* d_in, const int* in_sizes, int n_in,
                              void* d_out, int out_size, void* d_ws, size_t ws_size,
                              hipStream_t stream) {
  (void)in_sizes; (void)n_in; (void)out_size;
  if (ws_size < (size_t)19755264) return;
  const float* x  = (const float*)d_in[0];
  const float* pn = (const float*)d_in[1];
  const float* W1 = (const float*)d_in[8];
  const float* b1 = (const float*)d_in[9];
  const float* W2 = (const float*)d_in[10];
  const float* b2 = (const float*)d_in[11];
  float* out = (float*)d_out;
  char* ws = (char*)d_ws;

  u16*   C   = (u16*)(ws);                      // 4,194,304 B
  u16*   CT  = (u16*)(ws + 4194304);            // 4,194,304 B
  u16*   Hh  = (u16*)(ws + 8388608);            // 4,194,304 B
  float* H   = (float*)(ws + 12582912);         // 2,097,152 B
  float* ZB  = (float*)(ws + 14680064);         // 1,638,400 B
  u16*   ZbB = (u16*)(ws + 16318464);           // 1,048,576 B
  u16*   HfT = (u16*)(ws + 17367040);           // 1,048,576 B
  u16*   Hb  = (u16*)(ws + 18415616);           // 1,048,576 B
  u16*   PT  = (u16*)(ws + 19464192);           //   131,072 B
  float* G   = (float*)(ws + 19595264);         //    80,000 B
  float* WM  = (float*)(ws + 19675264);         //    80,000 B

  hipLaunchKernelGGL(kprep,  dim3(64),  dim3(256), 0, stream, pn, PT);
  hipLaunchKernelGGL(kC,     dim3(512), dim3(256), 0, stream, x, PT, C, CT);
  hipLaunchKernelGGL(kHp,    dim3(128), dim3(256), 0, stream, x, CT, H, Hb);
  hipLaunchKernelGGL(kgram,  dim3(8),   dim3(256), 0, stream, Hb, G);
  hipLaunchKernelGGL(kns3,   dim3(8),   dim3(256), 0, stream, G, WM);
  hipLaunchKernelGGL(kapply, dim3(128), dim3(256), 0, stream, H, WM, ZB);
  hipLaunchKernelGGL(knoise, dim3(512), dim3(256), 0, stream, ZB, ZbB);
  hipLaunchKernelGGL(kmlp1,  dim3(512), dim3(256), 0, stream, ZbB, W1, b1, Hh);
  hipLaunchKernelGGL(kmlp2,  dim3(128), dim3(256), 0, stream, Hh, W2, b2, HfT);
  hipLaunchKernelGGL(kdec,   dim3(512), dim3(256), 0, stream, x, C, HfT, out);
}

// Round 6
// 312.988 us; speedup vs baseline: 3.3447x; 1.3636x over previous
//
#include <hip/hip_runtime.h>
#include <stdint.h>
#include <math.h>

#define NS_ITERS 26
#define PIT 72   // LDS row pitch in shorts (144B: 16B-aligned, bank-spread)
#define P2  72   // pitch for kns3 matrices

typedef unsigned short u16;
typedef __attribute__((ext_vector_type(8))) short short8;
typedef __attribute__((ext_vector_type(4))) float f32x4;

__device__ __forceinline__ u16 f2b(float f){
  unsigned u = __float_as_uint(f);
  unsigned r = (u + 0x7FFFu + ((u>>16)&1u)) >> 16;
  return (u16)r;
}
__device__ __forceinline__ float b2f(u16 h){ return __uint_as_float(((unsigned)h)<<16); }

// ---------------- threefry2x32 (JAX-compatible) ----------------
__host__ __device__ constexpr uint32_t rotl32(uint32_t v, int n){ return (v<<n)|(v>>(32-n)); }
struct TFOut { uint32_t a, b; };
__host__ __device__ constexpr TFOut tf2x32(uint32_t k0, uint32_t k1, uint32_t x0, uint32_t x1){
  uint32_t ks2 = k0 ^ k1 ^ 0x1BD11BDAu;
  x0 += k0; x1 += k1;
#define TFR(R) x0 += x1; x1 = rotl32(x1,(R)) ^ x0;
  TFR(13) TFR(15) TFR(26) TFR(6)
  x0 += k1; x1 += ks2 + 1u;
  TFR(17) TFR(29) TFR(16) TFR(24)
  x0 += ks2; x1 += k0 + 2u;
  TFR(13) TFR(15) TFR(26) TFR(6)
  x0 += k0; x1 += k1 + 3u;
  TFR(17) TFR(29) TFR(16) TFR(24)
  x0 += k1; x1 += ks2 + 4u;
  TFR(13) TFR(15) TFR(26) TFR(6)
  x0 += ks2; x1 += k0 + 5u;
#undef TFR
  return TFOut{x0, x1};
}

__device__ __forceinline__ float erfinv_f32(float x){
  float w = -log1pf(-x*x);
  float p;
  if (w < 5.0f) {
    w -= 2.5f;
    p = 2.81022636e-08f;
    p = fmaf(p, w, 3.43273939e-07f);
    p = fmaf(p, w, -3.5233877e-06f);
    p = fmaf(p, w, -4.39150654e-06f);
    p = fmaf(p, w, 0.00021858087f);
    p = fmaf(p, w, -0.00125372503f);
    p = fmaf(p, w, -0.00417768164f);
    p = fmaf(p, w, 0.246640727f);
    p = fmaf(p, w, 1.50140941f);
  } else {
    w = sqrtf(w) - 3.0f;
    p = -0.000200214257f;
    p = fmaf(p, w, 0.000100950558f);
    p = fmaf(p, w, 0.00134934322f);
    p = fmaf(p, w, -0.00367342844f);
    p = fmaf(p, w, 0.00573950773f);
    p = fmaf(p, w, -0.0076224613f);
    p = fmaf(p, w, 0.00943887047f);
    p = fmaf(p, w, 1.00167406f);
    p = fmaf(p, w, 2.83297682f);
  }
  return p * x;
}

// ---------------- K1: primes -> PT bf16 [64][1024], unit-normalized, rows>=50 zero ----
__global__ __launch_bounds__(256) void kprep(const float* __restrict__ prime, u16* __restrict__ PT){
  int m = blockIdx.x;
  u16* dst = PT + m*1024;
  if (m >= 50){ for (int k = threadIdx.x; k < 1024; k += 256) dst[k] = 0; return; }
  __shared__ float red[256];
  const float* pr = prime + m*1024;
  float ss = 0.f;
  for (int k = threadIdx.x; k < 1024; k += 256){ float v = pr[k]; ss = fmaf(v,v,ss); }
  red[threadIdx.x] = ss; __syncthreads();
  for (int s = 128; s > 0; s >>= 1){ if (threadIdx.x < s) red[threadIdx.x] += red[threadIdx.x+s]; __syncthreads(); }
  float sc = 1.0f / fmaxf(sqrtf(red[0]), 1e-12f);
  for (int k = threadIdx.x; k < 1024; k += 256) dst[k] = f2b(pr[k]*sc);
}

// ---------------- K2: MFMA logits + softmax -> C[n][64] bf16 and CT[m][4096n] bf16 ----
__global__ __launch_bounds__(256) void kC(const float* __restrict__ x, const u16* __restrict__ PT,
                                          u16* __restrict__ C, u16* __restrict__ CT){
  int blk = blockIdx.x; int b = blk>>6, n0 = (blk&63)<<6;
  int tid = threadIdx.x, lane = tid&63, w = tid>>6;
  __shared__ __align__(16) u16 xs[64*PIT];
  __shared__ __align__(16) u16 ps[64*PIT];
  __shared__ float sq[64][5];
  f32x4 acc[4] = {{0,0,0,0},{0,0,0,0},{0,0,0,0},{0,0,0,0}};
  float sqa = 0.f;
  int stok = tid>>2, sseg = tid&3;                 // staging map
  int qtok = tid&63, qg = tid>>6;                  // sumsq map
  const float* xb = x + ((size_t)(b*4096 + n0))*1024;
  for (int kc = 0; kc < 16; kc++){
    int k0 = kc*64;
    __syncthreads();
    { // stage x (cvt bf16): 16 f32 per thread
      const float* src = xb + (size_t)stok*1024 + k0 + sseg*16;
      u16* d = &xs[stok*PIT + sseg*16];
#pragma unroll
      for (int i = 0; i < 4; i++){
        float4 v = *reinterpret_cast<const float4*>(src + i*4);
        d[i*4+0]=f2b(v.x); d[i*4+1]=f2b(v.y); d[i*4+2]=f2b(v.z); d[i*4+3]=f2b(v.w);
      }
    }
    { // stage P rows
      const u16* src = PT + (size_t)stok*1024 + k0 + sseg*16;
      *reinterpret_cast<uint4*>(&ps[stok*PIT + sseg*16])   = *reinterpret_cast<const uint4*>(src);
      *reinterpret_cast<uint4*>(&ps[stok*PIT + sseg*16+8]) = *reinterpret_cast<const uint4*>(src+8);
    }
    __syncthreads();
    { // sumsq of this token's 16 values
      const u16* xr = &xs[qtok*PIT + qg*16];
#pragma unroll
      for (int j = 0; j < 16; j++){ float v = b2f(xr[j]); sqa = fmaf(v,v,sqa); }
    }
#pragma unroll
    for (int s = 0; s < 2; s++){
      short8 a = *reinterpret_cast<const short8*>(&xs[(16*w + (lane&15))*PIT + s*32 + (lane>>4)*8]);
#pragma unroll
      for (int t = 0; t < 4; t++){
        short8 bb = *reinterpret_cast<const short8*>(&ps[(t*16 + (lane&15))*PIT + s*32 + (lane>>4)*8]);
        acc[t] = __builtin_amdgcn_mfma_f32_16x16x32_bf16(a, bb, acc[t], 0, 0, 0);
      }
    }
  }
  sq[qtok][qg] = sqa;
  __syncthreads();
  if (tid < 64){
    float ss = sq[tid][0]+sq[tid][1]+sq[tid][2]+sq[tid][3];
    sq[tid][4] = 10.0f / fmaxf(sqrtf(ss), 1e-12f);
  }
  __syncthreads();
  // softmax per token (rows spread over lane>>4 groups; primes = lane&15 + 16*t)
  u16* cl = xs;  // reuse
#pragma unroll
  for (int r = 0; r < 4; r++){
    int gt = 16*w + (lane>>4)*4 + r;
    float scale = sq[gt][4];
    float v[4];
#pragma unroll
    for (int t = 0; t < 4; t++) v[t] = acc[t][r] * scale;
    if ((lane&15) >= 2) v[3] = -1e30f;
    float mx = fmaxf(fmaxf(v[0],v[1]), fmaxf(v[2],v[3]));
#pragma unroll
    for (int off = 1; off < 16; off <<= 1) mx = fmaxf(mx, __shfl_xor(mx, off, 64));
    float e[4], sum = 0.f;
#pragma unroll
    for (int t = 0; t < 4; t++){ e[t] = __expf(v[t]-mx); sum += e[t]; }
#pragma unroll
    for (int off = 1; off < 16; off <<= 1) sum += __shfl_xor(sum, off, 64);
    float inv = 1.0f / sum;
#pragma unroll
    for (int t = 0; t < 4; t++) cl[gt*PIT + t*16 + (lane&15)] = f2b(e[t]*inv);
  }
  __syncthreads();
  { // C write (row-major) b128
    u16* dst = C + ((size_t)(b*4096 + n0 + stok))*64 + sseg*16;
    *reinterpret_cast<uint4*>(dst)   = *reinterpret_cast<const uint4*>(&cl[stok*PIT + sseg*16]);
    *reinterpret_cast<uint4*>(dst+8) = *reinterpret_cast<const uint4*>(&cl[stok*PIT + sseg*16+8]);
  }
  { // CT write (transposed)
    int m = tid>>2, nseg = tid&3;
    unsigned vs[8];
#pragma unroll
    for (int j = 0; j < 8; j++){
      u16 lo = cl[(nseg*16 + 2*j)*PIT + m];
      u16 hi = cl[(nseg*16 + 2*j+1)*PIT + m];
      vs[j] = (unsigned)lo | ((unsigned)hi<<16);
    }
    u16* dst = CT + ((size_t)(b*64 + m))*4096 + n0 + nseg*16;
    uint4 w0; w0.x=vs[0]; w0.y=vs[1]; w0.z=vs[2]; w0.w=vs[3];
    uint4 w1; w1.x=vs[4]; w1.y=vs[5]; w1.z=vs[6]; w1.w=vs[7];
    *reinterpret_cast<uint4*>(dst)   = w0;
    *reinterpret_cast<uint4*>(dst+8) = w1;
  }
}

// ---------------- K3: H_prime partials = CT @ x over n-quarter (MFMA, K-split x4) ----
__global__ __launch_bounds__(256) void kHp2(const float* __restrict__ x, const u16* __restrict__ CT,
                                            float* __restrict__ Hpart){
  int blk = blockIdx.x;            // 512 = b(8) * dt(16) * kt(4)
  int kt = blk & 3, dt = (blk >> 2) & 15, b = blk >> 6;
  int d0 = dt*64;
  int tid = threadIdx.x, lane = tid&63, w = tid>>6;
  __shared__ __align__(16) u16 cs[64*PIT];    // [m][n]
  __shared__ __align__(16) u16 xt[64*PIT];    // [d][n]
  f32x4 acc[4] = {{0,0,0,0},{0,0,0,0},{0,0,0,0},{0,0,0,0}};
  int nn = tid>>2, seg = tid&3;
  for (int nc = 0; nc < 16; nc++){
    int n0 = kt*1024 + nc*64;
    __syncthreads();
    { // stage CT rows [m][n-chunk]
      const u16* src = CT + ((size_t)(b*64 + nn))*4096 + n0 + seg*16;  // nn = m here
      *reinterpret_cast<uint4*>(&cs[nn*PIT + seg*16])   = *reinterpret_cast<const uint4*>(src);
      *reinterpret_cast<uint4*>(&cs[nn*PIT + seg*16+8]) = *reinterpret_cast<const uint4*>(src+8);
    }
    { // stage x transposed: read [n][d] f32, write [d][n] bf16
      const float* src = x + ((size_t)(b*4096 + n0 + nn))*1024 + d0 + seg*16;
#pragma unroll
      for (int i = 0; i < 4; i++){
        float4 v = *reinterpret_cast<const float4*>(src + i*4);
        xt[(seg*16 + i*4+0)*PIT + nn] = f2b(v.x);
        xt[(seg*16 + i*4+1)*PIT + nn] = f2b(v.y);
        xt[(seg*16 + i*4+2)*PIT + nn] = f2b(v.z);
        xt[(seg*16 + i*4+3)*PIT + nn] = f2b(v.w);
      }
    }
    __syncthreads();
#pragma unroll
    for (int s = 0; s < 2; s++){
      short8 a = *reinterpret_cast<const short8*>(&cs[(16*w + (lane&15))*PIT + s*32 + (lane>>4)*8]);
#pragma unroll
      for (int t = 0; t < 4; t++){
        short8 bb = *reinterpret_cast<const short8*>(&xt[(t*16 + (lane&15))*PIT + s*32 + (lane>>4)*8]);
        acc[t] = __builtin_amdgcn_mfma_f32_16x16x32_bf16(a, bb, acc[t], 0, 0, 0);
      }
    }
  }
#pragma unroll
  for (int t = 0; t < 4; t++)
#pragma unroll
    for (int r = 0; r < 4; r++){
      int m = 16*w + (lane>>4)*4 + r;
      int d = d0 + t*16 + (lane&15);
      if (m < 50) Hpart[(((size_t)(b*4) + kt)*50 + m)*1024 + d] = acc[t][r];
    }
}

// ---------------- K3b: reduce partials -> H f32 + Hb bf16 (grid 1600!) ----------------
__global__ void kredH(const float* __restrict__ Hpart, float* __restrict__ H, u16* __restrict__ Hb){
  int e = blockIdx.x*256 + threadIdx.x;    // grid 1600 -> 409600 over [b][m(50)][d]
  int b = e / 51200; int rem = e - b*51200;
  int m = rem >> 10, d = rem & 1023;
  const float* p = Hpart + (size_t)b*204800 + rem;
  float s = p[0] + p[51200] + p[102400] + p[153600];
  size_t o = ((size_t)(b*64 + m))*1024 + d;
  H[o] = s;
  Hb[o] = f2b(s);
}

// ---------------- K3c: zero pad rows 50..63 of Hb (keeps kgram's 64-row reads clean) ----
__global__ void kpadHb(u16* __restrict__ Hb){
  int e = blockIdx.x*256 + threadIdx.x;   // grid 448 -> 114688 = 8*14*1024
  int b = e / 14336; int rem = e - b*14336;
  int m = 50 + (rem >> 10), d = rem & 1023;
  Hb[((size_t)(b*64 + m))*1024 + d] = 0;
}

// ---------------- K4a: Gram via MFMA: G = Hb Hb^T ----------------
__global__ __launch_bounds__(256) void kgram(const u16* __restrict__ Hb, float* __restrict__ G){
  int b = blockIdx.x;
  int tid = threadIdx.x, lane = tid&63, w = tid>>6;
  __shared__ __align__(16) u16 hs[64*PIT];
  f32x4 acc[4] = {{0,0,0,0},{0,0,0,0},{0,0,0,0},{0,0,0,0}};
  int m = tid>>2, seg = tid&3;
  for (int kc = 0; kc < 16; kc++){
    int k0 = kc*64;
    __syncthreads();
    const u16* src = Hb + ((size_t)(b*64 + m))*1024 + k0 + seg*16;
    *reinterpret_cast<uint4*>(&hs[m*PIT + seg*16])   = *reinterpret_cast<const uint4*>(src);
    *reinterpret_cast<uint4*>(&hs[m*PIT + seg*16+8]) = *reinterpret_cast<const uint4*>(src+8);
    __syncthreads();
#pragma unroll
    for (int s = 0; s < 2; s++){
      short8 a = *reinterpret_cast<const short8*>(&hs[(16*w + (lane&15))*PIT + s*32 + (lane>>4)*8]);
#pragma unroll
      for (int t = 0; t < 4; t++){
        short8 bb = *reinterpret_cast<const short8*>(&hs[(t*16 + (lane&15))*PIT + s*32 + (lane>>4)*8]);
        acc[t] = __builtin_amdgcn_mfma_f32_16x16x32_bf16(a, bb, acc[t], 0, 0, 0);
      }
    }
  }
#pragma unroll
  for (int t = 0; t < 4; t++)
#pragma unroll
    for (int r = 0; r < 4; r++){
      int i = 16*w + (lane>>4)*4 + r;
      int j = t*16 + (lane&15);
      if (i < 50 && j < 50) G[(size_t)b*2500 + i*50 + j] = acc[t][r];
    }
}

// ---------------- K4b: Newton-Schulz invsqrt via MFMA (bf16 fragments, 64x64 padded) ----
__global__ __launch_bounds__(256) void kns3(const float* __restrict__ G, float* __restrict__ Wm){
  int b = blockIdx.x;
  __shared__ __align__(16) u16 Yr[2][64*P2], Yc[2][64*P2], Zr[2][64*P2], Zc[2][64*P2];
  __shared__ __align__(16) u16 Tr[64*P2], Tc[64*P2];
  __shared__ float sv[2];
  int tid = threadIdx.x, lane = tid&63, w = tid>>6;
  int lr = lane>>4, lc = lane&15;
  int row0 = 16*w;
  const float* Gb = G + (size_t)b*2500;
  if (tid < 64){
    float v = (tid < 50) ? Gb[tid*50+tid] : 0.f;
    for (int off = 1; off < 64; off <<= 1) v += __shfl_xor(v, off, 64);
    if (tid == 0){ sv[0] = 1.0f / v; sv[1] = rsqrtf(v); }
  }
  __syncthreads();
  float rs = sv[0];
  for (int idx = tid; idx < 4096; idx += 256){
    int r = idx>>6, c = idx&63;
    float yv = (r<50 && c<50) ? Gb[r*50+c]*rs : ((r==c) ? 1.f : 0.f);
    float zv = (r==c) ? 1.f : 0.f;
    u16 yb = f2b(yv), zb = f2b(zv);
    Yr[0][r*P2+c] = yb; Yc[0][c*P2+r] = yb;
    Zr[0][r*P2+c] = zb; Zc[0][c*P2+r] = zb;
  }
  __syncthreads();
  for (int it = 0; it < NS_ITERS; it++){
    int cur = it & 1, nxt = cur ^ 1;
    { // phase 1: T = 1.5I - 0.5 * Z@Y
      short8 a0 = *reinterpret_cast<const short8*>(&Zr[cur][(row0+lc)*P2 + lr*8]);
      short8 a1 = *reinterpret_cast<const short8*>(&Zr[cur][(row0+lc)*P2 + 32 + lr*8]);
      f32x4 acc[4] = {{0,0,0,0},{0,0,0,0},{0,0,0,0},{0,0,0,0}};
#pragma unroll
      for (int t = 0; t < 4; t++){
        short8 b0 = *reinterpret_cast<const short8*>(&Yc[cur][(t*16+lc)*P2 + lr*8]);
        short8 b1 = *reinterpret_cast<const short8*>(&Yc[cur][(t*16+lc)*P2 + 32 + lr*8]);
        acc[t] = __builtin_amdgcn_mfma_f32_16x16x32_bf16(a0, b0, acc[t], 0, 0, 0);
        acc[t] = __builtin_amdgcn_mfma_f32_16x16x32_bf16(a1, b1, acc[t], 0, 0, 0);
      }
#pragma unroll
      for (int t = 0; t < 4; t++)
#pragma unroll
        for (int r = 0; r < 4; r++){
          int row = row0 + lr*4 + r, col = t*16 + lc;
          float v = ((row==col) ? 1.5f : 0.f) - 0.5f*acc[t][r];
          u16 h = f2b(v);
          Tr[row*P2+col] = h; Tc[col*P2+row] = h;
        }
    }
    __syncthreads();
    { // phase 2: Y' = Y@T ; Z' = T@Z
      short8 ya0 = *reinterpret_cast<const short8*>(&Yr[cur][(row0+lc)*P2 + lr*8]);
      short8 ya1 = *reinterpret_cast<const short8*>(&Yr[cur][(row0+lc)*P2 + 32 + lr*8]);
      short8 ta0 = *reinterpret_cast<const short8*>(&Tr[(row0+lc)*P2 + lr*8]);
      short8 ta1 = *reinterpret_cast<const short8*>(&Tr[(row0+lc)*P2 + 32 + lr*8]);
      f32x4 accY[4] = {{0,0,0,0},{0,0,0,0},{0,0,0,0},{0,0,0,0}};
      f32x4 accZ[4] = {{0,0,0,0},{0,0,0,0},{0,0,0,0},{0,0,0,0}};
#pragma unroll
      for (int t = 0; t < 4; t++){
        short8 tb0 = *reinterpret_cast<const short8*>(&Tc[(t*16+lc)*P2 + lr*8]);
        short8 tb1 = *reinterpret_cast<const short8*>(&Tc[(t*16+lc)*P2 + 32 + lr*8]);
        accY[t] = __builtin_amdgcn_mfma_f32_16x16x32_bf16(ya0, tb0, accY[t], 0, 0, 0);
        accY[t] = __builtin_amdgcn_mfma_f32_16x16x32_bf16(ya1, tb1, accY[t], 0, 0, 0);
        short8 zb0 = *reinterpret_cast<const short8*>(&Zc[cur][(t*16+lc)*P2 + lr*8]);
        short8 zb1 = *reinterpret_cast<const short8*>(&Zc[cur][(t*16+lc)*P2 + 32 + lr*8]);
        accZ[t] = __builtin_amdgcn_mfma_f32_16x16x32_bf16(ta0, zb0, accZ[t], 0, 0, 0);
        accZ[t] = __builtin_amdgcn_mfma_f32_16x16x32_bf16(ta1, zb1, accZ[t], 0, 0, 0);
      }
#pragma unroll
      for (int t = 0; t < 4; t++)
#pragma unroll
        for (int r = 0; r < 4; r++){
          int row = row0 + lr*4 + r, col = t*16 + lc;
          u16 hy = f2b(accY[t][r]);
          u16 hz = f2b(accZ[t][r]);
          Yr[nxt][row*P2+col] = hy; Yc[nxt][col*P2+row] = hy;
          Zr[nxt][row*P2+col] = hz; Zc[nxt][col*P2+row] = hz;
        }
    }
    __syncthreads();
  }
  float rss = sv[1];
  int fin = NS_ITERS & 1;
  for (int idx = tid; idx < 2500; idx += 256){
    int r = idx/50, c = idx - r*50;
    Wm[(size_t)b*2500 + idx] = b2f(Zr[fin][r*P2+c]) * rss;
  }
}

// ---------------- K4c: H_logic = Wm @ H (fp32 VALU) ----------------
__global__ __launch_bounds__(256) void kapply(const float* __restrict__ H, const float* __restrict__ Wm, float* __restrict__ Zb){
  int blk = blockIdx.x;          // 128 = b(8) * dt(16)
  int dt = blk & 15, b = blk >> 4;
  int d0 = dt*64;
  int tid = threadIdx.x;
  int d = tid & 63, mg = tid >> 6;
  __shared__ __align__(16) float WsT[50*64];
  __shared__ float Hs[50*65];
  for (int idx = tid; idx < 3200; idx += 256){
    int j = idx >> 6, c = idx & 63;
    WsT[idx] = (c < 50) ? Wm[(size_t)b*2500 + c*50 + j] : 0.f;
  }
  for (int idx = tid; idx < 3200; idx += 256){
    int j = idx >> 6, c = idx & 63;
    Hs[j*65 + c] = H[((size_t)(b*64) + j)*1024 + d0 + c];
  }
  __syncthreads();
  float acc[16];
#pragma unroll
  for (int i = 0; i < 16; i++) acc[i] = 0.f;
  for (int j = 0; j < 50; j++){
    float hv = Hs[j*65 + d];
    const float* wb = WsT + j*64 + (mg << 4);
#pragma unroll
    for (int q = 0; q < 4; q++){
      float4 wv = *reinterpret_cast<const float4*>(wb + q*4);
      acc[q*4+0] = fmaf(wv.x, hv, acc[q*4+0]);
      acc[q*4+1] = fmaf(wv.y, hv, acc[q*4+1]);
      acc[q*4+2] = fmaf(wv.z, hv, acc[q*4+2]);
      acc[q*4+3] = fmaf(wv.w, hv, acc[q*4+3]);
    }
  }
#pragma unroll
  for (int i = 0; i < 16; i++){
    int m = (mg << 4) + i;
    if (m < 50) Zb[((size_t)(b*50) + m)*1024 + d0 + d] = acc[i];
  }
}

// ---------------- K4d: noise (threefry) on ZB; emit ZbB bf16 padded ----------------
__global__ __launch_bounds__(256) void knoise(float* __restrict__ z, u16* __restrict__ zb){
  TFOut K1 = tf2x32(0u, 42u, 0u, 0u);
  TFOut K2 = tf2x32(0u, 42u, 0u, 1u);
  int e0 = (blockIdx.x*256 + threadIdx.x)*4;    // over 8*64*1024
  int b = e0 >> 16, rem = e0 & 65535;
  int m = rem >> 10, d = rem & 1023;
  u16* zdst = zb + ((size_t)(b*64 + m))*1024 + d;
  if (m >= 50){
    uint2 zz; zz.x = 0; zz.y = 0;
    *reinterpret_cast<uint2*>(zdst) = zz;
    return;
  }
  size_t zoff = ((size_t)(b*50 + m))*1024 + d;
  float4 v = *reinterpret_cast<float4*>(z + zoff);
  float vv[4] = {v.x, v.y, v.z, v.w};
  uint32_t jbase = (uint32_t)zoff;
#pragma unroll
  for (int q = 0; q < 4; q++){
    uint32_t j = jbase + q;
    TFOut r1 = tf2x32(K1.a, K1.b, 0u, j);
    uint32_t bits = r1.a ^ r1.b;
    float u = __uint_as_float(0x3F800000u | (bits >> 9)) - 1.0f;
    if (u < 0.0464f){
      TFOut r2 = tf2x32(K2.a, K2.b, 0u, j);
      uint32_t nb = r2.a ^ r2.b;
      float ww = __uint_as_float(0x3F800000u | (nb >> 9)) - 1.0f;
      const float lo = -0.99999994f;
      float un = fmaxf(lo, fmaf(ww, 2.0f, lo));
      vv[q] += 0.1f * (1.4142135f * erfinv_f32(un));
    }
  }
  *reinterpret_cast<float4*>(z + zoff) = make_float4(vv[0], vv[1], vv[2], vv[3]);
  uint2 zz;
  zz.x = (unsigned)f2b(vv[0]) | ((unsigned)f2b(vv[1])<<16);
  zz.y = (unsigned)f2b(vv[2]) | ((unsigned)f2b(vv[3])<<16);
  *reinterpret_cast<uint2*>(zdst) = zz;
}

// ---------------- K5: Hh = gelu(ZbB @ W1 + b1) (MFMA; W1 transpose-staged) ----------------
__global__ __launch_bounds__(256) void kmlp1(const u16* __restrict__ ZbB, const float* __restrict__ W1,
                                             const float* __restrict__ b1, u16* __restrict__ Hh){
  int blk = blockIdx.x; int b = blk>>6, c0 = (blk&63)<<6;
  int tid = threadIdx.x, lane = tid&63, w = tid>>6;
  __shared__ __align__(16) u16 az[64*PIT];   // [m][k]
  __shared__ __align__(16) u16 wt[64*PIT];   // [n][k]
  f32x4 acc[4] = {{0,0,0,0},{0,0,0,0},{0,0,0,0},{0,0,0,0}};
  int rr = tid>>2, seg = tid&3;
  for (int kc = 0; kc < 16; kc++){
    int k0 = kc*64;
    __syncthreads();
    { // stage A (ZbB rows)
      const u16* src = ZbB + ((size_t)(b*64 + rr))*1024 + k0 + seg*16;
      *reinterpret_cast<uint4*>(&az[rr*PIT + seg*16])   = *reinterpret_cast<const uint4*>(src);
      *reinterpret_cast<uint4*>(&az[rr*PIT + seg*16+8]) = *reinterpret_cast<const uint4*>(src+8);
    }
    { // stage W1 transposed: read [k][n] f32 -> wt[n][k] bf16
      const float* src = W1 + ((size_t)(k0 + rr))*4096 + c0 + seg*16;  // rr = kk
#pragma unroll
      for (int i = 0; i < 4; i++){
        float4 v = *reinterpret_cast<const float4*>(src + i*4);
        wt[(seg*16 + i*4+0)*PIT + rr] = f2b(v.x);
        wt[(seg*16 + i*4+1)*PIT + rr] = f2b(v.y);
        wt[(seg*16 + i*4+2)*PIT + rr] = f2b(v.z);
        wt[(seg*16 + i*4+3)*PIT + rr] = f2b(v.w);
      }
    }
    __syncthreads();
#pragma unroll
    for (int s = 0; s < 2; s++){
      short8 a = *reinterpret_cast<const short8*>(&az[(16*w + (lane&15))*PIT + s*32 + (lane>>4)*8]);
#pragma unroll
      for (int t = 0; t < 4; t++){
        short8 bb = *reinterpret_cast<const short8*>(&wt[(t*16 + (lane&15))*PIT + s*32 + (lane>>4)*8]);
        acc[t] = __builtin_amdgcn_mfma_f32_16x16x32_bf16(a, bb, acc[t], 0, 0, 0);
      }
    }
  }
#pragma unroll
  for (int t = 0; t < 4; t++)
#pragma unroll
    for (int r = 0; r < 4; r++){
      int m = 16*w + (lane>>4)*4 + r;
      int n = c0 + t*16 + (lane&15);
      float val = acc[t][r] + b1[n];
      float g = 0.5f * val * (1.0f + erff(val * 0.70710678f));
      Hh[((size_t)(b*64 + m))*4096 + n] = (m < 50) ? f2b(g) : (u16)0;
    }
}

// ---------------- K6: partials of Hh @ W2 (MFMA, K-split x4) ----------------
__global__ __launch_bounds__(256) void kmlp2p(const u16* __restrict__ Hh, const float* __restrict__ W2,
                                              float* __restrict__ Mpart){
  int blk = blockIdx.x;            // 512 = b(8) * dt(16) * kt(4)
  int kt = blk & 3, dt = (blk >> 2) & 15, b = blk >> 6;
  int d0 = dt*64;
  int tid = threadIdx.x, lane = tid&63, w = tid>>6;
  __shared__ __align__(16) u16 az[64*PIT];
  __shared__ __align__(16) u16 wt[64*PIT];
  f32x4 acc[4] = {{0,0,0,0},{0,0,0,0},{0,0,0,0},{0,0,0,0}};
  int rr = tid>>2, seg = tid&3;
  for (int kc = 0; kc < 16; kc++){
    int k0 = kt*1024 + kc*64;
    __syncthreads();
    {
      const u16* src = Hh + ((size_t)(b*64 + rr))*4096 + k0 + seg*16;
      *reinterpret_cast<uint4*>(&az[rr*PIT + seg*16])   = *reinterpret_cast<const uint4*>(src);
      *reinterpret_cast<uint4*>(&az[rr*PIT + seg*16+8]) = *reinterpret_cast<const uint4*>(src+8);
    }
    {
      const float* src = W2 + ((size_t)(k0 + rr))*1024 + d0 + seg*16;
#pragma unroll
      for (int i = 0; i < 4; i++){
        float4 v = *reinterpret_cast<const float4*>(src + i*4);
        wt[(seg*16 + i*4+0)*PIT + rr] = f2b(v.x);
        wt[(seg*16 + i*4+1)*PIT + rr] = f2b(v.y);
        wt[(seg*16 + i*4+2)*PIT + rr] = f2b(v.z);
        wt[(seg*16 + i*4+3)*PIT + rr] = f2b(v.w);
      }
    }
    __syncthreads();
#pragma unroll
    for (int s = 0; s < 2; s++){
      short8 a = *reinterpret_cast<const short8*>(&az[(16*w + (lane&15))*PIT + s*32 + (lane>>4)*8]);
#pragma unroll
      for (int t = 0; t < 4; t++){
        short8 bb = *reinterpret_cast<const short8*>(&wt[(t*16 + (lane&15))*PIT + s*32 + (lane>>4)*8]);
        acc[t] = __builtin_amdgcn_mfma_f32_16x16x32_bf16(a, bb, acc[t], 0, 0, 0);
      }
    }
  }
#pragma unroll
  for (int t = 0; t < 4; t++)
#pragma unroll
    for (int r = 0; r < 4; r++){
      int m = 16*w + (lane>>4)*4 + r;
      int d = d0 + t*16 + (lane&15);
      if (m < 50) Mpart[(((size_t)(b*4) + kt)*50 + m)*1024 + d] = acc[t][r];
    }
}

// ---------------- K6b: HfT = tanh(sum partials + b2)^T, bf16, m>=50 zero ----------------
__global__ void kredT(const float* __restrict__ Mpart, const float* __restrict__ b2, u16* __restrict__ HfT){
  int e = blockIdx.x*256 + threadIdx.x;    // grid 2048 -> 524288 over [b][m(64)][d]
  int b = e >> 16, rem = e & 65535;
  int m = rem >> 10, d = rem & 1023;
  u16 outv = 0;
  if (m < 50){
    const float* p = Mpart + (size_t)b*204800 + m*1024 + d;
    float s = p[0] + p[51200] + p[102400] + p[153600] + b2[d];
    outv = f2b(tanhf(s));
  }
  HfT[((size_t)(b*1024) + d)*64 + m] = outv;
}

// ---------------- K7: out = x + C @ Hf (MFMA) ----------------
__global__ __launch_bounds__(256) void kdec(const float* __restrict__ x, const u16* __restrict__ C,
                                            const u16* __restrict__ HfT, float* __restrict__ out){
  int blk = blockIdx.x; int b = blk>>6, n0 = (blk&63)<<6;
  int tid = threadIdx.x, lane = tid&63, w = tid>>6;
  __shared__ __align__(16) u16 ctile[64*PIT];   // [tok][m]
  __shared__ __align__(16) u16 htile[64*PIT];   // [d][m]
  int rr = tid>>2, seg = tid&3;
  {
    const u16* src = C + ((size_t)(b*4096 + n0 + rr))*64 + seg*16;
    *reinterpret_cast<uint4*>(&ctile[rr*PIT + seg*16])   = *reinterpret_cast<const uint4*>(src);
    *reinterpret_cast<uint4*>(&ctile[rr*PIT + seg*16+8]) = *reinterpret_cast<const uint4*>(src+8);
  }
  __syncthreads();
  short8 afrag[2];
#pragma unroll
  for (int s = 0; s < 2; s++)
    afrag[s] = *reinterpret_cast<const short8*>(&ctile[(16*w + (lane&15))*PIT + s*32 + (lane>>4)*8]);
  for (int dt2 = 0; dt2 < 16; dt2++){
    int d0 = dt2*64;
    __syncthreads();
    {
      const u16* src = HfT + ((size_t)(b*1024 + d0 + rr))*64 + seg*16;
      *reinterpret_cast<uint4*>(&htile[rr*PIT + seg*16])   = *reinterpret_cast<const uint4*>(src);
      *reinterpret_cast<uint4*>(&htile[rr*PIT + seg*16+8]) = *reinterpret_cast<const uint4*>(src+8);
    }
    __syncthreads();
    f32x4 acc[4] = {{0,0,0,0},{0,0,0,0},{0,0,0,0},{0,0,0,0}};
#pragma unroll
    for (int s = 0; s < 2; s++){
#pragma unroll
      for (int t = 0; t < 4; t++){
        short8 bb = *reinterpret_cast<const short8*>(&htile[(t*16 + (lane&15))*PIT + s*32 + (lane>>4)*8]);
        acc[t] = __builtin_amdgcn_mfma_f32_16x16x32_bf16(afrag[s], bb, acc[t], 0, 0, 0);
      }
    }
#pragma unroll
    for (int t = 0; t < 4; t++)
#pragma unroll
      for (int r = 0; r < 4; r++){
        int n = n0 + 16*w + (lane>>4)*4 + r;
        int d = d0 + t*16 + (lane&15);
        size_t o = ((size_t)(b*4096 + n))*1024 + d;
        out[o] = x[o] + acc[t][r];
      }
  }
}

// ---------------- launch ----------------
extern "C" void kernel_launch(void* const* d_in, const int* in_sizes, int n_in,
                              void* d_out, int out_size, void* d_ws, size_t ws_size,
                              hipStream_t stream) {
  (void)in_sizes; (void)n_in; (void)out_size;
  if (ws_size < (size_t)19755264) return;
  const float* x  = (const float*)d_in[0];
  const float* pn = (const float*)d_in[1];
  const float* W1 = (const float*)d_in[8];
  const float* b1 = (const float*)d_in[9];
  const float* W2 = (const float*)d_in[10];
  const float* b2 = (const float*)d_in[11];
  float* out = (float*)d_out;
  char* ws = (char*)d_ws;

  // Overlapped layout (stream-ordered liveness):
  u16*   C   = (u16*)(ws);                      // [0, 4.19MB)        live kC->kdec
  u16*   CT  = (u16*)(ws + 4194304);            // CT region 4.19MB:  CT live kC->kHp2
  float* ZB  = (float*)(ws + 4194304);          //   reuses CT space  (kapply->knoise)
  u16*   ZbB = (u16*)(ws + 4194304 + 1638400);  //   (knoise->kmlp1)
  u16*   HfT = (u16*)(ws + 4194304 + 2686976);  //   (kredT->kdec)
  u16*   Hh  = (u16*)(ws + 8388608);            // Hh region 4.19MB:  Hh live kmlp1->kmlp2p
  u16*   Hb  = (u16*)(ws + 8388608);            //   reuses Hh space  (kredH->kgram)
  float* H   = (float*)(ws + 8388608 + 1048576);//   (kredH->kapply)
  float* HP  = (float*)(ws + 12582912);         // partials 6.55MB: kHp2->kredH, kmlp2p->kredT
  u16*   PT  = (u16*)(ws + 19136512);           // 131,072 B
  float* G   = (float*)(ws + 19267584);         // 80,000 B
  float* WM  = (float*)(ws + 19347584);         // 80,000 B

  hipLaunchKernelGGL(kprep,  dim3(64),   dim3(256), 0, stream, pn, PT);
  hipLaunchKernelGGL(kC,     dim3(512),  dim3(256), 0, stream, x, PT, C, CT);
  hipLaunchKernelGGL(kHp2,   dim3(512),  dim3(256), 0, stream, x, CT, HP);
  hipLaunchKernelGGL(kredH,  dim3(1600), dim3(256), 0, stream, HP, H, Hb);
  hipLaunchKernelGGL(kpadHb, dim3(448),  dim3(256), 0, stream, Hb);
  hipLaunchKernelGGL(kgram,  dim3(8),    dim3(256), 0, stream, Hb, G);
  hipLaunchKernelGGL(kns3,   dim3(8),    dim3(256), 0, stream, G, WM);
  hipLaunchKernelGGL(kapply, dim3(128),  dim3(256), 0, stream, H, WM, ZB);
  hipLaunchKernelGGL(knoise, dim3(512),  dim3(256), 0, stream, ZB, ZbB);
  hipLaunchKernelGGL(kmlp1,  dim3(512),  dim3(256), 0, stream, ZbB, W1, b1, Hh);
  hipLaunchKernelGGL(kmlp2p, dim3(512),  dim3(256), 0, stream, Hh, W2, HP);
  hipLaunchKernelGGL(kredT,  dim3(2048), dim3(256), 0, stream, HP, b2, HfT);
  hipLaunchKernelGGL(kdec,   dim3(512),  dim3(256), 0, stream, x, C, HfT, out);
}

// Round 7
// 271.338 us; speedup vs baseline: 3.8581x; 1.1535x over previous
//
#include <hip/hip_runtime.h>
#include <stdint.h>
#include <math.h>

#define NS_ITERS 26
#define PIT 72   // LDS row pitch in shorts (144B: 16B-aligned, bank-spread)
#define P2  72   // pitch for kns3 matrices

typedef unsigned short u16;
typedef __attribute__((ext_vector_type(8))) short short8;
typedef __attribute__((ext_vector_type(4))) float f32x4;

__device__ __forceinline__ u16 f2b(float f){
  unsigned u = __float_as_uint(f);
  unsigned r = (u + 0x7FFFu + ((u>>16)&1u)) >> 16;
  return (u16)r;
}
__device__ __forceinline__ float b2f(u16 h){ return __uint_as_float(((unsigned)h)<<16); }

// ---------------- threefry2x32 (JAX-compatible) ----------------
__host__ __device__ constexpr uint32_t rotl32(uint32_t v, int n){ return (v<<n)|(v>>(32-n)); }
struct TFOut { uint32_t a, b; };
__host__ __device__ constexpr TFOut tf2x32(uint32_t k0, uint32_t k1, uint32_t x0, uint32_t x1){
  uint32_t ks2 = k0 ^ k1 ^ 0x1BD11BDAu;
  x0 += k0; x1 += k1;
#define TFR(R) x0 += x1; x1 = rotl32(x1,(R)) ^ x0;
  TFR(13) TFR(15) TFR(26) TFR(6)
  x0 += k1; x1 += ks2 + 1u;
  TFR(17) TFR(29) TFR(16) TFR(24)
  x0 += ks2; x1 += k0 + 2u;
  TFR(13) TFR(15) TFR(26) TFR(6)
  x0 += k0; x1 += k1 + 3u;
  TFR(17) TFR(29) TFR(16) TFR(24)
  x0 += k1; x1 += ks2 + 4u;
  TFR(13) TFR(15) TFR(26) TFR(6)
  x0 += ks2; x1 += k0 + 5u;
#undef TFR
  return TFOut{x0, x1};
}

__device__ __forceinline__ float erfinv_f32(float x){
  float w = -log1pf(-x*x);
  float p;
  if (w < 5.0f) {
    w -= 2.5f;
    p = 2.81022636e-08f;
    p = fmaf(p, w, 3.43273939e-07f);
    p = fmaf(p, w, -3.5233877e-06f);
    p = fmaf(p, w, -4.39150654e-06f);
    p = fmaf(p, w, 0.00021858087f);
    p = fmaf(p, w, -0.00125372503f);
    p = fmaf(p, w, -0.00417768164f);
    p = fmaf(p, w, 0.246640727f);
    p = fmaf(p, w, 1.50140941f);
  } else {
    w = sqrtf(w) - 3.0f;
    p = -0.000200214257f;
    p = fmaf(p, w, 0.000100950558f);
    p = fmaf(p, w, 0.00134934322f);
    p = fmaf(p, w, -0.00367342844f);
    p = fmaf(p, w, 0.00573950773f);
    p = fmaf(p, w, -0.0076224613f);
    p = fmaf(p, w, 0.00943887047f);
    p = fmaf(p, w, 1.00167406f);
    p = fmaf(p, w, 2.83297682f);
  }
  return p * x;
}

// ---------------- K1: primes -> PT bf16 [64][1024], unit-normalized, rows>=50 zero ----
__global__ __launch_bounds__(256) void kprep(const float* __restrict__ prime, u16* __restrict__ PT){
  int m = blockIdx.x;
  u16* dst = PT + m*1024;
  if (m >= 50){ for (int k = threadIdx.x; k < 1024; k += 256) dst[k] = 0; return; }
  __shared__ float red[256];
  const float* pr = prime + m*1024;
  float ss = 0.f;
  for (int k = threadIdx.x; k < 1024; k += 256){ float v = pr[k]; ss = fmaf(v,v,ss); }
  red[threadIdx.x] = ss; __syncthreads();
  for (int s = 128; s > 0; s >>= 1){ if (threadIdx.x < s) red[threadIdx.x] += red[threadIdx.x+s]; __syncthreads(); }
  float sc = 1.0f / fmaxf(sqrtf(red[0]), 1e-12f);
  for (int k = threadIdx.x; k < 1024; k += 256) dst[k] = f2b(pr[k]*sc);
}

// ---------------- K2: MFMA logits + softmax -> C[n][64] bf16 and CT[m][4096n] bf16 ----
__global__ __launch_bounds__(256) void kC(const float* __restrict__ x, const u16* __restrict__ PT,
                                          u16* __restrict__ C, u16* __restrict__ CT){
  int blk = blockIdx.x; int b = blk>>6, n0 = (blk&63)<<6;
  int tid = threadIdx.x, lane = tid&63, w = tid>>6;
  __shared__ __align__(16) u16 xs[64*PIT];
  __shared__ __align__(16) u16 ps[64*PIT];
  __shared__ float sq[64][5];
  f32x4 acc[4] = {{0,0,0,0},{0,0,0,0},{0,0,0,0},{0,0,0,0}};
  float sqa = 0.f;
  int stok = tid>>2, sseg = tid&3;                 // staging map
  int qtok = tid&63, qg = tid>>6;                  // sumsq map
  const float* xb = x + ((size_t)(b*4096 + n0))*1024;
  for (int kc = 0; kc < 16; kc++){
    int k0 = kc*64;
    __syncthreads();
    { // stage x (cvt bf16): 16 f32 per thread
      const float* src = xb + (size_t)stok*1024 + k0 + sseg*16;
      u16* d = &xs[stok*PIT + sseg*16];
#pragma unroll
      for (int i = 0; i < 4; i++){
        float4 v = *reinterpret_cast<const float4*>(src + i*4);
        d[i*4+0]=f2b(v.x); d[i*4+1]=f2b(v.y); d[i*4+2]=f2b(v.z); d[i*4+3]=f2b(v.w);
      }
    }
    { // stage P rows
      const u16* src = PT + (size_t)stok*1024 + k0 + sseg*16;
      *reinterpret_cast<uint4*>(&ps[stok*PIT + sseg*16])   = *reinterpret_cast<const uint4*>(src);
      *reinterpret_cast<uint4*>(&ps[stok*PIT + sseg*16+8]) = *reinterpret_cast<const uint4*>(src+8);
    }
    __syncthreads();
    { // sumsq of this token's 16 values
      const u16* xr = &xs[qtok*PIT + qg*16];
#pragma unroll
      for (int j = 0; j < 16; j++){ float v = b2f(xr[j]); sqa = fmaf(v,v,sqa); }
    }
#pragma unroll
    for (int s = 0; s < 2; s++){
      short8 a = *reinterpret_cast<const short8*>(&xs[(16*w + (lane&15))*PIT + s*32 + (lane>>4)*8]);
#pragma unroll
      for (int t = 0; t < 4; t++){
        short8 bb = *reinterpret_cast<const short8*>(&ps[(t*16 + (lane&15))*PIT + s*32 + (lane>>4)*8]);
        acc[t] = __builtin_amdgcn_mfma_f32_16x16x32_bf16(a, bb, acc[t], 0, 0, 0);
      }
    }
  }
  sq[qtok][qg] = sqa;
  __syncthreads();
  if (tid < 64){
    float ss = sq[tid][0]+sq[tid][1]+sq[tid][2]+sq[tid][3];
    sq[tid][4] = 10.0f / fmaxf(sqrtf(ss), 1e-12f);
  }
  __syncthreads();
  // softmax per token (rows spread over lane>>4 groups; primes = lane&15 + 16*t)
  u16* cl = xs;  // reuse
#pragma unroll
  for (int r = 0; r < 4; r++){
    int gt = 16*w + (lane>>4)*4 + r;
    float scale = sq[gt][4];
    float v[4];
#pragma unroll
    for (int t = 0; t < 4; t++) v[t] = acc[t][r] * scale;
    if ((lane&15) >= 2) v[3] = -1e30f;
    float mx = fmaxf(fmaxf(v[0],v[1]), fmaxf(v[2],v[3]));
#pragma unroll
    for (int off = 1; off < 16; off <<= 1) mx = fmaxf(mx, __shfl_xor(mx, off, 64));
    float e[4], sum = 0.f;
#pragma unroll
    for (int t = 0; t < 4; t++){ e[t] = __expf(v[t]-mx); sum += e[t]; }
#pragma unroll
    for (int off = 1; off < 16; off <<= 1) sum += __shfl_xor(sum, off, 64);
    float inv = 1.0f / sum;
#pragma unroll
    for (int t = 0; t < 4; t++) cl[gt*PIT + t*16 + (lane&15)] = f2b(e[t]*inv);
  }
  __syncthreads();
  { // C write (row-major) b128
    u16* dst = C + ((size_t)(b*4096 + n0 + stok))*64 + sseg*16;
    *reinterpret_cast<uint4*>(dst)   = *reinterpret_cast<const uint4*>(&cl[stok*PIT + sseg*16]);
    *reinterpret_cast<uint4*>(dst+8) = *reinterpret_cast<const uint4*>(&cl[stok*PIT + sseg*16+8]);
  }
  { // CT write (transposed)
    int m = tid>>2, nseg = tid&3;
    unsigned vs[8];
#pragma unroll
    for (int j = 0; j < 8; j++){
      u16 lo = cl[(nseg*16 + 2*j)*PIT + m];
      u16 hi = cl[(nseg*16 + 2*j+1)*PIT + m];
      vs[j] = (unsigned)lo | ((unsigned)hi<<16);
    }
    u16* dst = CT + ((size_t)(b*64 + m))*4096 + n0 + nseg*16;
    uint4 w0; w0.x=vs[0]; w0.y=vs[1]; w0.z=vs[2]; w0.w=vs[3];
    uint4 w1; w1.x=vs[4]; w1.y=vs[5]; w1.z=vs[6]; w1.w=vs[7];
    *reinterpret_cast<uint4*>(dst)   = w0;
    *reinterpret_cast<uint4*>(dst+8) = w1;
  }
}

// ---------------- K3: H_prime partials = CT @ x over n-quarter (MFMA, K-split x4) ----
__global__ __launch_bounds__(256) void kHp2(const float* __restrict__ x, const u16* __restrict__ CT,
                                            float* __restrict__ Hpart){
  int blk = blockIdx.x;            // 512 = b(8) * dt(16) * kt(4)
  int kt = blk & 3, dt = (blk >> 2) & 15, b = blk >> 6;
  int d0 = dt*64;
  int tid = threadIdx.x, lane = tid&63, w = tid>>6;
  __shared__ __align__(16) u16 cs[64*PIT];    // [m][n]
  __shared__ __align__(16) u16 xt[64*PIT];    // [d][n]
  f32x4 acc[4] = {{0,0,0,0},{0,0,0,0},{0,0,0,0},{0,0,0,0}};
  int nn = tid>>2, seg = tid&3;
  for (int nc = 0; nc < 16; nc++){
    int n0 = kt*1024 + nc*64;
    __syncthreads();
    { // stage CT rows [m][n-chunk]
      const u16* src = CT + ((size_t)(b*64 + nn))*4096 + n0 + seg*16;  // nn = m here
      *reinterpret_cast<uint4*>(&cs[nn*PIT + seg*16])   = *reinterpret_cast<const uint4*>(src);
      *reinterpret_cast<uint4*>(&cs[nn*PIT + seg*16+8]) = *reinterpret_cast<const uint4*>(src+8);
    }
    { // stage x transposed: read [n][d] f32, write [d][n] bf16
      const float* src = x + ((size_t)(b*4096 + n0 + nn))*1024 + d0 + seg*16;
#pragma unroll
      for (int i = 0; i < 4; i++){
        float4 v = *reinterpret_cast<const float4*>(src + i*4);
        xt[(seg*16 + i*4+0)*PIT + nn] = f2b(v.x);
        xt[(seg*16 + i*4+1)*PIT + nn] = f2b(v.y);
        xt[(seg*16 + i*4+2)*PIT + nn] = f2b(v.z);
        xt[(seg*16 + i*4+3)*PIT + nn] = f2b(v.w);
      }
    }
    __syncthreads();
#pragma unroll
    for (int s = 0; s < 2; s++){
      short8 a = *reinterpret_cast<const short8*>(&cs[(16*w + (lane&15))*PIT + s*32 + (lane>>4)*8]);
#pragma unroll
      for (int t = 0; t < 4; t++){
        short8 bb = *reinterpret_cast<const short8*>(&xt[(t*16 + (lane&15))*PIT + s*32 + (lane>>4)*8]);
        acc[t] = __builtin_amdgcn_mfma_f32_16x16x32_bf16(a, bb, acc[t], 0, 0, 0);
      }
    }
  }
#pragma unroll
  for (int t = 0; t < 4; t++)
#pragma unroll
    for (int r = 0; r < 4; r++){
      int m = 16*w + (lane>>4)*4 + r;
      int d = d0 + t*16 + (lane&15);
      if (m < 50) Hpart[(((size_t)(b*4) + kt)*50 + m)*1024 + d] = acc[t][r];
    }
}

// ---------------- K3b: reduce partials -> H f32 + Hb bf16 (grid 1600) ----------------
__global__ void kredH(const float* __restrict__ Hpart, float* __restrict__ H, u16* __restrict__ Hb){
  int e = blockIdx.x*256 + threadIdx.x;    // grid 1600 -> 409600 over [b][m(50)][d]
  int b = e / 51200; int rem = e - b*51200;
  int m = rem >> 10, d = rem & 1023;
  const float* p = Hpart + (size_t)b*204800 + rem;
  float s = p[0] + p[51200] + p[102400] + p[153600];
  size_t o = ((size_t)(b*64 + m))*1024 + d;
  H[o] = s;
  Hb[o] = f2b(s);
}

// ---------------- K3c: zero pad rows 50..63 of Hb ----------------
__global__ void kpadHb(u16* __restrict__ Hb){
  int e = blockIdx.x*256 + threadIdx.x;   // grid 448 -> 114688 = 8*14*1024
  int b = e / 14336; int rem = e - b*14336;
  int m = 50 + (rem >> 10), d = rem & 1023;
  Hb[((size_t)(b*64 + m))*1024 + d] = 0;
}

// ---------------- K4a: Gram via MFMA: G = Hb Hb^T ----------------
__global__ __launch_bounds__(256) void kgram(const u16* __restrict__ Hb, float* __restrict__ G){
  int b = blockIdx.x;
  int tid = threadIdx.x, lane = tid&63, w = tid>>6;
  __shared__ __align__(16) u16 hs[64*PIT];
  f32x4 acc[4] = {{0,0,0,0},{0,0,0,0},{0,0,0,0},{0,0,0,0}};
  int m = tid>>2, seg = tid&3;
  for (int kc = 0; kc < 16; kc++){
    int k0 = kc*64;
    __syncthreads();
    const u16* src = Hb + ((size_t)(b*64 + m))*1024 + k0 + seg*16;
    *reinterpret_cast<uint4*>(&hs[m*PIT + seg*16])   = *reinterpret_cast<const uint4*>(src);
    *reinterpret_cast<uint4*>(&hs[m*PIT + seg*16+8]) = *reinterpret_cast<const uint4*>(src+8);
    __syncthreads();
#pragma unroll
    for (int s = 0; s < 2; s++){
      short8 a = *reinterpret_cast<const short8*>(&hs[(16*w + (lane&15))*PIT + s*32 + (lane>>4)*8]);
#pragma unroll
      for (int t = 0; t < 4; t++){
        short8 bb = *reinterpret_cast<const short8*>(&hs[(t*16 + (lane&15))*PIT + s*32 + (lane>>4)*8]);
        acc[t] = __builtin_amdgcn_mfma_f32_16x16x32_bf16(a, bb, acc[t], 0, 0, 0);
      }
    }
  }
#pragma unroll
  for (int t = 0; t < 4; t++)
#pragma unroll
    for (int r = 0; r < 4; r++){
      int i = 16*w + (lane>>4)*4 + r;
      int j = t*16 + (lane&15);
      if (i < 50 && j < 50) G[(size_t)b*2500 + i*50 + j] = acc[t][r];
    }
}

// ---------------- K4b: Newton-Schulz invsqrt via MFMA (bf16 fragments, 64x64 padded) ----
__global__ __launch_bounds__(256) void kns3(const float* __restrict__ G, float* __restrict__ Wm){
  int b = blockIdx.x;
  __shared__ __align__(16) u16 Yr[2][64*P2], Yc[2][64*P2], Zr[2][64*P2], Zc[2][64*P2];
  __shared__ __align__(16) u16 Tr[64*P2], Tc[64*P2];
  __shared__ float sv[2];
  int tid = threadIdx.x, lane = tid&63, w = tid>>6;
  int lr = lane>>4, lc = lane&15;
  int row0 = 16*w;
  const float* Gb = G + (size_t)b*2500;
  if (tid < 64){
    float v = (tid < 50) ? Gb[tid*50+tid] : 0.f;
    for (int off = 1; off < 64; off <<= 1) v += __shfl_xor(v, off, 64);
    if (tid == 0){ sv[0] = 1.0f / v; sv[1] = rsqrtf(v); }
  }
  __syncthreads();
  float rs = sv[0];
  for (int idx = tid; idx < 4096; idx += 256){
    int r = idx>>6, c = idx&63;
    float yv = (r<50 && c<50) ? Gb[r*50+c]*rs : ((r==c) ? 1.f : 0.f);
    float zv = (r==c) ? 1.f : 0.f;
    u16 yb = f2b(yv), zb = f2b(zv);
    Yr[0][r*P2+c] = yb; Yc[0][c*P2+r] = yb;
    Zr[0][r*P2+c] = zb; Zc[0][c*P2+r] = zb;
  }
  __syncthreads();
  for (int it = 0; it < NS_ITERS; it++){
    int cur = it & 1, nxt = cur ^ 1;
    { // phase 1: T = 1.5I - 0.5 * Z@Y
      short8 a0 = *reinterpret_cast<const short8*>(&Zr[cur][(row0+lc)*P2 + lr*8]);
      short8 a1 = *reinterpret_cast<const short8*>(&Zr[cur][(row0+lc)*P2 + 32 + lr*8]);
      f32x4 acc[4] = {{0,0,0,0},{0,0,0,0},{0,0,0,0},{0,0,0,0}};
#pragma unroll
      for (int t = 0; t < 4; t++){
        short8 b0 = *reinterpret_cast<const short8*>(&Yc[cur][(t*16+lc)*P2 + lr*8]);
        short8 b1 = *reinterpret_cast<const short8*>(&Yc[cur][(t*16+lc)*P2 + 32 + lr*8]);
        acc[t] = __builtin_amdgcn_mfma_f32_16x16x32_bf16(a0, b0, acc[t], 0, 0, 0);
        acc[t] = __builtin_amdgcn_mfma_f32_16x16x32_bf16(a1, b1, acc[t], 0, 0, 0);
      }
#pragma unroll
      for (int t = 0; t < 4; t++)
#pragma unroll
        for (int r = 0; r < 4; r++){
          int row = row0 + lr*4 + r, col = t*16 + lc;
          float v = ((row==col) ? 1.5f : 0.f) - 0.5f*acc[t][r];
          u16 h = f2b(v);
          Tr[row*P2+col] = h; Tc[col*P2+row] = h;
        }
    }
    __syncthreads();
    { // phase 2: Y' = Y@T ; Z' = T@Z
      short8 ya0 = *reinterpret_cast<const short8*>(&Yr[cur][(row0+lc)*P2 + lr*8]);
      short8 ya1 = *reinterpret_cast<const short8*>(&Yr[cur][(row0+lc)*P2 + 32 + lr*8]);
      short8 ta0 = *reinterpret_cast<const short8*>(&Tr[(row0+lc)*P2 + lr*8]);
      short8 ta1 = *reinterpret_cast<const short8*>(&Tr[(row0+lc)*P2 + 32 + lr*8]);
      f32x4 accY[4] = {{0,0,0,0},{0,0,0,0},{0,0,0,0},{0,0,0,0}};
      f32x4 accZ[4] = {{0,0,0,0},{0,0,0,0},{0,0,0,0},{0,0,0,0}};
#pragma unroll
      for (int t = 0; t < 4; t++){
        short8 tb0 = *reinterpret_cast<const short8*>(&Tc[(t*16+lc)*P2 + lr*8]);
        short8 tb1 = *reinterpret_cast<const short8*>(&Tc[(t*16+lc)*P2 + 32 + lr*8]);
        accY[t] = __builtin_amdgcn_mfma_f32_16x16x32_bf16(ya0, tb0, accY[t], 0, 0, 0);
        accY[t] = __builtin_amdgcn_mfma_f32_16x16x32_bf16(ya1, tb1, accY[t], 0, 0, 0);
        short8 zb0 = *reinterpret_cast<const short8*>(&Zc[cur][(t*16+lc)*P2 + lr*8]);
        short8 zb1 = *reinterpret_cast<const short8*>(&Zc[cur][(t*16+lc)*P2 + 32 + lr*8]);
        accZ[t] = __builtin_amdgcn_mfma_f32_16x16x32_bf16(ta0, zb0, accZ[t], 0, 0, 0);
        accZ[t] = __builtin_amdgcn_mfma_f32_16x16x32_bf16(ta1, zb1, accZ[t], 0, 0, 0);
      }
#pragma unroll
      for (int t = 0; t < 4; t++)
#pragma unroll
        for (int r = 0; r < 4; r++){
          int row = row0 + lr*4 + r, col = t*16 + lc;
          u16 hy = f2b(accY[t][r]);
          u16 hz = f2b(accZ[t][r]);
          Yr[nxt][row*P2+col] = hy; Yc[nxt][col*P2+row] = hy;
          Zr[nxt][row*P2+col] = hz; Zc[nxt][col*P2+row] = hz;
        }
    }
    __syncthreads();
  }
  float rss = sv[1];
  int fin = NS_ITERS & 1;
  for (int idx = tid; idx < 2500; idx += 256){
    int r = idx/50, c = idx - r*50;
    Wm[(size_t)b*2500 + idx] = b2f(Zr[fin][r*P2+c]) * rss;
  }
}

// ---------------- K4c: H_logic = Wm @ H (fp32 VALU) ----------------
__global__ __launch_bounds__(256) void kapply(const float* __restrict__ H, const float* __restrict__ Wm, float* __restrict__ Zb){
  int blk = blockIdx.x;          // 128 = b(8) * dt(16)
  int dt = blk & 15, b = blk >> 4;
  int d0 = dt*64;
  int tid = threadIdx.x;
  int d = tid & 63, mg = tid >> 6;
  __shared__ __align__(16) float WsT[50*64];
  __shared__ float Hs[50*65];
  for (int idx = tid; idx < 3200; idx += 256){
    int j = idx >> 6, c = idx & 63;
    WsT[idx] = (c < 50) ? Wm[(size_t)b*2500 + c*50 + j] : 0.f;
  }
  for (int idx = tid; idx < 3200; idx += 256){
    int j = idx >> 6, c = idx & 63;
    Hs[j*65 + c] = H[((size_t)(b*64) + j)*1024 + d0 + c];
  }
  __syncthreads();
  float acc[16];
#pragma unroll
  for (int i = 0; i < 16; i++) acc[i] = 0.f;
  for (int j = 0; j < 50; j++){
    float hv = Hs[j*65 + d];
    const float* wb = WsT + j*64 + (mg << 4);
#pragma unroll
    for (int q = 0; q < 4; q++){
      float4 wv = *reinterpret_cast<const float4*>(wb + q*4);
      acc[q*4+0] = fmaf(wv.x, hv, acc[q*4+0]);
      acc[q*4+1] = fmaf(wv.y, hv, acc[q*4+1]);
      acc[q*4+2] = fmaf(wv.z, hv, acc[q*4+2]);
      acc[q*4+3] = fmaf(wv.w, hv, acc[q*4+3]);
    }
  }
#pragma unroll
  for (int i = 0; i < 16; i++){
    int m = (mg << 4) + i;
    if (m < 50) Zb[((size_t)(b*50) + m)*1024 + d0 + d] = acc[i];
  }
}

// ---------------- K4d: noise (threefry) on ZB; emit ZbB bf16 padded ----------------
__global__ __launch_bounds__(256) void knoise(float* __restrict__ z, u16* __restrict__ zb){
  TFOut K1 = tf2x32(0u, 42u, 0u, 0u);
  TFOut K2 = tf2x32(0u, 42u, 0u, 1u);
  int e0 = (blockIdx.x*256 + threadIdx.x)*4;    // over 8*64*1024
  int b = e0 >> 16, rem = e0 & 65535;
  int m = rem >> 10, d = rem & 1023;
  u16* zdst = zb + ((size_t)(b*64 + m))*1024 + d;
  if (m >= 50){
    uint2 zz; zz.x = 0; zz.y = 0;
    *reinterpret_cast<uint2*>(zdst) = zz;
    return;
  }
  size_t zoff = ((size_t)(b*50 + m))*1024 + d;
  float4 v = *reinterpret_cast<float4*>(z + zoff);
  float vv[4] = {v.x, v.y, v.z, v.w};
  uint32_t jbase = (uint32_t)zoff;
#pragma unroll
  for (int q = 0; q < 4; q++){
    uint32_t j = jbase + q;
    TFOut r1 = tf2x32(K1.a, K1.b, 0u, j);
    uint32_t bits = r1.a ^ r1.b;
    float u = __uint_as_float(0x3F800000u | (bits >> 9)) - 1.0f;
    if (u < 0.0464f){
      TFOut r2 = tf2x32(K2.a, K2.b, 0u, j);
      uint32_t nb = r2.a ^ r2.b;
      float ww = __uint_as_float(0x3F800000u | (nb >> 9)) - 1.0f;
      const float lo = -0.99999994f;
      float un = fmaxf(lo, fmaf(ww, 2.0f, lo));
      vv[q] += 0.1f * (1.4142135f * erfinv_f32(un));
    }
  }
  *reinterpret_cast<float4*>(z + zoff) = make_float4(vv[0], vv[1], vv[2], vv[3]);
  uint2 zz;
  zz.x = (unsigned)f2b(vv[0]) | ((unsigned)f2b(vv[1])<<16);
  zz.y = (unsigned)f2b(vv[2]) | ((unsigned)f2b(vv[3])<<16);
  *reinterpret_cast<uint2*>(zdst) = zz;
}

// ---------------- K5: Hh = gelu(ZbB @ W1 + b1) (MFMA; W1 transpose-staged) ----------------
__global__ __launch_bounds__(256) void kmlp1(const u16* __restrict__ ZbB, const float* __restrict__ W1,
                                             const float* __restrict__ b1, u16* __restrict__ Hh){
  int blk = blockIdx.x; int b = blk>>6, c0 = (blk&63)<<6;
  int tid = threadIdx.x, lane = tid&63, w = tid>>6;
  __shared__ __align__(16) u16 az[64*PIT];   // [m][k]
  __shared__ __align__(16) u16 wt[64*PIT];   // [n][k]
  f32x4 acc[4] = {{0,0,0,0},{0,0,0,0},{0,0,0,0},{0,0,0,0}};
  int rr = tid>>2, seg = tid&3;
  for (int kc = 0; kc < 16; kc++){
    int k0 = kc*64;
    __syncthreads();
    { // stage A (ZbB rows)
      const u16* src = ZbB + ((size_t)(b*64 + rr))*1024 + k0 + seg*16;
      *reinterpret_cast<uint4*>(&az[rr*PIT + seg*16])   = *reinterpret_cast<const uint4*>(src);
      *reinterpret_cast<uint4*>(&az[rr*PIT + seg*16+8]) = *reinterpret_cast<const uint4*>(src+8);
    }
    { // stage W1 transposed: read [k][n] f32 -> wt[n][k] bf16
      const float* src = W1 + ((size_t)(k0 + rr))*4096 + c0 + seg*16;  // rr = kk
#pragma unroll
      for (int i = 0; i < 4; i++){
        float4 v = *reinterpret_cast<const float4*>(src + i*4);
        wt[(seg*16 + i*4+0)*PIT + rr] = f2b(v.x);
        wt[(seg*16 + i*4+1)*PIT + rr] = f2b(v.y);
        wt[(seg*16 + i*4+2)*PIT + rr] = f2b(v.z);
        wt[(seg*16 + i*4+3)*PIT + rr] = f2b(v.w);
      }
    }
    __syncthreads();
#pragma unroll
    for (int s = 0; s < 2; s++){
      short8 a = *reinterpret_cast<const short8*>(&az[(16*w + (lane&15))*PIT + s*32 + (lane>>4)*8]);
#pragma unroll
      for (int t = 0; t < 4; t++){
        short8 bb = *reinterpret_cast<const short8*>(&wt[(t*16 + (lane&15))*PIT + s*32 + (lane>>4)*8]);
        acc[t] = __builtin_amdgcn_mfma_f32_16x16x32_bf16(a, bb, acc[t], 0, 0, 0);
      }
    }
  }
#pragma unroll
  for (int t = 0; t < 4; t++)
#pragma unroll
    for (int r = 0; r < 4; r++){
      int m = 16*w + (lane>>4)*4 + r;
      int n = c0 + t*16 + (lane&15);
      float val = acc[t][r] + b1[n];
      float g = 0.5f * val * (1.0f + erff(val * 0.70710678f));
      Hh[((size_t)(b*64 + m))*4096 + n] = (m < 50) ? f2b(g) : (u16)0;
    }
}

// ---------------- K6: partials of Hh @ W2 (MFMA, K-split x4) ----------------
__global__ __launch_bounds__(256) void kmlp2p(const u16* __restrict__ Hh, const float* __restrict__ W2,
                                              float* __restrict__ Mpart){
  int blk = blockIdx.x;            // 512 = b(8) * dt(16) * kt(4)
  int kt = blk & 3, dt = (blk >> 2) & 15, b = blk >> 6;
  int d0 = dt*64;
  int tid = threadIdx.x, lane = tid&63, w = tid>>6;
  __shared__ __align__(16) u16 az[64*PIT];
  __shared__ __align__(16) u16 wt[64*PIT];
  f32x4 acc[4] = {{0,0,0,0},{0,0,0,0},{0,0,0,0},{0,0,0,0}};
  int rr = tid>>2, seg = tid&3;
  for (int kc = 0; kc < 16; kc++){
    int k0 = kt*1024 + kc*64;
    __syncthreads();
    {
      const u16* src = Hh + ((size_t)(b*64 + rr))*4096 + k0 + seg*16;
      *reinterpret_cast<uint4*>(&az[rr*PIT + seg*16])   = *reinterpret_cast<const uint4*>(src);
      *reinterpret_cast<uint4*>(&az[rr*PIT + seg*16+8]) = *reinterpret_cast<const uint4*>(src+8);
    }
    {
      const float* src = W2 + ((size_t)(k0 + rr))*1024 + d0 + seg*16;
#pragma unroll
      for (int i = 0; i < 4; i++){
        float4 v = *reinterpret_cast<const float4*>(src + i*4);
        wt[(seg*16 + i*4+0)*PIT + rr] = f2b(v.x);
        wt[(seg*16 + i*4+1)*PIT + rr] = f2b(v.y);
        wt[(seg*16 + i*4+2)*PIT + rr] = f2b(v.z);
        wt[(seg*16 + i*4+3)*PIT + rr] = f2b(v.w);
      }
    }
    __syncthreads();
#pragma unroll
    for (int s = 0; s < 2; s++){
      short8 a = *reinterpret_cast<const short8*>(&az[(16*w + (lane&15))*PIT + s*32 + (lane>>4)*8]);
#pragma unroll
      for (int t = 0; t < 4; t++){
        short8 bb = *reinterpret_cast<const short8*>(&wt[(t*16 + (lane&15))*PIT + s*32 + (lane>>4)*8]);
        acc[t] = __builtin_amdgcn_mfma_f32_16x16x32_bf16(a, bb, acc[t], 0, 0, 0);
      }
    }
  }
#pragma unroll
  for (int t = 0; t < 4; t++)
#pragma unroll
    for (int r = 0; r < 4; r++){
      int m = 16*w + (lane>>4)*4 + r;
      int d = d0 + t*16 + (lane&15);
      if (m < 50) Mpart[(((size_t)(b*4) + kt)*50 + m)*1024 + d] = acc[t][r];
    }
}

// ---------------- K6b: HfT = tanh(sum partials + b2)^T, bf16, m>=50 zero ----------------
__global__ void kredT(const float* __restrict__ Mpart, const float* __restrict__ b2, u16* __restrict__ HfT){
  int e = blockIdx.x*256 + threadIdx.x;    // grid 2048 -> 524288 over [b][m(64)][d]
  int b = e >> 16, rem = e & 65535;
  int m = rem >> 10, d = rem & 1023;
  u16 outv = 0;
  if (m < 50){
    const float* p = Mpart + (size_t)b*204800 + m*1024 + d;
    float s = p[0] + p[51200] + p[102400] + p[153600] + b2[d];
    outv = f2b(tanhf(s));
  }
  HfT[((size_t)(b*1024) + d)*64 + m] = outv;
}

// ---------------- K7: out = x + C @ Hf (MFMA + LDS-bounced coalesced epilogue) ----------
__global__ __launch_bounds__(256) void kdec2(const float* __restrict__ x, const u16* __restrict__ C,
                                             const u16* __restrict__ HfT, float* __restrict__ out){
  int blk = blockIdx.x;              // 2048 = b(8) * nt(64) * dq(4)
  int dq = blk & 3, nt = (blk >> 2) & 63, b = blk >> 8;
  int n0 = nt << 6;
  int tid = threadIdx.x, lane = tid&63, w = tid>>6;
  __shared__ __align__(16) u16 ctile[64*PIT];   // [tok][m]
  __shared__ __align__(16) u16 htile[64*PIT];   // [d][m]
  __shared__ __align__(16) float obuf[64*68];   // [n][d] f32, pitch 68
  int rr = tid>>2, seg = tid&3;
  {
    const u16* src = C + ((size_t)(b*4096 + n0 + rr))*64 + seg*16;
    *reinterpret_cast<uint4*>(&ctile[rr*PIT + seg*16])   = *reinterpret_cast<const uint4*>(src);
    *reinterpret_cast<uint4*>(&ctile[rr*PIT + seg*16+8]) = *reinterpret_cast<const uint4*>(src+8);
  }
  __syncthreads();
  short8 afrag[2];
#pragma unroll
  for (int s = 0; s < 2; s++)
    afrag[s] = *reinterpret_cast<const short8*>(&ctile[(16*w + (lane&15))*PIT + s*32 + (lane>>4)*8]);
  for (int dt2 = 0; dt2 < 4; dt2++){
    int d0 = (dq*4 + dt2) * 64;
    __syncthreads();
    {
      const u16* src = HfT + ((size_t)(b*1024 + d0 + rr))*64 + seg*16;
      *reinterpret_cast<uint4*>(&htile[rr*PIT + seg*16])   = *reinterpret_cast<const uint4*>(src);
      *reinterpret_cast<uint4*>(&htile[rr*PIT + seg*16+8]) = *reinterpret_cast<const uint4*>(src+8);
    }
    __syncthreads();
    f32x4 acc[4] = {{0,0,0,0},{0,0,0,0},{0,0,0,0},{0,0,0,0}};
#pragma unroll
    for (int s = 0; s < 2; s++){
#pragma unroll
      for (int t = 0; t < 4; t++){
        short8 bb = *reinterpret_cast<const short8*>(&htile[(t*16 + (lane&15))*PIT + s*32 + (lane>>4)*8]);
        acc[t] = __builtin_amdgcn_mfma_f32_16x16x32_bf16(afrag[s], bb, acc[t], 0, 0, 0);
      }
    }
    // scatter acc into LDS [n][d] f32
#pragma unroll
    for (int t = 0; t < 4; t++)
#pragma unroll
      for (int r = 0; r < 4; r++){
        int nl = 16*w + (lane>>4)*4 + r;
        int dl = t*16 + (lane&15);
        obuf[nl*68 + dl] = acc[t][r];
      }
    __syncthreads();
    // coalesced epilogue: 1024 float4-slots (64 rows x 16 slots), 4 per thread
#pragma unroll
    for (int pass = 0; pass < 4; pass++){
      int s2 = tid + pass*256;
      int nl = s2 >> 4, sg = s2 & 15;
      size_t o = ((size_t)(b*4096 + n0 + nl))*1024 + d0 + sg*4;
      float4 xv = *reinterpret_cast<const float4*>(x + o);
      const float* ob = &obuf[nl*68 + sg*4];
      float4 ov;
      ov.x = xv.x + ob[0];
      ov.y = xv.y + ob[1];
      ov.z = xv.z + ob[2];
      ov.w = xv.w + ob[3];
      *reinterpret_cast<float4*>(out + o) = ov;
    }
  }
}

// ---------------- launch ----------------
extern "C" void kernel_launch(void* const* d_in, const int* in_sizes, int n_in,
                              void* d_out, int out_size, void* d_ws, size_t ws_size,
                              hipStream_t stream) {
  (void)in_sizes; (void)n_in; (void)out_size;
  if (ws_size < (size_t)19755264) return;
  const float* x  = (const float*)d_in[0];
  const float* pn = (const float*)d_in[1];
  const float* W1 = (const float*)d_in[8];
  const float* b1 = (const float*)d_in[9];
  const float* W2 = (const float*)d_in[10];
  const float* b2 = (const float*)d_in[11];
  float* out = (float*)d_out;
  char* ws = (char*)d_ws;

  // Overlapped layout (stream-ordered liveness):
  u16*   C   = (u16*)(ws);                      // [0, 4.19MB)        live kC->kdec
  u16*   CT  = (u16*)(ws + 4194304);            // CT region 4.19MB:  CT live kC->kHp2
  float* ZB  = (float*)(ws + 4194304);          //   reuses CT space  (kapply->knoise)
  u16*   ZbB = (u16*)(ws + 4194304 + 1638400);  //   (knoise->kmlp1)
  u16*   HfT = (u16*)(ws + 4194304 + 2686976);  //   (kredT->kdec)
  u16*   Hh  = (u16*)(ws + 8388608);            // Hh region 4.19MB:  Hh live kmlp1->kmlp2p
  u16*   Hb  = (u16*)(ws + 8388608);            //   reuses Hh space  (kredH->kgram)
  float* H   = (float*)(ws + 8388608 + 1048576);//   (kredH->kapply)
  float* HP  = (float*)(ws + 12582912);         // partials 6.55MB: kHp2->kredH, kmlp2p->kredT
  u16*   PT  = (u16*)(ws + 19136512);           // 131,072 B
  float* G   = (float*)(ws + 19267584);         // 80,000 B
  float* WM  = (float*)(ws + 19347584);         // 80,000 B

  hipLaunchKernelGGL(kprep,  dim3(64),   dim3(256), 0, stream, pn, PT);
  hipLaunchKernelGGL(kC,     dim3(512),  dim3(256), 0, stream, x, PT, C, CT);
  hipLaunchKernelGGL(kHp2,   dim3(512),  dim3(256), 0, stream, x, CT, HP);
  hipLaunchKernelGGL(kredH,  dim3(1600), dim3(256), 0, stream, HP, H, Hb);
  hipLaunchKernelGGL(kpadHb, dim3(448),  dim3(256), 0, stream, Hb);
  hipLaunchKernelGGL(kgram,  dim3(8),    dim3(256), 0, stream, Hb, G);
  hipLaunchKernelGGL(kns3,   dim3(8),    dim3(256), 0, stream, G, WM);
  hipLaunchKernelGGL(kapply, dim3(128),  dim3(256), 0, stream, H, WM, ZB);
  hipLaunchKernelGGL(knoise, dim3(512),  dim3(256), 0, stream, ZB, ZbB);
  hipLaunchKernelGGL(kmlp1,  dim3(512),  dim3(256), 0, stream, ZbB, W1, b1, Hh);
  hipLaunchKernelGGL(kmlp2p, dim3(512),  dim3(256), 0, stream, Hh, W2, HP);
  hipLaunchKernelGGL(kredT,  dim3(2048), dim3(256), 0, stream, HP, b2, HfT);
  hipLaunchKernelGGL(kdec2,  dim3(2048), dim3(256), 0, stream, x, C, HfT, out);
}

// Round 8
// 260.979 us; speedup vs baseline: 4.0113x; 1.0397x over previous
//
#include <hip/hip_runtime.h>
#include <stdint.h>
#include <math.h>

#define NS_ITERS 26
#define PIT 72   // LDS row pitch in shorts (144B: 16B-aligned, bank-spread)
#define P2  72   // pitch for kns3 matrices

typedef unsigned short u16;
typedef __attribute__((ext_vector_type(8))) short short8;
typedef __attribute__((ext_vector_type(4))) float f32x4;

__device__ __forceinline__ u16 f2b(float f){
  unsigned u = __float_as_uint(f);
  unsigned r = (u + 0x7FFFu + ((u>>16)&1u)) >> 16;
  return (u16)r;
}
__device__ __forceinline__ float b2f(u16 h){ return __uint_as_float(((unsigned)h)<<16); }
__device__ __forceinline__ unsigned pk2(float lo, float hi){
  return (unsigned)f2b(lo) | ((unsigned)f2b(hi) << 16);
}

// ---------------- threefry2x32 (JAX-compatible) ----------------
__host__ __device__ constexpr uint32_t rotl32(uint32_t v, int n){ return (v<<n)|(v>>(32-n)); }
struct TFOut { uint32_t a, b; };
__host__ __device__ constexpr TFOut tf2x32(uint32_t k0, uint32_t k1, uint32_t x0, uint32_t x1){
  uint32_t ks2 = k0 ^ k1 ^ 0x1BD11BDAu;
  x0 += k0; x1 += k1;
#define TFR(R) x0 += x1; x1 = rotl32(x1,(R)) ^ x0;
  TFR(13) TFR(15) TFR(26) TFR(6)
  x0 += k1; x1 += ks2 + 1u;
  TFR(17) TFR(29) TFR(16) TFR(24)
  x0 += ks2; x1 += k0 + 2u;
  TFR(13) TFR(15) TFR(26) TFR(6)
  x0 += k0; x1 += k1 + 3u;
  TFR(17) TFR(29) TFR(16) TFR(24)
  x0 += k1; x1 += ks2 + 4u;
  TFR(13) TFR(15) TFR(26) TFR(6)
  x0 += ks2; x1 += k0 + 5u;
#undef TFR
  return TFOut{x0, x1};
}

__device__ __forceinline__ float erfinv_f32(float x){
  float w = -log1pf(-x*x);
  float p;
  if (w < 5.0f) {
    w -= 2.5f;
    p = 2.81022636e-08f;
    p = fmaf(p, w, 3.43273939e-07f);
    p = fmaf(p, w, -3.5233877e-06f);
    p = fmaf(p, w, -4.39150654e-06f);
    p = fmaf(p, w, 0.00021858087f);
    p = fmaf(p, w, -0.00125372503f);
    p = fmaf(p, w, -0.00417768164f);
    p = fmaf(p, w, 0.246640727f);
    p = fmaf(p, w, 1.50140941f);
  } else {
    w = sqrtf(w) - 3.0f;
    p = -0.000200214257f;
    p = fmaf(p, w, 0.000100950558f);
    p = fmaf(p, w, 0.00134934322f);
    p = fmaf(p, w, -0.00367342844f);
    p = fmaf(p, w, 0.00573950773f);
    p = fmaf(p, w, -0.0076224613f);
    p = fmaf(p, w, 0.00943887047f);
    p = fmaf(p, w, 1.00167406f);
    p = fmaf(p, w, 2.83297682f);
  }
  return p * x;
}

// ---------------- K1: primes -> PT bf16 [64][1024], unit-normalized, rows>=50 zero ----
__global__ __launch_bounds__(256) void kprep(const float* __restrict__ prime, u16* __restrict__ PT){
  int m = blockIdx.x;
  u16* dst = PT + m*1024;
  if (m >= 50){ for (int k = threadIdx.x; k < 1024; k += 256) dst[k] = 0; return; }
  __shared__ float red[256];
  const float* pr = prime + m*1024;
  float ss = 0.f;
  for (int k = threadIdx.x; k < 1024; k += 256){ float v = pr[k]; ss = fmaf(v,v,ss); }
  red[threadIdx.x] = ss; __syncthreads();
  for (int s = 128; s > 0; s >>= 1){ if (threadIdx.x < s) red[threadIdx.x] += red[threadIdx.x+s]; __syncthreads(); }
  float sc = 1.0f / fmaxf(sqrtf(red[0]), 1e-12f);
  for (int k = threadIdx.x; k < 1024; k += 256) dst[k] = f2b(pr[k]*sc);
}

// ---------------- K2: MFMA logits + softmax -> C[n][64] bf16 and CT[m][4096n] bf16 ----
__global__ __launch_bounds__(256) void kC(const float* __restrict__ x, const u16* __restrict__ PT,
                                          u16* __restrict__ C, u16* __restrict__ CT){
  int blk = blockIdx.x; int b = blk>>6, n0 = (blk&63)<<6;
  int tid = threadIdx.x, lane = tid&63, w = tid>>6;
  __shared__ __align__(16) u16 xs[64*PIT];
  __shared__ __align__(16) u16 ps[64*PIT];
  __shared__ float sq[64][5];
  f32x4 acc[4] = {{0,0,0,0},{0,0,0,0},{0,0,0,0},{0,0,0,0}};
  float sqa = 0.f;
  int stok = tid>>2, sseg = tid&3;                 // staging map
  int qtok = tid&63, qg = tid>>6;                  // sumsq map
  const float* xb = x + ((size_t)(b*4096 + n0))*1024;
  for (int kc = 0; kc < 16; kc++){
    int k0 = kc*64;
    __syncthreads();
    { // stage x (cvt bf16, packed uint4 writes)
      const float* src = xb + (size_t)stok*1024 + k0 + sseg*16;
      unsigned p[8];
#pragma unroll
      for (int i = 0; i < 4; i++){
        float4 v = *reinterpret_cast<const float4*>(src + i*4);
        p[2*i]   = pk2(v.x, v.y);
        p[2*i+1] = pk2(v.z, v.w);
      }
      uint4 w0; w0.x=p[0]; w0.y=p[1]; w0.z=p[2]; w0.w=p[3];
      uint4 w1; w1.x=p[4]; w1.y=p[5]; w1.z=p[6]; w1.w=p[7];
      *reinterpret_cast<uint4*>(&xs[stok*PIT + sseg*16])     = w0;
      *reinterpret_cast<uint4*>(&xs[stok*PIT + sseg*16 + 8]) = w1;
    }
    { // stage P rows
      const u16* src = PT + (size_t)stok*1024 + k0 + sseg*16;
      *reinterpret_cast<uint4*>(&ps[stok*PIT + sseg*16])   = *reinterpret_cast<const uint4*>(src);
      *reinterpret_cast<uint4*>(&ps[stok*PIT + sseg*16+8]) = *reinterpret_cast<const uint4*>(src+8);
    }
    __syncthreads();
    { // sumsq of this token's 16 values
      const u16* xr = &xs[qtok*PIT + qg*16];
#pragma unroll
      for (int j = 0; j < 16; j++){ float v = b2f(xr[j]); sqa = fmaf(v,v,sqa); }
    }
#pragma unroll
    for (int s = 0; s < 2; s++){
      short8 a = *reinterpret_cast<const short8*>(&xs[(16*w + (lane&15))*PIT + s*32 + (lane>>4)*8]);
#pragma unroll
      for (int t = 0; t < 4; t++){
        short8 bb = *reinterpret_cast<const short8*>(&ps[(t*16 + (lane&15))*PIT + s*32 + (lane>>4)*8]);
        acc[t] = __builtin_amdgcn_mfma_f32_16x16x32_bf16(a, bb, acc[t], 0, 0, 0);
      }
    }
  }
  sq[qtok][qg] = sqa;
  __syncthreads();
  if (tid < 64){
    float ss = sq[tid][0]+sq[tid][1]+sq[tid][2]+sq[tid][3];
    sq[tid][4] = 10.0f / fmaxf(sqrtf(ss), 1e-12f);
  }
  __syncthreads();
  // softmax per token (rows spread over lane>>4 groups; primes = lane&15 + 16*t)
  u16* cl = xs;  // reuse
#pragma unroll
  for (int r = 0; r < 4; r++){
    int gt = 16*w + (lane>>4)*4 + r;
    float scale = sq[gt][4];
    float v[4];
#pragma unroll
    for (int t = 0; t < 4; t++) v[t] = acc[t][r] * scale;
    if ((lane&15) >= 2) v[3] = -1e30f;
    float mx = fmaxf(fmaxf(v[0],v[1]), fmaxf(v[2],v[3]));
#pragma unroll
    for (int off = 1; off < 16; off <<= 1) mx = fmaxf(mx, __shfl_xor(mx, off, 64));
    float e[4], sum = 0.f;
#pragma unroll
    for (int t = 0; t < 4; t++){ e[t] = __expf(v[t]-mx); sum += e[t]; }
#pragma unroll
    for (int off = 1; off < 16; off <<= 1) sum += __shfl_xor(sum, off, 64);
    float inv = 1.0f / sum;
#pragma unroll
    for (int t = 0; t < 4; t++) cl[gt*PIT + t*16 + (lane&15)] = f2b(e[t]*inv);
  }
  __syncthreads();
  { // C write (row-major) b128
    u16* dst = C + ((size_t)(b*4096 + n0 + stok))*64 + sseg*16;
    *reinterpret_cast<uint4*>(dst)   = *reinterpret_cast<const uint4*>(&cl[stok*PIT + sseg*16]);
    *reinterpret_cast<uint4*>(dst+8) = *reinterpret_cast<const uint4*>(&cl[stok*PIT + sseg*16+8]);
  }
  { // CT write (transposed)
    int m = tid>>2, nseg = tid&3;
    unsigned vs[8];
#pragma unroll
    for (int j = 0; j < 8; j++){
      u16 lo = cl[(nseg*16 + 2*j)*PIT + m];
      u16 hi = cl[(nseg*16 + 2*j+1)*PIT + m];
      vs[j] = (unsigned)lo | ((unsigned)hi<<16);
    }
    u16* dst = CT + ((size_t)(b*64 + m))*4096 + n0 + nseg*16;
    uint4 w0; w0.x=vs[0]; w0.y=vs[1]; w0.z=vs[2]; w0.w=vs[3];
    uint4 w1; w1.x=vs[4]; w1.y=vs[5]; w1.z=vs[6]; w1.w=vs[7];
    *reinterpret_cast<uint4*>(dst)   = w0;
    *reinterpret_cast<uint4*>(dst+8) = w1;
  }
}

// ---------------- K3: H_prime partials = CT @ x over n-quarter (MFMA, K-split x4) ----
__global__ __launch_bounds__(256) void kHp2(const float* __restrict__ x, const u16* __restrict__ CT,
                                            float* __restrict__ Hpart){
  int blk = blockIdx.x;            // 512 = b(8) * dt(16) * kt(4)
  int kt = blk & 3, dt = (blk >> 2) & 15, b = blk >> 6;
  int d0 = dt*64;
  int tid = threadIdx.x, lane = tid&63, w = tid>>6;
  __shared__ __align__(16) u16 cs[64*PIT];    // [m][n]
  __shared__ __align__(16) u16 xt[64*PIT];    // [d][n]
  f32x4 acc[4] = {{0,0,0,0},{0,0,0,0},{0,0,0,0},{0,0,0,0}};
  int nn = tid>>2, seg = tid&3;
  int np = tid & 31, dsg = tid >> 5;          // n-pair staging map
  for (int nc = 0; nc < 16; nc++){
    int n0 = kt*1024 + nc*64;
    __syncthreads();
    { // stage CT rows [m][n-chunk]
      const u16* src = CT + ((size_t)(b*64 + nn))*4096 + n0 + seg*16;  // nn = m here
      *reinterpret_cast<uint4*>(&cs[nn*PIT + seg*16])   = *reinterpret_cast<const uint4*>(src);
      *reinterpret_cast<uint4*>(&cs[nn*PIT + seg*16+8]) = *reinterpret_cast<const uint4*>(src+8);
    }
    { // stage x transposed: n-paired packed u32 writes (conflict-free)
      const float* s0 = x + ((size_t)(b*4096 + n0 + 2*np))*1024 + d0 + dsg*8;
      const float* s1 = s0 + 1024;
      float4 a0 = *reinterpret_cast<const float4*>(s0);
      float4 a1 = *reinterpret_cast<const float4*>(s0+4);
      float4 c0v = *reinterpret_cast<const float4*>(s1);
      float4 c1v = *reinterpret_cast<const float4*>(s1+4);
      float av[8] = {a0.x,a0.y,a0.z,a0.w,a1.x,a1.y,a1.z,a1.w};
      float cv[8] = {c0v.x,c0v.y,c0v.z,c0v.w,c1v.x,c1v.y,c1v.z,c1v.w};
#pragma unroll
      for (int j2 = 0; j2 < 8; j2++){
        int dd = dsg*8 + j2;
        *reinterpret_cast<unsigned*>(&xt[dd*PIT + 2*np]) = pk2(av[j2], cv[j2]);
      }
    }
    __syncthreads();
#pragma unroll
    for (int s = 0; s < 2; s++){
      short8 a = *reinterpret_cast<const short8*>(&cs[(16*w + (lane&15))*PIT + s*32 + (lane>>4)*8]);
#pragma unroll
      for (int t = 0; t < 4; t++){
        short8 bb = *reinterpret_cast<const short8*>(&xt[(t*16 + (lane&15))*PIT + s*32 + (lane>>4)*8]);
        acc[t] = __builtin_amdgcn_mfma_f32_16x16x32_bf16(a, bb, acc[t], 0, 0, 0);
      }
    }
  }
#pragma unroll
  for (int t = 0; t < 4; t++)
#pragma unroll
    for (int r = 0; r < 4; r++){
      int m = 16*w + (lane>>4)*4 + r;
      int d = d0 + t*16 + (lane&15);
      if (m < 50) Hpart[(((size_t)(b*4) + kt)*50 + m)*1024 + d] = acc[t][r];
    }
}

// ---------------- K3b: reduce partials -> H f32 + Hb bf16, pad rows zeroed (grid 2048) ----
__global__ void kredH(const float* __restrict__ Hpart, float* __restrict__ H, u16* __restrict__ Hb){
  int e = blockIdx.x*256 + threadIdx.x;    // grid 2048 -> 524288 over [b][m(64)][d]
  int b = e >> 16, rem = e & 65535;
  int m = rem >> 10, d = rem & 1023;
  size_t o = ((size_t)(b*64 + m))*1024 + d;
  if (m < 50){
    const float* p = Hpart + (size_t)b*204800 + m*1024 + d;
    float s = p[0] + p[51200] + p[102400] + p[153600];
    H[o] = s;
    Hb[o] = f2b(s);
  } else {
    Hb[o] = 0;
  }
}

// ---------------- K4a: Gram via MFMA: G = Hb Hb^T ----------------
__global__ __launch_bounds__(256) void kgram(const u16* __restrict__ Hb, float* __restrict__ G){
  int b = blockIdx.x;
  int tid = threadIdx.x, lane = tid&63, w = tid>>6;
  __shared__ __align__(16) u16 hs[64*PIT];
  f32x4 acc[4] = {{0,0,0,0},{0,0,0,0},{0,0,0,0},{0,0,0,0}};
  int m = tid>>2, seg = tid&3;
  for (int kc = 0; kc < 16; kc++){
    int k0 = kc*64;
    __syncthreads();
    const u16* src = Hb + ((size_t)(b*64 + m))*1024 + k0 + seg*16;
    *reinterpret_cast<uint4*>(&hs[m*PIT + seg*16])   = *reinterpret_cast<const uint4*>(src);
    *reinterpret_cast<uint4*>(&hs[m*PIT + seg*16+8]) = *reinterpret_cast<const uint4*>(src+8);
    __syncthreads();
#pragma unroll
    for (int s = 0; s < 2; s++){
      short8 a = *reinterpret_cast<const short8*>(&hs[(16*w + (lane&15))*PIT + s*32 + (lane>>4)*8]);
#pragma unroll
      for (int t = 0; t < 4; t++){
        short8 bb = *reinterpret_cast<const short8*>(&hs[(t*16 + (lane&15))*PIT + s*32 + (lane>>4)*8]);
        acc[t] = __builtin_amdgcn_mfma_f32_16x16x32_bf16(a, bb, acc[t], 0, 0, 0);
      }
    }
  }
#pragma unroll
  for (int t = 0; t < 4; t++)
#pragma unroll
    for (int r = 0; r < 4; r++){
      int i = 16*w + (lane>>4)*4 + r;
      int j = t*16 + (lane&15);
      if (i < 50 && j < 50) G[(size_t)b*2500 + i*50 + j] = acc[t][r];
    }
}

// ---------------- K4b: Newton-Schulz invsqrt via MFMA (bf16 fragments, 64x64 padded) ----
__global__ __launch_bounds__(256) void kns3(const float* __restrict__ G, float* __restrict__ Wm){
  int b = blockIdx.x;
  __shared__ __align__(16) u16 Yr[2][64*P2], Yc[2][64*P2], Zr[2][64*P2], Zc[2][64*P2];
  __shared__ __align__(16) u16 Tr[64*P2], Tc[64*P2];
  __shared__ float sv[2];
  int tid = threadIdx.x, lane = tid&63, w = tid>>6;
  int lr = lane>>4, lc = lane&15;
  int row0 = 16*w;
  const float* Gb = G + (size_t)b*2500;
  if (tid < 64){
    float v = (tid < 50) ? Gb[tid*50+tid] : 0.f;
    for (int off = 1; off < 64; off <<= 1) v += __shfl_xor(v, off, 64);
    if (tid == 0){ sv[0] = 1.0f / v; sv[1] = rsqrtf(v); }
  }
  __syncthreads();
  float rs = sv[0];
  for (int idx = tid; idx < 4096; idx += 256){
    int r = idx>>6, c = idx&63;
    float yv = (r<50 && c<50) ? Gb[r*50+c]*rs : ((r==c) ? 1.f : 0.f);
    float zv = (r==c) ? 1.f : 0.f;
    u16 yb = f2b(yv), zb = f2b(zv);
    Yr[0][r*P2+c] = yb; Yc[0][c*P2+r] = yb;
    Zr[0][r*P2+c] = zb; Zc[0][c*P2+r] = zb;
  }
  __syncthreads();
  for (int it = 0; it < NS_ITERS; it++){
    int cur = it & 1, nxt = cur ^ 1;
    { // phase 1: T = 1.5I - 0.5 * Z@Y
      short8 a0 = *reinterpret_cast<const short8*>(&Zr[cur][(row0+lc)*P2 + lr*8]);
      short8 a1 = *reinterpret_cast<const short8*>(&Zr[cur][(row0+lc)*P2 + 32 + lr*8]);
      f32x4 acc[4] = {{0,0,0,0},{0,0,0,0},{0,0,0,0},{0,0,0,0}};
#pragma unroll
      for (int t = 0; t < 4; t++){
        short8 b0 = *reinterpret_cast<const short8*>(&Yc[cur][(t*16+lc)*P2 + lr*8]);
        short8 b1 = *reinterpret_cast<const short8*>(&Yc[cur][(t*16+lc)*P2 + 32 + lr*8]);
        acc[t] = __builtin_amdgcn_mfma_f32_16x16x32_bf16(a0, b0, acc[t], 0, 0, 0);
        acc[t] = __builtin_amdgcn_mfma_f32_16x16x32_bf16(a1, b1, acc[t], 0, 0, 0);
      }
#pragma unroll
      for (int t = 0; t < 4; t++)
#pragma unroll
        for (int r = 0; r < 4; r++){
          int row = row0 + lr*4 + r, col = t*16 + lc;
          float v = ((row==col) ? 1.5f : 0.f) - 0.5f*acc[t][r];
          u16 h = f2b(v);
          Tr[row*P2+col] = h; Tc[col*P2+row] = h;
        }
    }
    __syncthreads();
    { // phase 2: Y' = Y@T ; Z' = T@Z
      short8 ya0 = *reinterpret_cast<const short8*>(&Yr[cur][(row0+lc)*P2 + lr*8]);
      short8 ya1 = *reinterpret_cast<const short8*>(&Yr[cur][(row0+lc)*P2 + 32 + lr*8]);
      short8 ta0 = *reinterpret_cast<const short8*>(&Tr[(row0+lc)*P2 + lr*8]);
      short8 ta1 = *reinterpret_cast<const short8*>(&Tr[(row0+lc)*P2 + 32 + lr*8]);
      f32x4 accY[4] = {{0,0,0,0},{0,0,0,0},{0,0,0,0},{0,0,0,0}};
      f32x4 accZ[4] = {{0,0,0,0},{0,0,0,0},{0,0,0,0},{0,0,0,0}};
#pragma unroll
      for (int t = 0; t < 4; t++){
        short8 tb0 = *reinterpret_cast<const short8*>(&Tc[(t*16+lc)*P2 + lr*8]);
        short8 tb1 = *reinterpret_cast<const short8*>(&Tc[(t*16+lc)*P2 + 32 + lr*8]);
        accY[t] = __builtin_amdgcn_mfma_f32_16x16x32_bf16(ya0, tb0, accY[t], 0, 0, 0);
        accY[t] = __builtin_amdgcn_mfma_f32_16x16x32_bf16(ya1, tb1, accY[t], 0, 0, 0);
        short8 zb0 = *reinterpret_cast<const short8*>(&Zc[cur][(t*16+lc)*P2 + lr*8]);
        short8 zb1 = *reinterpret_cast<const short8*>(&Zc[cur][(t*16+lc)*P2 + 32 + lr*8]);
        accZ[t] = __builtin_amdgcn_mfma_f32_16x16x32_bf16(ta0, zb0, accZ[t], 0, 0, 0);
        accZ[t] = __builtin_amdgcn_mfma_f32_16x16x32_bf16(ta1, zb1, accZ[t], 0, 0, 0);
      }
#pragma unroll
      for (int t = 0; t < 4; t++)
#pragma unroll
        for (int r = 0; r < 4; r++){
          int row = row0 + lr*4 + r, col = t*16 + lc;
          u16 hy = f2b(accY[t][r]);
          u16 hz = f2b(accZ[t][r]);
          Yr[nxt][row*P2+col] = hy; Yc[nxt][col*P2+row] = hy;
          Zr[nxt][row*P2+col] = hz; Zc[nxt][col*P2+row] = hz;
        }
    }
    __syncthreads();
  }
  float rss = sv[1];
  int fin = NS_ITERS & 1;
  for (int idx = tid; idx < 2500; idx += 256){
    int r = idx/50, c = idx - r*50;
    Wm[(size_t)b*2500 + idx] = b2f(Zr[fin][r*P2+c]) * rss;
  }
}

// ---------------- K4c: H_logic = Wm @ H + threefry noise -> ZbB bf16 (fused) ----------------
__global__ __launch_bounds__(256) void kapply2(const float* __restrict__ H, const float* __restrict__ Wm,
                                               u16* __restrict__ zb){
  TFOut K1 = tf2x32(0u, 42u, 0u, 0u);
  TFOut K2 = tf2x32(0u, 42u, 0u, 1u);
  int blk = blockIdx.x;          // 128 = b(8) * dt(16)
  int dt = blk & 15, b = blk >> 4;
  int d0 = dt*64;
  int tid = threadIdx.x;
  int d = tid & 63, mg = tid >> 6;
  __shared__ __align__(16) float WsT[50*64];
  __shared__ float Hs[50*65];
  for (int idx = tid; idx < 3200; idx += 256){
    int j = idx >> 6, c = idx & 63;
    WsT[idx] = (c < 50) ? Wm[(size_t)b*2500 + c*50 + j] : 0.f;
  }
  for (int idx = tid; idx < 3200; idx += 256){
    int j = idx >> 6, c = idx & 63;
    Hs[j*65 + c] = H[((size_t)(b*64) + j)*1024 + d0 + c];
  }
  __syncthreads();
  float acc[16];
#pragma unroll
  for (int i = 0; i < 16; i++) acc[i] = 0.f;
  for (int j = 0; j < 50; j++){
    float hv = Hs[j*65 + d];
    const float* wb = WsT + j*64 + (mg << 4);
#pragma unroll
    for (int q = 0; q < 4; q++){
      float4 wv = *reinterpret_cast<const float4*>(wb + q*4);
      acc[q*4+0] = fmaf(wv.x, hv, acc[q*4+0]);
      acc[q*4+1] = fmaf(wv.y, hv, acc[q*4+1]);
      acc[q*4+2] = fmaf(wv.z, hv, acc[q*4+2]);
      acc[q*4+3] = fmaf(wv.w, hv, acc[q*4+3]);
    }
  }
#pragma unroll
  for (int i = 0; i < 16; i++){
    int m = (mg << 4) + i;
    size_t zo = ((size_t)(b*64 + m))*1024 + d0 + d;
    u16 ov = 0;
    if (m < 50){
      float val = acc[i];
      uint32_t j = (uint32_t)(((b*50 + m) << 10) + d0 + d);
      TFOut r1 = tf2x32(K1.a, K1.b, 0u, j);
      uint32_t bits = r1.a ^ r1.b;
      float u = __uint_as_float(0x3F800000u | (bits >> 9)) - 1.0f;
      if (u < 0.0464f){
        TFOut r2 = tf2x32(K2.a, K2.b, 0u, j);
        uint32_t nb = r2.a ^ r2.b;
        float ww = __uint_as_float(0x3F800000u | (nb >> 9)) - 1.0f;
        const float lo = -0.99999994f;
        float un = fmaxf(lo, fmaf(ww, 2.0f, lo));
        val += 0.1f * (1.4142135f * erfinv_f32(un));
      }
      ov = f2b(val);
    }
    zb[zo] = ov;
  }
}

// ---------------- K5: Hh = gelu(ZbB @ W1 + b1) (MFMA; W1 k-paired staging) ----------------
__global__ __launch_bounds__(256) void kmlp1(const u16* __restrict__ ZbB, const float* __restrict__ W1,
                                             const float* __restrict__ b1, u16* __restrict__ Hh){
  int blk = blockIdx.x; int b = blk>>6, c0 = (blk&63)<<6;
  int tid = threadIdx.x, lane = tid&63, w = tid>>6;
  __shared__ __align__(16) u16 az[64*PIT];   // [m][k]
  __shared__ __align__(16) u16 wt[64*PIT];   // [n][k]
  f32x4 acc[4] = {{0,0,0,0},{0,0,0,0},{0,0,0,0},{0,0,0,0}};
  int rr = tid>>2, seg = tid&3;
  int kp = tid & 31, nsg = tid >> 5;          // k-pair staging map
  for (int kc = 0; kc < 16; kc++){
    int k0 = kc*64;
    __syncthreads();
    { // stage A (ZbB rows)
      const u16* src = ZbB + ((size_t)(b*64 + rr))*1024 + k0 + seg*16;
      *reinterpret_cast<uint4*>(&az[rr*PIT + seg*16])   = *reinterpret_cast<const uint4*>(src);
      *reinterpret_cast<uint4*>(&az[rr*PIT + seg*16+8]) = *reinterpret_cast<const uint4*>(src+8);
    }
    { // stage W1 transposed: k-paired packed u32 writes (conflict-free)
      const float* s0 = W1 + (size_t)(k0 + 2*kp)*4096 + c0 + nsg*8;
      const float* s1 = s0 + 4096;
      float4 a0 = *reinterpret_cast<const float4*>(s0);
      float4 a1 = *reinterpret_cast<const float4*>(s0+4);
      float4 c0v = *reinterpret_cast<const float4*>(s1);
      float4 c1v = *reinterpret_cast<const float4*>(s1+4);
      float av[8] = {a0.x,a0.y,a0.z,a0.w,a1.x,a1.y,a1.z,a1.w};
      float cv[8] = {c0v.x,c0v.y,c0v.z,c0v.w,c1v.x,c1v.y,c1v.z,c1v.w};
#pragma unroll
      for (int j2 = 0; j2 < 8; j2++){
        int n = nsg*8 + j2;
        *reinterpret_cast<unsigned*>(&wt[n*PIT + 2*kp]) = pk2(av[j2], cv[j2]);
      }
    }
    __syncthreads();
#pragma unroll
    for (int s = 0; s < 2; s++){
      short8 a = *reinterpret_cast<const short8*>(&az[(16*w + (lane&15))*PIT + s*32 + (lane>>4)*8]);
#pragma unroll
      for (int t = 0; t < 4; t++){
        short8 bb = *reinterpret_cast<const short8*>(&wt[(t*16 + (lane&15))*PIT + s*32 + (lane>>4)*8]);
        acc[t] = __builtin_amdgcn_mfma_f32_16x16x32_bf16(a, bb, acc[t], 0, 0, 0);
      }
    }
  }
#pragma unroll
  for (int t = 0; t < 4; t++)
#pragma unroll
    for (int r = 0; r < 4; r++){
      int m = 16*w + (lane>>4)*4 + r;
      int n = c0 + t*16 + (lane&15);
      float val = acc[t][r] + b1[n];
      float g = 0.5f * val * (1.0f + erff(val * 0.70710678f));
      Hh[((size_t)(b*64 + m))*4096 + n] = (m < 50) ? f2b(g) : (u16)0;
    }
}

// ---------------- K6: partials of Hh @ W2 (MFMA, K-split x4, k-paired staging) ----------------
__global__ __launch_bounds__(256) void kmlp2p(const u16* __restrict__ Hh, const float* __restrict__ W2,
                                              float* __restrict__ Mpart){
  int blk = blockIdx.x;            // 512 = b(8) * dt(16) * kt(4)
  int kt = blk & 3, dt = (blk >> 2) & 15, b = blk >> 6;
  int d0 = dt*64;
  int tid = threadIdx.x, lane = tid&63, w = tid>>6;
  __shared__ __align__(16) u16 az[64*PIT];
  __shared__ __align__(16) u16 wt[64*PIT];
  f32x4 acc[4] = {{0,0,0,0},{0,0,0,0},{0,0,0,0},{0,0,0,0}};
  int rr = tid>>2, seg = tid&3;
  int kp = tid & 31, nsg = tid >> 5;
  for (int kc = 0; kc < 16; kc++){
    int k0 = kt*1024 + kc*64;
    __syncthreads();
    {
      const u16* src = Hh + ((size_t)(b*64 + rr))*4096 + k0 + seg*16;
      *reinterpret_cast<uint4*>(&az[rr*PIT + seg*16])   = *reinterpret_cast<const uint4*>(src);
      *reinterpret_cast<uint4*>(&az[rr*PIT + seg*16+8]) = *reinterpret_cast<const uint4*>(src+8);
    }
    { // stage W2 transposed: k-paired packed u32 writes
      const float* s0 = W2 + (size_t)(k0 + 2*kp)*1024 + d0 + nsg*8;
      const float* s1 = s0 + 1024;
      float4 a0 = *reinterpret_cast<const float4*>(s0);
      float4 a1 = *reinterpret_cast<const float4*>(s0+4);
      float4 c0v = *reinterpret_cast<const float4*>(s1);
      float4 c1v = *reinterpret_cast<const float4*>(s1+4);
      float av[8] = {a0.x,a0.y,a0.z,a0.w,a1.x,a1.y,a1.z,a1.w};
      float cv[8] = {c0v.x,c0v.y,c0v.z,c0v.w,c1v.x,c1v.y,c1v.z,c1v.w};
#pragma unroll
      for (int j2 = 0; j2 < 8; j2++){
        int n = nsg*8 + j2;
        *reinterpret_cast<unsigned*>(&wt[n*PIT + 2*kp]) = pk2(av[j2], cv[j2]);
      }
    }
    __syncthreads();
#pragma unroll
    for (int s = 0; s < 2; s++){
      short8 a = *reinterpret_cast<const short8*>(&az[(16*w + (lane&15))*PIT + s*32 + (lane>>4)*8]);
#pragma unroll
      for (int t = 0; t < 4; t++){
        short8 bb = *reinterpret_cast<const short8*>(&wt[(t*16 + (lane&15))*PIT + s*32 + (lane>>4)*8]);
        acc[t] = __builtin_amdgcn_mfma_f32_16x16x32_bf16(a, bb, acc[t], 0, 0, 0);
      }
    }
  }
#pragma unroll
  for (int t = 0; t < 4; t++)
#pragma unroll
    for (int r = 0; r < 4; r++){
      int m = 16*w + (lane>>4)*4 + r;
      int d = d0 + t*16 + (lane&15);
      if (m < 50) Mpart[(((size_t)(b*4) + kt)*50 + m)*1024 + d] = acc[t][r];
    }
}

// ---------------- K6b: HfT = tanh(sum partials + b2)^T, bf16, m>=50 zero ----------------
__global__ void kredT(const float* __restrict__ Mpart, const float* __restrict__ b2, u16* __restrict__ HfT){
  int e = blockIdx.x*256 + threadIdx.x;    // grid 2048 -> 524288 over [b][m(64)][d]
  int b = e >> 16, rem = e & 65535;
  int m = rem >> 10, d = rem & 1023;
  u16 outv = 0;
  if (m < 50){
    const float* p = Mpart + (size_t)b*204800 + m*1024 + d;
    float s = p[0] + p[51200] + p[102400] + p[153600] + b2[d];
    outv = f2b(tanhf(s));
  }
  HfT[((size_t)(b*1024) + d)*64 + m] = outv;
}

// ---------------- K7: out = x + C @ Hf (MFMA + LDS-bounced coalesced epilogue) ----------
__global__ __launch_bounds__(256) void kdec2(const float* __restrict__ x, const u16* __restrict__ C,
                                             const u16* __restrict__ HfT, float* __restrict__ out){
  int blk = blockIdx.x;              // 2048 = b(8) * nt(64) * dq(4)
  int dq = blk & 3, nt = (blk >> 2) & 63, b = blk >> 8;
  int n0 = nt << 6;
  int tid = threadIdx.x, lane = tid&63, w = tid>>6;
  __shared__ __align__(16) u16 ctile[64*PIT];   // [tok][m]
  __shared__ __align__(16) u16 htile[64*PIT];   // [d][m]
  __shared__ __align__(16) float obuf[64*68];   // [n][d] f32, pitch 68
  int rr = tid>>2, seg = tid&3;
  {
    const u16* src = C + ((size_t)(b*4096 + n0 + rr))*64 + seg*16;
    *reinterpret_cast<uint4*>(&ctile[rr*PIT + seg*16])   = *reinterpret_cast<const uint4*>(src);
    *reinterpret_cast<uint4*>(&ctile[rr*PIT + seg*16+8]) = *reinterpret_cast<const uint4*>(src+8);
  }
  __syncthreads();
  short8 afrag[2];
#pragma unroll
  for (int s = 0; s < 2; s++)
    afrag[s] = *reinterpret_cast<const short8*>(&ctile[(16*w + (lane&15))*PIT + s*32 + (lane>>4)*8]);
  for (int dt2 = 0; dt2 < 4; dt2++){
    int d0 = (dq*4 + dt2) * 64;
    __syncthreads();
    {
      const u16* src = HfT + ((size_t)(b*1024 + d0 + rr))*64 + seg*16;
      *reinterpret_cast<uint4*>(&htile[rr*PIT + seg*16])   = *reinterpret_cast<const uint4*>(src);
      *reinterpret_cast<uint4*>(&htile[rr*PIT + seg*16+8]) = *reinterpret_cast<const uint4*>(src+8);
    }
    __syncthreads();
    f32x4 acc[4] = {{0,0,0,0},{0,0,0,0},{0,0,0,0},{0,0,0,0}};
#pragma unroll
    for (int s = 0; s < 2; s++){
#pragma unroll
      for (int t = 0; t < 4; t++){
        short8 bb = *reinterpret_cast<const short8*>(&htile[(t*16 + (lane&15))*PIT + s*32 + (lane>>4)*8]);
        acc[t] = __builtin_amdgcn_mfma_f32_16x16x32_bf16(afrag[s], bb, acc[t], 0, 0, 0);
      }
    }
    // scatter acc into LDS [n][d] f32
#pragma unroll
    for (int t = 0; t < 4; t++)
#pragma unroll
      for (int r = 0; r < 4; r++){
        int nl = 16*w + (lane>>4)*4 + r;
        int dl = t*16 + (lane&15);
        obuf[nl*68 + dl] = acc[t][r];
      }
    __syncthreads();
    // coalesced epilogue: 1024 float4-slots (64 rows x 16 slots), 4 per thread
#pragma unroll
    for (int pass = 0; pass < 4; pass++){
      int s2 = tid + pass*256;
      int nl = s2 >> 4, sg = s2 & 15;
      size_t o = ((size_t)(b*4096 + n0 + nl))*1024 + d0 + sg*4;
      float4 xv = *reinterpret_cast<const float4*>(x + o);
      const float* ob = &obuf[nl*68 + sg*4];
      float4 ov;
      ov.x = xv.x + ob[0];
      ov.y = xv.y + ob[1];
      ov.z = xv.z + ob[2];
      ov.w = xv.w + ob[3];
      *reinterpret_cast<float4*>(out + o) = ov;
    }
  }
}

// ---------------- launch ----------------
extern "C" void kernel_launch(void* const* d_in, const int* in_sizes, int n_in,
                              void* d_out, int out_size, void* d_ws, size_t ws_size,
                              hipStream_t stream) {
  (void)in_sizes; (void)n_in; (void)out_size;
  if (ws_size < (size_t)19755264) return;
  const float* x  = (const float*)d_in[0];
  const float* pn = (const float*)d_in[1];
  const float* W1 = (const float*)d_in[8];
  const float* b1 = (const float*)d_in[9];
  const float* W2 = (const float*)d_in[10];
  const float* b2 = (const float*)d_in[11];
  float* out = (float*)d_out;
  char* ws = (char*)d_ws;

  // Overlapped layout (stream-ordered liveness):
  u16*   C   = (u16*)(ws);                      // [0, 4.19MB)        live kC->kdec2
  u16*   CT  = (u16*)(ws + 4194304);            // CT region 4.19MB:  CT live kC->kHp2
  u16*   ZbB = (u16*)(ws + 4194304 + 1638400);  //   reuses CT space  (kapply2->kmlp1)
  u16*   HfT = (u16*)(ws + 4194304 + 2686976);  //   (kredT->kdec2)
  u16*   Hh  = (u16*)(ws + 8388608);            // Hh region 4.19MB:  Hh live kmlp1->kmlp2p
  u16*   Hb  = (u16*)(ws + 8388608);            //   reuses Hh space  (kredH->kgram)
  float* H   = (float*)(ws + 8388608 + 1048576);//   (kredH->kapply2)
  float* HP  = (float*)(ws + 12582912);         // partials 6.55MB: kHp2->kredH, kmlp2p->kredT
  u16*   PT  = (u16*)(ws + 19136512);           // 131,072 B
  float* G   = (float*)(ws + 19267584);         // 80,000 B
  float* WM  = (float*)(ws + 19347584);         // 80,000 B

  hipLaunchKernelGGL(kprep,   dim3(64),   dim3(256), 0, stream, pn, PT);
  hipLaunchKernelGGL(kC,      dim3(512),  dim3(256), 0, stream, x, PT, C, CT);
  hipLaunchKernelGGL(kHp2,    dim3(512),  dim3(256), 0, stream, x, CT, HP);
  hipLaunchKernelGGL(kredH,   dim3(2048), dim3(256), 0, stream, HP, H, Hb);
  hipLaunchKernelGGL(kgram,   dim3(8),    dim3(256), 0, stream, Hb, G);
  hipLaunchKernelGGL(kns3,    dim3(8),    dim3(256), 0, stream, G, WM);
  hipLaunchKernelGGL(kapply2, dim3(128),  dim3(256), 0, stream, H, WM, ZbB);
  hipLaunchKernelGGL(kmlp1,   dim3(512),  dim3(256), 0, stream, ZbB, W1, b1, Hh);
  hipLaunchKernelGGL(kmlp2p,  dim3(512),  dim3(256), 0, stream, Hh, W2, HP);
  hipLaunchKernelGGL(kredT,   dim3(2048), dim3(256), 0, stream, HP, b2, HfT);
  hipLaunchKernelGGL(kdec2,   dim3(2048), dim3(256), 0, stream, x, C, HfT, out);
}

// Round 9
// 246.987 us; speedup vs baseline: 4.2385x; 1.0566x over previous
//
#include <hip/hip_runtime.h>
#include <stdint.h>
#include <math.h>

#define NS_ITERS 26
#define PIT 72   // LDS row pitch in shorts (144B: 16B-aligned, bank-spread)
#define P2  72   // pitch for kns3 matrices

typedef unsigned short u16;
typedef __attribute__((ext_vector_type(8))) short short8;
typedef __attribute__((ext_vector_type(4))) float f32x4;

__device__ __forceinline__ u16 f2b(float f){
  unsigned u = __float_as_uint(f);
  unsigned r = (u + 0x7FFFu + ((u>>16)&1u)) >> 16;
  return (u16)r;
}
__device__ __forceinline__ float b2f(u16 h){ return __uint_as_float(((unsigned)h)<<16); }
__device__ __forceinline__ unsigned pk2(float lo, float hi){
  return (unsigned)f2b(lo) | ((unsigned)f2b(hi) << 16);
}

// ---------------- threefry2x32 (JAX-compatible) ----------------
__host__ __device__ constexpr uint32_t rotl32(uint32_t v, int n){ return (v<<n)|(v>>(32-n)); }
struct TFOut { uint32_t a, b; };
__host__ __device__ constexpr TFOut tf2x32(uint32_t k0, uint32_t k1, uint32_t x0, uint32_t x1){
  uint32_t ks2 = k0 ^ k1 ^ 0x1BD11BDAu;
  x0 += k0; x1 += k1;
#define TFR(R) x0 += x1; x1 = rotl32(x1,(R)) ^ x0;
  TFR(13) TFR(15) TFR(26) TFR(6)
  x0 += k1; x1 += ks2 + 1u;
  TFR(17) TFR(29) TFR(16) TFR(24)
  x0 += ks2; x1 += k0 + 2u;
  TFR(13) TFR(15) TFR(26) TFR(6)
  x0 += k0; x1 += k1 + 3u;
  TFR(17) TFR(29) TFR(16) TFR(24)
  x0 += k1; x1 += ks2 + 4u;
  TFR(13) TFR(15) TFR(26) TFR(6)
  x0 += ks2; x1 += k0 + 5u;
#undef TFR
  return TFOut{x0, x1};
}

__device__ __forceinline__ float erfinv_f32(float x){
  float w = -log1pf(-x*x);
  float p;
  if (w < 5.0f) {
    w -= 2.5f;
    p = 2.81022636e-08f;
    p = fmaf(p, w, 3.43273939e-07f);
    p = fmaf(p, w, -3.5233877e-06f);
    p = fmaf(p, w, -4.39150654e-06f);
    p = fmaf(p, w, 0.00021858087f);
    p = fmaf(p, w, -0.00125372503f);
    p = fmaf(p, w, -0.00417768164f);
    p = fmaf(p, w, 0.246640727f);
    p = fmaf(p, w, 1.50140941f);
  } else {
    w = sqrtf(w) - 3.0f;
    p = -0.000200214257f;
    p = fmaf(p, w, 0.000100950558f);
    p = fmaf(p, w, 0.00134934322f);
    p = fmaf(p, w, -0.00367342844f);
    p = fmaf(p, w, 0.00573950773f);
    p = fmaf(p, w, -0.0076224613f);
    p = fmaf(p, w, 0.00943887047f);
    p = fmaf(p, w, 1.00167406f);
    p = fmaf(p, w, 2.83297682f);
  }
  return p * x;
}

// ---------------- K1: fused prep ----------------
// blk 0..63     : primes -> PT bf16 [64][1024], unit-norm, rows>=50 zero
// blk 64..1087  : W1 [1024][4096] -> W1T bf16 [4096][1024] (64x64 tiles)
// blk 1088..2111: W2 [4096][1024] -> W2T bf16 [1024][4096]
__global__ __launch_bounds__(256) void kprepAll(const float* __restrict__ prime, u16* __restrict__ PT,
                                                const float* __restrict__ W1, u16* __restrict__ W1T,
                                                const float* __restrict__ W2, u16* __restrict__ W2T){
  int blk = blockIdx.x;
  int tid = threadIdx.x;
  if (blk < 64){
    int m = blk;
    u16* dst = PT + m*1024;
    if (m >= 50){ for (int k = tid; k < 1024; k += 256) dst[k] = 0; return; }
    __shared__ float red[256];
    const float* pr = prime + m*1024;
    float ss = 0.f;
    for (int k = tid; k < 1024; k += 256){ float v = pr[k]; ss = fmaf(v,v,ss); }
    red[tid] = ss; __syncthreads();
    for (int s = 128; s > 0; s >>= 1){ if (tid < s) red[tid] += red[tid+s]; __syncthreads(); }
    float sc = 1.0f / fmaxf(sqrtf(red[0]), 1e-12f);
    for (int k = tid; k < 1024; k += 256) dst[k] = f2b(pr[k]*sc);
    return;
  }
  const float* src; u16* dst; int srcStride, dstStride;
  if (blk < 1088){
    int t = blk - 64;
    int kt2 = t >> 6, nt2 = t & 63;
    src = W1 + (size_t)(kt2*64)*4096 + nt2*64; srcStride = 4096;
    dst = W1T + (size_t)(nt2*64)*1024 + kt2*64; dstStride = 1024;
  } else {
    int t = blk - 1088;
    int kt2 = t >> 4, dt2 = t & 15;
    src = W2 + (size_t)(kt2*64)*1024 + dt2*64; srcStride = 1024;
    dst = W2T + (size_t)(dt2*64)*4096 + kt2*64; dstStride = 4096;
  }
  __shared__ __align__(16) u16 ts[64*PIT];   // [src_row(k)][src_col(n)]
  int r = tid>>2, sseg = tid&3;
  {
    const float* s0 = src + (size_t)r*srcStride + sseg*16;
    unsigned p[8];
#pragma unroll
    for (int i = 0; i < 4; i++){
      float4 v = *reinterpret_cast<const float4*>(s0 + i*4);
      p[2*i]   = pk2(v.x, v.y);
      p[2*i+1] = pk2(v.z, v.w);
    }
    uint4 w0; w0.x=p[0]; w0.y=p[1]; w0.z=p[2]; w0.w=p[3];
    uint4 w1; w1.x=p[4]; w1.y=p[5]; w1.z=p[6]; w1.w=p[7];
    *reinterpret_cast<uint4*>(&ts[r*PIT + sseg*16])     = w0;
    *reinterpret_cast<uint4*>(&ts[r*PIT + sseg*16 + 8]) = w1;
  }
  __syncthreads();
  {
    int n2 = tid>>2, kseg = tid&3;
    unsigned q[8];
#pragma unroll
    for (int j = 0; j < 8; j++){
      u16 lo = ts[(kseg*16 + 2*j)*PIT + n2];
      u16 hi = ts[(kseg*16 + 2*j+1)*PIT + n2];
      q[j] = (unsigned)lo | ((unsigned)hi<<16);
    }
    u16* d2 = dst + (size_t)n2*dstStride + kseg*16;
    uint4 w0; w0.x=q[0]; w0.y=q[1]; w0.z=q[2]; w0.w=q[3];
    uint4 w1; w1.x=q[4]; w1.y=q[5]; w1.z=q[6]; w1.w=q[7];
    *reinterpret_cast<uint4*>(d2)   = w0;
    *reinterpret_cast<uint4*>(d2+8) = w1;
  }
}

// ---------------- K2: MFMA logits + softmax -> C[n][64] bf16 and CT[m][4096n] bf16 ----
__global__ __launch_bounds__(256) void kC(const float* __restrict__ x, const u16* __restrict__ PT,
                                          u16* __restrict__ C, u16* __restrict__ CT){
  int blk = blockIdx.x; int b = blk>>6, n0 = (blk&63)<<6;
  int tid = threadIdx.x, lane = tid&63, w = tid>>6;
  __shared__ __align__(16) u16 xs[64*PIT];
  __shared__ __align__(16) u16 ps[64*PIT];
  __shared__ float sq[64][5];
  f32x4 acc[4] = {{0,0,0,0},{0,0,0,0},{0,0,0,0},{0,0,0,0}};
  float sqa = 0.f;
  int stok = tid>>2, sseg = tid&3;                 // staging map
  int qtok = tid&63, qg = tid>>6;                  // sumsq map
  const float* xb = x + ((size_t)(b*4096 + n0))*1024;
  for (int kc = 0; kc < 16; kc++){
    int k0 = kc*64;
    __syncthreads();
    { // stage x (cvt bf16, packed uint4 writes)
      const float* src = xb + (size_t)stok*1024 + k0 + sseg*16;
      unsigned p[8];
#pragma unroll
      for (int i = 0; i < 4; i++){
        float4 v = *reinterpret_cast<const float4*>(src + i*4);
        p[2*i]   = pk2(v.x, v.y);
        p[2*i+1] = pk2(v.z, v.w);
      }
      uint4 w0; w0.x=p[0]; w0.y=p[1]; w0.z=p[2]; w0.w=p[3];
      uint4 w1; w1.x=p[4]; w1.y=p[5]; w1.z=p[6]; w1.w=p[7];
      *reinterpret_cast<uint4*>(&xs[stok*PIT + sseg*16])     = w0;
      *reinterpret_cast<uint4*>(&xs[stok*PIT + sseg*16 + 8]) = w1;
    }
    { // stage P rows
      const u16* src = PT + (size_t)stok*1024 + k0 + sseg*16;
      *reinterpret_cast<uint4*>(&ps[stok*PIT + sseg*16])   = *reinterpret_cast<const uint4*>(src);
      *reinterpret_cast<uint4*>(&ps[stok*PIT + sseg*16+8]) = *reinterpret_cast<const uint4*>(src+8);
    }
    __syncthreads();
    { // sumsq of this token's 16 values
      const u16* xr = &xs[qtok*PIT + qg*16];
#pragma unroll
      for (int j = 0; j < 16; j++){ float v = b2f(xr[j]); sqa = fmaf(v,v,sqa); }
    }
#pragma unroll
    for (int s = 0; s < 2; s++){
      short8 a = *reinterpret_cast<const short8*>(&xs[(16*w + (lane&15))*PIT + s*32 + (lane>>4)*8]);
#pragma unroll
      for (int t = 0; t < 4; t++){
        short8 bb = *reinterpret_cast<const short8*>(&ps[(t*16 + (lane&15))*PIT + s*32 + (lane>>4)*8]);
        acc[t] = __builtin_amdgcn_mfma_f32_16x16x32_bf16(a, bb, acc[t], 0, 0, 0);
      }
    }
  }
  sq[qtok][qg] = sqa;
  __syncthreads();
  if (tid < 64){
    float ss = sq[tid][0]+sq[tid][1]+sq[tid][2]+sq[tid][3];
    sq[tid][4] = 10.0f / fmaxf(sqrtf(ss), 1e-12f);
  }
  __syncthreads();
  // softmax per token (rows spread over lane>>4 groups; primes = lane&15 + 16*t)
  u16* cl = xs;  // reuse
#pragma unroll
  for (int r = 0; r < 4; r++){
    int gt = 16*w + (lane>>4)*4 + r;
    float scale = sq[gt][4];
    float v[4];
#pragma unroll
    for (int t = 0; t < 4; t++) v[t] = acc[t][r] * scale;
    if ((lane&15) >= 2) v[3] = -1e30f;
    float mx = fmaxf(fmaxf(v[0],v[1]), fmaxf(v[2],v[3]));
#pragma unroll
    for (int off = 1; off < 16; off <<= 1) mx = fmaxf(mx, __shfl_xor(mx, off, 64));
    float e[4], sum = 0.f;
#pragma unroll
    for (int t = 0; t < 4; t++){ e[t] = __expf(v[t]-mx); sum += e[t]; }
#pragma unroll
    for (int off = 1; off < 16; off <<= 1) sum += __shfl_xor(sum, off, 64);
    float inv = 1.0f / sum;
#pragma unroll
    for (int t = 0; t < 4; t++) cl[gt*PIT + t*16 + (lane&15)] = f2b(e[t]*inv);
  }
  __syncthreads();
  { // C write (row-major) b128
    u16* dst = C + ((size_t)(b*4096 + n0 + stok))*64 + sseg*16;
    *reinterpret_cast<uint4*>(dst)   = *reinterpret_cast<const uint4*>(&cl[stok*PIT + sseg*16]);
    *reinterpret_cast<uint4*>(dst+8) = *reinterpret_cast<const uint4*>(&cl[stok*PIT + sseg*16+8]);
  }
  { // CT write (transposed)
    int m = tid>>2, nseg = tid&3;
    unsigned vs[8];
#pragma unroll
    for (int j = 0; j < 8; j++){
      u16 lo = cl[(nseg*16 + 2*j)*PIT + m];
      u16 hi = cl[(nseg*16 + 2*j+1)*PIT + m];
      vs[j] = (unsigned)lo | ((unsigned)hi<<16);
    }
    u16* dst = CT + ((size_t)(b*64 + m))*4096 + n0 + nseg*16;
    uint4 w0; w0.x=vs[0]; w0.y=vs[1]; w0.z=vs[2]; w0.w=vs[3];
    uint4 w1; w1.x=vs[4]; w1.y=vs[5]; w1.z=vs[6]; w1.w=vs[7];
    *reinterpret_cast<uint4*>(dst)   = w0;
    *reinterpret_cast<uint4*>(dst+8) = w1;
  }
}

// ---------------- K3: H_prime partials = CT @ x over n-quarter (MFMA, K-split x4) ----
__global__ __launch_bounds__(256) void kHp2(const float* __restrict__ x, const u16* __restrict__ CT,
                                            float* __restrict__ Hpart){
  int blk = blockIdx.x;            // 512 = b(8) * dt(16) * kt(4)
  int kt = blk & 3, dt = (blk >> 2) & 15, b = blk >> 6;
  int d0 = dt*64;
  int tid = threadIdx.x, lane = tid&63, w = tid>>6;
  __shared__ __align__(16) u16 cs[64*PIT];    // [m][n]
  __shared__ __align__(16) u16 xt[64*PIT];    // [d][n]
  f32x4 acc[4] = {{0,0,0,0},{0,0,0,0},{0,0,0,0},{0,0,0,0}};
  int nn = tid>>2, seg = tid&3;
  int np = tid & 31, dsg = tid >> 5;          // n-pair staging map
  for (int nc = 0; nc < 16; nc++){
    int n0 = kt*1024 + nc*64;
    __syncthreads();
    { // stage CT rows [m][n-chunk]
      const u16* src = CT + ((size_t)(b*64 + nn))*4096 + n0 + seg*16;  // nn = m here
      *reinterpret_cast<uint4*>(&cs[nn*PIT + seg*16])   = *reinterpret_cast<const uint4*>(src);
      *reinterpret_cast<uint4*>(&cs[nn*PIT + seg*16+8]) = *reinterpret_cast<const uint4*>(src+8);
    }
    { // stage x transposed: n-paired packed u32 writes (conflict-free)
      const float* s0 = x + ((size_t)(b*4096 + n0 + 2*np))*1024 + d0 + dsg*8;
      const float* s1 = s0 + 1024;
      float4 a0 = *reinterpret_cast<const float4*>(s0);
      float4 a1 = *reinterpret_cast<const float4*>(s0+4);
      float4 c0v = *reinterpret_cast<const float4*>(s1);
      float4 c1v = *reinterpret_cast<const float4*>(s1+4);
      float av[8] = {a0.x,a0.y,a0.z,a0.w,a1.x,a1.y,a1.z,a1.w};
      float cv[8] = {c0v.x,c0v.y,c0v.z,c0v.w,c1v.x,c1v.y,c1v.z,c1v.w};
#pragma unroll
      for (int j2 = 0; j2 < 8; j2++){
        int dd = dsg*8 + j2;
        *reinterpret_cast<unsigned*>(&xt[dd*PIT + 2*np]) = pk2(av[j2], cv[j2]);
      }
    }
    __syncthreads();
#pragma unroll
    for (int s = 0; s < 2; s++){
      short8 a = *reinterpret_cast<const short8*>(&cs[(16*w + (lane&15))*PIT + s*32 + (lane>>4)*8]);
#pragma unroll
      for (int t = 0; t < 4; t++){
        short8 bb = *reinterpret_cast<const short8*>(&xt[(t*16 + (lane&15))*PIT + s*32 + (lane>>4)*8]);
        acc[t] = __builtin_amdgcn_mfma_f32_16x16x32_bf16(a, bb, acc[t], 0, 0, 0);
      }
    }
  }
#pragma unroll
  for (int t = 0; t < 4; t++)
#pragma unroll
    for (int r = 0; r < 4; r++){
      int m = 16*w + (lane>>4)*4 + r;
      int d = d0 + t*16 + (lane&15);
      if (m < 50) Hpart[(((size_t)(b*4) + kt)*50 + m)*1024 + d] = acc[t][r];
    }
}

// ---------------- K3b: reduce partials -> H f32 + Hb bf16, pad rows zeroed (grid 2048) ----
__global__ void kredH(const float* __restrict__ Hpart, float* __restrict__ H, u16* __restrict__ Hb){
  int e = blockIdx.x*256 + threadIdx.x;    // grid 2048 -> 524288 over [b][m(64)][d]
  int b = e >> 16, rem = e & 65535;
  int m = rem >> 10, d = rem & 1023;
  size_t o = ((size_t)(b*64 + m))*1024 + d;
  if (m < 50){
    const float* p = Hpart + (size_t)b*204800 + m*1024 + d;
    float s = p[0] + p[51200] + p[102400] + p[153600];
    H[o] = s;
    Hb[o] = f2b(s);
  } else {
    Hb[o] = 0;
  }
}

// ---------------- K4a: Gram via MFMA: G = Hb Hb^T ----------------
__global__ __launch_bounds__(256) void kgram(const u16* __restrict__ Hb, float* __restrict__ G){
  int b = blockIdx.x;
  int tid = threadIdx.x, lane = tid&63, w = tid>>6;
  __shared__ __align__(16) u16 hs[64*PIT];
  f32x4 acc[4] = {{0,0,0,0},{0,0,0,0},{0,0,0,0},{0,0,0,0}};
  int m = tid>>2, seg = tid&3;
  for (int kc = 0; kc < 16; kc++){
    int k0 = kc*64;
    __syncthreads();
    const u16* src = Hb + ((size_t)(b*64 + m))*1024 + k0 + seg*16;
    *reinterpret_cast<uint4*>(&hs[m*PIT + seg*16])   = *reinterpret_cast<const uint4*>(src);
    *reinterpret_cast<uint4*>(&hs[m*PIT + seg*16+8]) = *reinterpret_cast<const uint4*>(src+8);
    __syncthreads();
#pragma unroll
    for (int s = 0; s < 2; s++){
      short8 a = *reinterpret_cast<const short8*>(&hs[(16*w + (lane&15))*PIT + s*32 + (lane>>4)*8]);
#pragma unroll
      for (int t = 0; t < 4; t++){
        short8 bb = *reinterpret_cast<const short8*>(&hs[(t*16 + (lane&15))*PIT + s*32 + (lane>>4)*8]);
        acc[t] = __builtin_amdgcn_mfma_f32_16x16x32_bf16(a, bb, acc[t], 0, 0, 0);
      }
    }
  }
#pragma unroll
  for (int t = 0; t < 4; t++)
#pragma unroll
    for (int r = 0; r < 4; r++){
      int i = 16*w + (lane>>4)*4 + r;
      int j = t*16 + (lane&15);
      if (i < 50 && j < 50) G[(size_t)b*2500 + i*50 + j] = acc[t][r];
    }
}

// ---------------- K4b: Newton-Schulz invsqrt via MFMA (bf16 fragments, 64x64 padded) ----
__global__ __launch_bounds__(256) void kns3(const float* __restrict__ G, float* __restrict__ Wm){
  int b = blockIdx.x;
  __shared__ __align__(16) u16 Yr[2][64*P2], Yc[2][64*P2], Zr[2][64*P2], Zc[2][64*P2];
  __shared__ __align__(16) u16 Tr[64*P2], Tc[64*P2];
  __shared__ float sv[2];
  int tid = threadIdx.x, lane = tid&63, w = tid>>6;
  int lr = lane>>4, lc = lane&15;
  int row0 = 16*w;
  const float* Gb = G + (size_t)b*2500;
  if (tid < 64){
    float v = (tid < 50) ? Gb[tid*50+tid] : 0.f;
    for (int off = 1; off < 64; off <<= 1) v += __shfl_xor(v, off, 64);
    if (tid == 0){ sv[0] = 1.0f / v; sv[1] = rsqrtf(v); }
  }
  __syncthreads();
  float rs = sv[0];
  for (int idx = tid; idx < 4096; idx += 256){
    int r = idx>>6, c = idx&63;
    float yv = (r<50 && c<50) ? Gb[r*50+c]*rs : ((r==c) ? 1.f : 0.f);
    float zv = (r==c) ? 1.f : 0.f;
    u16 yb = f2b(yv), zb = f2b(zv);
    Yr[0][r*P2+c] = yb; Yc[0][c*P2+r] = yb;
    Zr[0][r*P2+c] = zb; Zc[0][c*P2+r] = zb;
  }
  __syncthreads();
  for (int it = 0; it < NS_ITERS; it++){
    int cur = it & 1, nxt = cur ^ 1;
    { // phase 1: T = 1.5I - 0.5 * Z@Y
      short8 a0 = *reinterpret_cast<const short8*>(&Zr[cur][(row0+lc)*P2 + lr*8]);
      short8 a1 = *reinterpret_cast<const short8*>(&Zr[cur][(row0+lc)*P2 + 32 + lr*8]);
      f32x4 acc[4] = {{0,0,0,0},{0,0,0,0},{0,0,0,0},{0,0,0,0}};
#pragma unroll
      for (int t = 0; t < 4; t++){
        short8 b0 = *reinterpret_cast<const short8*>(&Yc[cur][(t*16+lc)*P2 + lr*8]);
        short8 b1 = *reinterpret_cast<const short8*>(&Yc[cur][(t*16+lc)*P2 + 32 + lr*8]);
        acc[t] = __builtin_amdgcn_mfma_f32_16x16x32_bf16(a0, b0, acc[t], 0, 0, 0);
        acc[t] = __builtin_amdgcn_mfma_f32_16x16x32_bf16(a1, b1, acc[t], 0, 0, 0);
      }
#pragma unroll
      for (int t = 0; t < 4; t++)
#pragma unroll
        for (int r = 0; r < 4; r++){
          int row = row0 + lr*4 + r, col = t*16 + lc;
          float v = ((row==col) ? 1.5f : 0.f) - 0.5f*acc[t][r];
          u16 h = f2b(v);
          Tr[row*P2+col] = h; Tc[col*P2+row] = h;
        }
    }
    __syncthreads();
    { // phase 2: Y' = Y@T ; Z' = T@Z
      short8 ya0 = *reinterpret_cast<const short8*>(&Yr[cur][(row0+lc)*P2 + lr*8]);
      short8 ya1 = *reinterpret_cast<const short8*>(&Yr[cur][(row0+lc)*P2 + 32 + lr*8]);
      short8 ta0 = *reinterpret_cast<const short8*>(&Tr[(row0+lc)*P2 + lr*8]);
      short8 ta1 = *reinterpret_cast<const short8*>(&Tr[(row0+lc)*P2 + 32 + lr*8]);
      f32x4 accY[4] = {{0,0,0,0},{0,0,0,0},{0,0,0,0},{0,0,0,0}};
      f32x4 accZ[4] = {{0,0,0,0},{0,0,0,0},{0,0,0,0},{0,0,0,0}};
#pragma unroll
      for (int t = 0; t < 4; t++){
        short8 tb0 = *reinterpret_cast<const short8*>(&Tc[(t*16+lc)*P2 + lr*8]);
        short8 tb1 = *reinterpret_cast<const short8*>(&Tc[(t*16+lc)*P2 + 32 + lr*8]);
        accY[t] = __builtin_amdgcn_mfma_f32_16x16x32_bf16(ya0, tb0, accY[t], 0, 0, 0);
        accY[t] = __builtin_amdgcn_mfma_f32_16x16x32_bf16(ya1, tb1, accY[t], 0, 0, 0);
        short8 zb0 = *reinterpret_cast<const short8*>(&Zc[cur][(t*16+lc)*P2 + lr*8]);
        short8 zb1 = *reinterpret_cast<const short8*>(&Zc[cur][(t*16+lc)*P2 + 32 + lr*8]);
        accZ[t] = __builtin_amdgcn_mfma_f32_16x16x32_bf16(ta0, zb0, accZ[t], 0, 0, 0);
        accZ[t] = __builtin_amdgcn_mfma_f32_16x16x32_bf16(ta1, zb1, accZ[t], 0, 0, 0);
      }
#pragma unroll
      for (int t = 0; t < 4; t++)
#pragma unroll
        for (int r = 0; r < 4; r++){
          int row = row0 + lr*4 + r, col = t*16 + lc;
          u16 hy = f2b(accY[t][r]);
          u16 hz = f2b(accZ[t][r]);
          Yr[nxt][row*P2+col] = hy; Yc[nxt][col*P2+row] = hy;
          Zr[nxt][row*P2+col] = hz; Zc[nxt][col*P2+row] = hz;
        }
    }
    __syncthreads();
  }
  float rss = sv[1];
  int fin = NS_ITERS & 1;
  for (int idx = tid; idx < 2500; idx += 256){
    int r = idx/50, c = idx - r*50;
    Wm[(size_t)b*2500 + idx] = b2f(Zr[fin][r*P2+c]) * rss;
  }
}

// ---------------- K4c: H_logic = Wm @ H + threefry noise -> ZbB bf16 (fused) ----------------
__global__ __launch_bounds__(256) void kapply2(const float* __restrict__ H, const float* __restrict__ Wm,
                                               u16* __restrict__ zb){
  TFOut K1 = tf2x32(0u, 42u, 0u, 0u);
  TFOut K2 = tf2x32(0u, 42u, 0u, 1u);
  int blk = blockIdx.x;          // 128 = b(8) * dt(16)
  int dt = blk & 15, b = blk >> 4;
  int d0 = dt*64;
  int tid = threadIdx.x;
  int d = tid & 63, mg = tid >> 6;
  __shared__ __align__(16) float WsT[50*64];
  __shared__ float Hs[50*65];
  for (int idx = tid; idx < 3200; idx += 256){
    int j = idx >> 6, c = idx & 63;
    WsT[idx] = (c < 50) ? Wm[(size_t)b*2500 + c*50 + j] : 0.f;
  }
  for (int idx = tid; idx < 3200; idx += 256){
    int j = idx >> 6, c = idx & 63;
    Hs[j*65 + c] = H[((size_t)(b*64) + j)*1024 + d0 + c];
  }
  __syncthreads();
  float acc[16];
#pragma unroll
  for (int i = 0; i < 16; i++) acc[i] = 0.f;
  for (int j = 0; j < 50; j++){
    float hv = Hs[j*65 + d];
    const float* wb = WsT + j*64 + (mg << 4);
#pragma unroll
    for (int q = 0; q < 4; q++){
      float4 wv = *reinterpret_cast<const float4*>(wb + q*4);
      acc[q*4+0] = fmaf(wv.x, hv, acc[q*4+0]);
      acc[q*4+1] = fmaf(wv.y, hv, acc[q*4+1]);
      acc[q*4+2] = fmaf(wv.z, hv, acc[q*4+2]);
      acc[q*4+3] = fmaf(wv.w, hv, acc[q*4+3]);
    }
  }
#pragma unroll
  for (int i = 0; i < 16; i++){
    int m = (mg << 4) + i;
    size_t zo = ((size_t)(b*64 + m))*1024 + d0 + d;
    u16 ov = 0;
    if (m < 50){
      float val = acc[i];
      uint32_t j = (uint32_t)(((b*50 + m) << 10) + d0 + d);
      TFOut r1 = tf2x32(K1.a, K1.b, 0u, j);
      uint32_t bits = r1.a ^ r1.b;
      float u = __uint_as_float(0x3F800000u | (bits >> 9)) - 1.0f;
      if (u < 0.0464f){
        TFOut r2 = tf2x32(K2.a, K2.b, 0u, j);
        uint32_t nb = r2.a ^ r2.b;
        float ww = __uint_as_float(0x3F800000u | (nb >> 9)) - 1.0f;
        const float lo = -0.99999994f;
        float un = fmaxf(lo, fmaf(ww, 2.0f, lo));
        val += 0.1f * (1.4142135f * erfinv_f32(un));
      }
      ov = f2b(val);
    }
    zb[zo] = ov;
  }
}

// ---------------- K5: Hh = gelu(ZbB @ W1T + b1) (MFMA; bf16 W1T direct staging) ----------------
__global__ __launch_bounds__(256) void kmlp1(const u16* __restrict__ ZbB, const u16* __restrict__ W1T,
                                             const float* __restrict__ b1, u16* __restrict__ Hh){
  int blk = blockIdx.x; int b = blk>>6, c0 = (blk&63)<<6;
  int tid = threadIdx.x, lane = tid&63, w = tid>>6;
  __shared__ __align__(16) u16 az[64*PIT];   // [m][k]
  __shared__ __align__(16) u16 wt[64*PIT];   // [n][k]
  f32x4 acc[4] = {{0,0,0,0},{0,0,0,0},{0,0,0,0},{0,0,0,0}};
  int rr = tid>>2, seg = tid&3;
  for (int kc = 0; kc < 16; kc++){
    int k0 = kc*64;
    __syncthreads();
    { // stage A (ZbB rows)
      const u16* src = ZbB + ((size_t)(b*64 + rr))*1024 + k0 + seg*16;
      *reinterpret_cast<uint4*>(&az[rr*PIT + seg*16])   = *reinterpret_cast<const uint4*>(src);
      *reinterpret_cast<uint4*>(&az[rr*PIT + seg*16+8]) = *reinterpret_cast<const uint4*>(src+8);
    }
    { // stage B (W1T rows, direct bf16 copy)
      const u16* src = W1T + ((size_t)(c0 + rr))*1024 + k0 + seg*16;
      *reinterpret_cast<uint4*>(&wt[rr*PIT + seg*16])   = *reinterpret_cast<const uint4*>(src);
      *reinterpret_cast<uint4*>(&wt[rr*PIT + seg*16+8]) = *reinterpret_cast<const uint4*>(src+8);
    }
    __syncthreads();
#pragma unroll
    for (int s = 0; s < 2; s++){
      short8 a = *reinterpret_cast<const short8*>(&az[(16*w + (lane&15))*PIT + s*32 + (lane>>4)*8]);
#pragma unroll
      for (int t = 0; t < 4; t++){
        short8 bb = *reinterpret_cast<const short8*>(&wt[(t*16 + (lane&15))*PIT + s*32 + (lane>>4)*8]);
        acc[t] = __builtin_amdgcn_mfma_f32_16x16x32_bf16(a, bb, acc[t], 0, 0, 0);
      }
    }
  }
#pragma unroll
  for (int t = 0; t < 4; t++)
#pragma unroll
    for (int r = 0; r < 4; r++){
      int m = 16*w + (lane>>4)*4 + r;
      int n = c0 + t*16 + (lane&15);
      float val = acc[t][r] + b1[n];
      float g = 0.5f * val * (1.0f + erff(val * 0.70710678f));
      Hh[((size_t)(b*64 + m))*4096 + n] = (m < 50) ? f2b(g) : (u16)0;
    }
}

// ---------------- K6: partials of Hh @ W2T (MFMA, K-split x4, bf16 direct staging) ----------------
__global__ __launch_bounds__(256) void kmlp2p(const u16* __restrict__ Hh, const u16* __restrict__ W2T,
                                              float* __restrict__ Mpart){
  int blk = blockIdx.x;            // 512 = b(8) * dt(16) * kt(4)
  int kt = blk & 3, dt = (blk >> 2) & 15, b = blk >> 6;
  int d0 = dt*64;
  int tid = threadIdx.x, lane = tid&63, w = tid>>6;
  __shared__ __align__(16) u16 az[64*PIT];
  __shared__ __align__(16) u16 wt[64*PIT];
  f32x4 acc[4] = {{0,0,0,0},{0,0,0,0},{0,0,0,0},{0,0,0,0}};
  int rr = tid>>2, seg = tid&3;
  for (int kc = 0; kc < 16; kc++){
    int k0 = kt*1024 + kc*64;
    __syncthreads();
    {
      const u16* src = Hh + ((size_t)(b*64 + rr))*4096 + k0 + seg*16;
      *reinterpret_cast<uint4*>(&az[rr*PIT + seg*16])   = *reinterpret_cast<const uint4*>(src);
      *reinterpret_cast<uint4*>(&az[rr*PIT + seg*16+8]) = *reinterpret_cast<const uint4*>(src+8);
    }
    { // stage B (W2T rows, direct bf16 copy)
      const u16* src = W2T + ((size_t)(d0 + rr))*4096 + k0 + seg*16;
      *reinterpret_cast<uint4*>(&wt[rr*PIT + seg*16])   = *reinterpret_cast<const uint4*>(src);
      *reinterpret_cast<uint4*>(&wt[rr*PIT + seg*16+8]) = *reinterpret_cast<const uint4*>(src+8);
    }
    __syncthreads();
#pragma unroll
    for (int s = 0; s < 2; s++){
      short8 a = *reinterpret_cast<const short8*>(&az[(16*w + (lane&15))*PIT + s*32 + (lane>>4)*8]);
#pragma unroll
      for (int t = 0; t < 4; t++){
        short8 bb = *reinterpret_cast<const short8*>(&wt[(t*16 + (lane&15))*PIT + s*32 + (lane>>4)*8]);
        acc[t] = __builtin_amdgcn_mfma_f32_16x16x32_bf16(a, bb, acc[t], 0, 0, 0);
      }
    }
  }
#pragma unroll
  for (int t = 0; t < 4; t++)
#pragma unroll
    for (int r = 0; r < 4; r++){
      int m = 16*w + (lane>>4)*4 + r;
      int d = d0 + t*16 + (lane&15);
      if (m < 50) Mpart[(((size_t)(b*4) + kt)*50 + m)*1024 + d] = acc[t][r];
    }
}

// ---------------- K6b: HfT = tanh(sum partials + b2)^T, bf16, m>=50 zero ----------------
__global__ void kredT(const float* __restrict__ Mpart, const float* __restrict__ b2, u16* __restrict__ HfT){
  int e = blockIdx.x*256 + threadIdx.x;    // grid 2048 -> 524288 over [b][m(64)][d]
  int b = e >> 16, rem = e & 65535;
  int m = rem >> 10, d = rem & 1023;
  u16 outv = 0;
  if (m < 50){
    const float* p = Mpart + (size_t)b*204800 + m*1024 + d;
    float s = p[0] + p[51200] + p[102400] + p[153600] + b2[d];
    outv = f2b(tanhf(s));
  }
  HfT[((size_t)(b*1024) + d)*64 + m] = outv;
}

// ---------------- K7: out = x + C @ Hf (MFMA + LDS-bounced coalesced epilogue) ----------
__global__ __launch_bounds__(256) void kdec2(const float* __restrict__ x, const u16* __restrict__ C,
                                             const u16* __restrict__ HfT, float* __restrict__ out){
  int blk = blockIdx.x;              // 2048 = b(8) * nt(64) * dq(4)
  int dq = blk & 3, nt = (blk >> 2) & 63, b = blk >> 8;
  int n0 = nt << 6;
  int tid = threadIdx.x, lane = tid&63, w = tid>>6;
  __shared__ __align__(16) u16 ctile[64*PIT];   // [tok][m]
  __shared__ __align__(16) u16 htile[64*PIT];   // [d][m]
  __shared__ __align__(16) float obuf[64*68];   // [n][d] f32, pitch 68
  int rr = tid>>2, seg = tid&3;
  {
    const u16* src = C + ((size_t)(b*4096 + n0 + rr))*64 + seg*16;
    *reinterpret_cast<uint4*>(&ctile[rr*PIT + seg*16])   = *reinterpret_cast<const uint4*>(src);
    *reinterpret_cast<uint4*>(&ctile[rr*PIT + seg*16+8]) = *reinterpret_cast<const uint4*>(src+8);
  }
  __syncthreads();
  short8 afrag[2];
#pragma unroll
  for (int s = 0; s < 2; s++)
    afrag[s] = *reinterpret_cast<const short8*>(&ctile[(16*w + (lane&15))*PIT + s*32 + (lane>>4)*8]);
  for (int dt2 = 0; dt2 < 4; dt2++){
    int d0 = (dq*4 + dt2) * 64;
    __syncthreads();
    {
      const u16* src = HfT + ((size_t)(b*1024 + d0 + rr))*64 + seg*16;
      *reinterpret_cast<uint4*>(&htile[rr*PIT + seg*16])   = *reinterpret_cast<const uint4*>(src);
      *reinterpret_cast<uint4*>(&htile[rr*PIT + seg*16+8]) = *reinterpret_cast<const uint4*>(src+8);
    }
    __syncthreads();
    f32x4 acc[4] = {{0,0,0,0},{0,0,0,0},{0,0,0,0},{0,0,0,0}};
#pragma unroll
    for (int s = 0; s < 2; s++){
#pragma unroll
      for (int t = 0; t < 4; t++){
        short8 bb = *reinterpret_cast<const short8*>(&htile[(t*16 + (lane&15))*PIT + s*32 + (lane>>4)*8]);
        acc[t] = __builtin_amdgcn_mfma_f32_16x16x32_bf16(afrag[s], bb, acc[t], 0, 0, 0);
      }
    }
    // scatter acc into LDS [n][d] f32
#pragma unroll
    for (int t = 0; t < 4; t++)
#pragma unroll
      for (int r = 0; r < 4; r++){
        int nl = 16*w + (lane>>4)*4 + r;
        int dl = t*16 + (lane&15);
        obuf[nl*68 + dl] = acc[t][r];
      }
    __syncthreads();
    // coalesced epilogue: 1024 float4-slots (64 rows x 16 slots), 4 per thread
#pragma unroll
    for (int pass = 0; pass < 4; pass++){
      int s2 = tid + pass*256;
      int nl = s2 >> 4, sg = s2 & 15;
      size_t o = ((size_t)(b*4096 + n0 + nl))*1024 + d0 + sg*4;
      float4 xv = *reinterpret_cast<const float4*>(x + o);
      const float* ob = &obuf[nl*68 + sg*4];
      float4 ov;
      ov.x = xv.x + ob[0];
      ov.y = xv.y + ob[1];
      ov.z = xv.z + ob[2];
      ov.w = xv.w + ob[3];
      *reinterpret_cast<float4*>(out + o) = ov;
    }
  }
}

// ---------------- launch ----------------
extern "C" void kernel_launch(void* const* d_in, const int* in_sizes, int n_in,
                              void* d_out, int out_size, void* d_ws, size_t ws_size,
                              hipStream_t stream) {
  (void)in_sizes; (void)n_in; (void)out_size;
  if (ws_size < (size_t)19755264) return;
  const float* x  = (const float*)d_in[0];
  const float* pn = (const float*)d_in[1];
  const float* W1 = (const float*)d_in[8];
  const float* b1 = (const float*)d_in[9];
  const float* W2 = (const float*)d_in[10];
  const float* b2 = (const float*)d_in[11];
  float* out = (float*)d_out;
  char* ws = (char*)d_ws;

  // W1T/W2T bf16 scratch lives in d_out (134 MB): dead before kdec2 fully
  // overwrites out. W1T = 4096x1024 bf16 (8.39MB), W2T = 1024x4096 bf16.
  u16*   W1T = (u16*)d_out;
  u16*   W2T = (u16*)d_out + 4194304;

  // Overlapped ws layout (stream-ordered liveness):
  u16*   C   = (u16*)(ws);                      // [0, 4.19MB)        live kC->kdec2
  u16*   CT  = (u16*)(ws + 4194304);            // CT region 4.19MB:  CT live kC->kHp2
  u16*   ZbB = (u16*)(ws + 4194304 + 1638400);  //   reuses CT space  (kapply2->kmlp1)
  u16*   HfT = (u16*)(ws + 4194304 + 2686976);  //   (kredT->kdec2)
  u16*   Hh  = (u16*)(ws + 8388608);            // Hh region 4.19MB:  Hh live kmlp1->kmlp2p
  u16*   Hb  = (u16*)(ws + 8388608);            //   reuses Hh space  (kredH->kgram)
  float* H   = (float*)(ws + 8388608 + 1048576);//   (kredH->kapply2)
  float* HP  = (float*)(ws + 12582912);         // partials 6.55MB: kHp2->kredH, kmlp2p->kredT
  u16*   PT  = (u16*)(ws + 19136512);           // 131,072 B
  float* G   = (float*)(ws + 19267584);         // 80,000 B
  float* WM  = (float*)(ws + 19347584);         // 80,000 B

  hipLaunchKernelGGL(kprepAll, dim3(2112), dim3(256), 0, stream, pn, PT, W1, W1T, W2, W2T);
  hipLaunchKernelGGL(kC,       dim3(512),  dim3(256), 0, stream, x, PT, C, CT);
  hipLaunchKernelGGL(kHp2,     dim3(512),  dim3(256), 0, stream, x, CT, HP);
  hipLaunchKernelGGL(kredH,    dim3(2048), dim3(256), 0, stream, HP, H, Hb);
  hipLaunchKernelGGL(kgram,    dim3(8),    dim3(256), 0, stream, Hb, G);
  hipLaunchKernelGGL(kns3,     dim3(8),    dim3(256), 0, stream, G, WM);
  hipLaunchKernelGGL(kapply2,  dim3(128),  dim3(256), 0, stream, H, WM, ZbB);
  hipLaunchKernelGGL(kmlp1,    dim3(512),  dim3(256), 0, stream, ZbB, W1T, b1, Hh);
  hipLaunchKernelGGL(kmlp2p,   dim3(512),  dim3(256), 0, stream, Hh, W2T, HP);
  hipLaunchKernelGGL(kredT,    dim3(2048), dim3(256), 0, stream, HP, b2, HfT);
  hipLaunchKernelGGL(kdec2,    dim3(2048), dim3(256), 0, stream, x, C, HfT, out);
}